// Round 2
// baseline (5979.069 us; speedup 1.0000x reference)
//
#include <hip/hip_runtime.h>
#include <hip/hip_bf16.h>

#define DEV __device__ __forceinline__

DEV float toF(float v){ return v; }
DEV float toF(__hip_bfloat16 v){ return __bfloat162float(v); }
DEV void fromF(float v, float& o){ o = v; }
DEV void fromF(float v, __hip_bfloat16& o){ o = __float2bfloat16(v); }

// ---------------- weight reorder: -> [ci][tap][co] ----------------
__global__ __launch_bounds__(256) void wtrans_conv(const float* __restrict__ w,
    float* __restrict__ w2, int CO, int CI, int KK) {
  int i = blockIdx.x*256 + threadIdx.x;
  int total = CO*CI*KK;
  if (i >= total) return;
  int t = i % KK; int ci = (i/KK) % CI; int co = i/(KK*CI);   // src w[co][ci][t]
  w2[((long)ci*KK + t)*CO + co] = w[i];
}
__global__ __launch_bounds__(256) void wtrans_deconv(const float* __restrict__ w,
    float* __restrict__ w2, int CI, int CO, int KK) {
  int i = blockIdx.x*256 + threadIdx.x;
  int total = CI*CO*KK;
  if (i >= total) return;
  int t = i % KK; int co = (i/KK) % CO; int ci = i/(KK*CO);   // src w[ci][co][t]
  w2[((long)ci*KK + t)*CO + co] = w[i];
}

// ---------------- conv stride2 k4 pad1 (f32) ----------------
// block: 64 co x (8x8) px, thread: 4co x 4px
template<int CIN, int CC, bool RELU>
__global__ __launch_bounds__(256) void conv_s2k4(
    const float* __restrict__ x, const float* __restrict__ w2,
    const float* __restrict__ bias, float* __restrict__ y,
    int Hin, int Win, int Hout, int Wout, int COtot) {
  constexpr int TCO = 64;
  __shared__ __align__(16) float sIn[CC][18][20];
  __shared__ __align__(16) float sW[CC*16*TCO];
  const int tid = threadIdx.x;
  const int cogs = COtot / TCO;
  const int b = blockIdx.z / cogs, cog = blockIdx.z % cogs;
  const int co0 = cog*TCO;
  const int oy0 = blockIdx.y*8, ox0 = blockIdx.x*8;
  const int pg = tid & 15, cg = tid >> 4;
  const int r = pg >> 1, cb4 = (pg & 1)*4;
  float acc[4][4];
  #pragma unroll
  for (int cc=0;cc<4;cc++){ float bv = bias[co0+cg*4+cc];
    #pragma unroll
    for (int j=0;j<4;j++) acc[cc][j]=bv; }
  const float* xb = x + (long)b*CIN*Hin*Win;
  const int iy0 = 2*oy0 - 1, ix0 = 2*ox0 - 1;
  for (int ci0=0; ci0<CIN; ci0+=CC) {
    __syncthreads();
    for (int t=tid; t<CC*18*18; t+=256) {
      int xx = t%18, yy=(t/18)%18, ci=t/(18*18);
      int gy = iy0+yy, gx = ix0+xx;
      float v = 0.f;
      if (gy>=0 && gy<Hin && gx>=0 && gx<Win) v = xb[((long)(ci0+ci)*Hin+gy)*Win+gx];
      sIn[ci][yy][xx] = v;
    }
    const float* wsrc = w2 + (long)ci0*16*COtot + co0;
    for (int t=tid; t<CC*16*TCO; t+=256) {
      int cox = t & 63, rest = t >> 6;
      sW[t] = wsrc[(long)rest*COtot + cox];
    }
    __syncthreads();
    for (int ci=0; ci<CC; ci++) {
      #pragma unroll
      for (int ky=0;ky<4;ky++)
      #pragma unroll
      for (int kx=0;kx<4;kx++) {
        float4 wv = *(const float4*)(&sW[(ci*16 + ky*4+kx)*TCO + cg*4]);
        const int yy = 2*r + ky;
        #pragma unroll
        for (int j=0;j<4;j++) {
          float iv = sIn[ci][yy][2*(cb4+j)+kx];
          acc[0][j] += wv.x*iv; acc[1][j] += wv.y*iv;
          acc[2][j] += wv.z*iv; acc[3][j] += wv.w*iv;
        }
      }
    }
  }
  #pragma unroll
  for (int cc=0;cc<4;cc++)
  #pragma unroll
  for (int j=0;j<4;j++) {
    float v = acc[cc][j];
    if (RELU) v = fmaxf(v, 0.f);
    y[(((long)b*COtot + co0+cg*4+cc)*Hout + oy0+r)*Wout + ox0+cb4+j] = v;
  }
}

// ---------------- conv stride1 k3 pad1 (f32) ----------------
template<int CIN, int CC, bool RELU>
__global__ __launch_bounds__(256) void conv_s1k3(
    const float* __restrict__ x, const float* __restrict__ w2,
    const float* __restrict__ bias, float* __restrict__ y,
    int H, int W, int COtot) {
  constexpr int TCO = 64;
  __shared__ __align__(16) float sIn[CC][10][12];
  __shared__ __align__(16) float sW[CC*9*TCO];
  const int tid = threadIdx.x;
  const int cogs = COtot / TCO;
  const int b = blockIdx.z / cogs, cog = blockIdx.z % cogs;
  const int co0 = cog*TCO;
  const int oy0 = blockIdx.y*8, ox0 = blockIdx.x*8;
  const int pg = tid & 15, cg = tid >> 4;
  const int r = pg >> 1, cb4 = (pg & 1)*4;
  float acc[4][4];
  #pragma unroll
  for (int cc=0;cc<4;cc++){ float bv = bias[co0+cg*4+cc];
    #pragma unroll
    for (int j=0;j<4;j++) acc[cc][j]=bv; }
  const float* xb = x + (long)b*CIN*H*W;
  for (int ci0=0; ci0<CIN; ci0+=CC) {
    __syncthreads();
    for (int t=tid; t<CC*10*10; t+=256) {
      int xx = t%10, yy=(t/10)%10, ci=t/100;
      int gy = oy0-1+yy, gx = ox0-1+xx;
      float v = 0.f;
      if (gy>=0 && gy<H && gx>=0 && gx<W) v = xb[((long)(ci0+ci)*H+gy)*W+gx];
      sIn[ci][yy][xx] = v;
    }
    const float* wsrc = w2 + (long)ci0*9*COtot + co0;
    for (int t=tid; t<CC*9*TCO; t+=256) {
      int cox = t & 63, rest = t >> 6;
      sW[t] = wsrc[(long)rest*COtot + cox];
    }
    __syncthreads();
    for (int ci=0; ci<CC; ci++) {
      #pragma unroll
      for (int ky=0;ky<3;ky++)
      #pragma unroll
      for (int kx=0;kx<3;kx++) {
        float4 wv = *(const float4*)(&sW[(ci*9 + ky*3+kx)*TCO + cg*4]);
        #pragma unroll
        for (int j=0;j<4;j++) {
          float iv = sIn[ci][r+ky][cb4+j+kx];
          acc[0][j] += wv.x*iv; acc[1][j] += wv.y*iv;
          acc[2][j] += wv.z*iv; acc[3][j] += wv.w*iv;
        }
      }
    }
  }
  #pragma unroll
  for (int cc=0;cc<4;cc++)
  #pragma unroll
  for (int j=0;j<4;j++) {
    float v = acc[cc][j];
    if (RELU) v = fmaxf(v, 0.f);
    y[(((long)b*COtot + co0+cg*4+cc)*H + oy0+r)*W + ox0+cb4+j] = v;
  }
}

// ---------------- ConvTranspose2d stride2 k4 pad1 ----------------
// parity: for output (oy,ox), e=oy&1,f=ox&1: ky=2a+1-e, iy=(oy>>1)+e-a; same for x.
// block: 32 co x (16x16) px, thread: 4co x 8px (same-parity columns)
template<int CIN, int CC, bool RELU, typename TIN, typename TOUT>
__global__ __launch_bounds__(256) void deconv_s2k4(
    const TIN* __restrict__ x, const float* __restrict__ w2,
    const float* __restrict__ bias, TOUT* __restrict__ y,
    int Hin, int Win, int Hout, int Wout, int COtot) {
  constexpr int TCO = 32;
  __shared__ __align__(16) float sIn[CC][10][12];
  __shared__ __align__(16) float sW[CC*16*TCO];
  const int tid = threadIdx.x;
  const int cogs = COtot / TCO;
  const int b = blockIdx.z / cogs, cog = blockIdx.z % cogs;
  const int co0 = cog*TCO;
  const int oy0 = blockIdx.y*16, ox0 = blockIdx.x*16;
  const int ty0 = blockIdx.y*8, tx0 = blockIdx.x*8;
  const int pg = tid & 31, cg = tid >> 5;
  const int r = pg >> 1, cb = pg & 1;
  const int ep = r & 1, fp = cb;
  const int ybase = (r>>1) + 1 + ep;
  float acc[4][8];
  #pragma unroll
  for (int cc=0;cc<4;cc++){ float bv = bias[co0+cg*4+cc];
    #pragma unroll
    for (int j=0;j<8;j++) acc[cc][j]=bv; }
  const TIN* xb = x + (long)b*CIN*Hin*Win;
  for (int ci0=0; ci0<CIN; ci0+=CC) {
    __syncthreads();
    for (int t=tid; t<CC*10*10; t+=256) {
      int xx = t%10, yy=(t/10)%10, ci=t/100;
      int gy = ty0-1+yy, gx = tx0-1+xx;
      float v = 0.f;
      if (gy>=0 && gy<Hin && gx>=0 && gx<Win) v = toF(xb[((long)(ci0+ci)*Hin+gy)*Win+gx]);
      sIn[ci][yy][xx] = v;
    }
    const float* wsrc = w2 + (long)ci0*16*COtot + co0;
    for (int t=tid; t<CC*16*TCO; t+=256) {
      int cox = t & 31, rest = t >> 5;
      sW[t] = wsrc[(long)rest*COtot + cox];
    }
    __syncthreads();
    for (int ci=0; ci<CC; ci++) {
      #pragma unroll
      for (int a=0;a<2;a++)
      #pragma unroll
      for (int bb=0;bb<2;bb++) {
        const int ky = 2*a + 1 - ep;
        const int kx = 2*bb + 1 - fp;
        float4 wv = *(const float4*)(&sW[(ci*16 + ky*4+kx)*TCO + cg*4]);
        const int yy = ybase - a;
        #pragma unroll
        for (int j=0;j<8;j++) {
          float iv = sIn[ci][yy][j + 1 + fp - bb];
          acc[0][j] += wv.x*iv; acc[1][j] += wv.y*iv;
          acc[2][j] += wv.z*iv; acc[3][j] += wv.w*iv;
        }
      }
    }
  }
  #pragma unroll
  for (int cc=0;cc<4;cc++)
  #pragma unroll
  for (int j=0;j<8;j++) {
    float v = acc[cc][j];
    if (RELU) v = fmaxf(v, 0.f);
    fromF(v, y[(((long)b*COtot + co0+cg*4+cc)*Hout + oy0+r)*Wout + ox0 + cb + 2*j]);
  }
}

// ---------------- ConvTranspose2d stride1 k3 pad1 + sigmoid, COUT=3 ----------------
template<int CIN, int CC, typename TIN>
__global__ __launch_bounds__(256) void deconv_s1k3_sig(
    const TIN* __restrict__ x, const float* __restrict__ w2,
    const float* __restrict__ bias, float* __restrict__ y, int H, int W) {
  __shared__ float sIn[CC][34][36];
  __shared__ float sW[CC*9*3];
  const int tid = threadIdx.x;
  const int b = blockIdx.z;
  const int oy0 = blockIdx.y*32, ox0 = blockIdx.x*32;
  const int r = tid >> 3, cB = (tid & 7)*4;
  float acc[3][4];
  #pragma unroll
  for (int co=0;co<3;co++){ float bv = bias[co];
    #pragma unroll
    for (int j=0;j<4;j++) acc[co][j]=bv; }
  const TIN* xb = x + (long)b*CIN*H*W;
  for (int ci0=0; ci0<CIN; ci0+=CC) {
    __syncthreads();
    for (int t=tid; t<CC*34*34; t+=256) {
      int xx = t%34, yy=(t/34)%34, ci=t/(34*34);
      int gy = oy0-1+yy, gx = ox0-1+xx;
      float v = 0.f;
      if (gy>=0 && gy<H && gx>=0 && gx<W) v = toF(xb[((long)(ci0+ci)*H+gy)*W+gx]);
      sIn[ci][yy][xx] = v;
    }
    for (int t=tid; t<CC*9*3; t+=256) sW[t] = w2[(long)ci0*9*3 + t];
    __syncthreads();
    for (int ci=0; ci<CC; ci++) {
      #pragma unroll
      for (int ky=0;ky<3;ky++)
      #pragma unroll
      for (int kx=0;kx<3;kx++) {
        const float* wp = &sW[(ci*9 + ky*3+kx)*3];
        float w0 = wp[0], w1 = wp[1], w2v = wp[2];
        const int yy = r + 2 - ky;   // iy = oy+1-ky
        #pragma unroll
        for (int j=0;j<4;j++) {
          float iv = sIn[ci][yy][cB+j+2-kx];
          acc[0][j] += w0*iv; acc[1][j] += w1*iv; acc[2][j] += w2v*iv;
        }
      }
    }
  }
  #pragma unroll
  for (int co=0;co<3;co++)
  #pragma unroll
  for (int j=0;j<4;j++) {
    float v = acc[co][j];
    v = 1.f/(1.f + expf(-v));
    y[(((long)b*3 + co)*H + oy0+r)*W + ox0+cB+j] = v;
  }
}

// ---------------- vector quantizer ----------------
// flat row n = 64 consecutive floats of z_e (NCHW reshape(-1,64)).
__global__ __launch_bounds__(256) void vq_kernel(
    const float* __restrict__ ze, const float* __restrict__ emb,
    float* __restrict__ out_idx, float* __restrict__ zq) {
  __shared__ __align__(16) float se[128*64];
  __shared__ float sn[128];
  const int tid = threadIdx.x;
  const long n = (long)blockIdx.x*256 + tid;
  float4 rv[16];
  const float4* zr = (const float4*)(ze + n*64);
  #pragma unroll
  for (int q=0;q<16;q++) rv[q] = zr[q];
  float best = 3.4e38f; int bidx = 0;
  for (int ch=0; ch<4; ch++) {
    __syncthreads();
    #pragma unroll
    for (int i=0;i<32;i++) se[tid + i*256] = emb[ch*8192 + tid + i*256];
    __syncthreads();
    if (tid < 128) {
      float s = 0.f;
      #pragma unroll 8
      for (int d=0; d<64; d++){ float v = se[tid*64+d]; s += v*v; }
      sn[tid] = s;
    }
    __syncthreads();
    for (int k=0; k<128; k++) {
      const float4* ev = (const float4*)&se[k*64];
      float dot = 0.f;
      #pragma unroll
      for (int q=0;q<16;q++){
        float4 e4 = ev[q];
        dot += rv[q].x*e4.x + rv[q].y*e4.y + rv[q].z*e4.z + rv[q].w*e4.w;
      }
      float s = sn[k] - 2.f*dot;
      if (s < best) { best = s; bidx = ch*128 + k; }
    }
  }
  out_idx[n] = (float)bidx;
  const float4* eb = (const float4*)(emb + (long)bidx*64);
  float4* zo = (float4*)(zq + n*64);
  #pragma unroll
  for (int q=0;q<16;q++) zo[q] = eb[q];
}

// ---------------- launch ----------------
extern "C" void kernel_launch(void* const* d_in, const int* in_sizes, int n_in,
                              void* d_out, int out_size, void* d_ws, size_t ws_size,
                              hipStream_t stream) {
  const float* x   = (const float*)d_in[0];
  const float* c1w = (const float*)d_in[1];  const float* c1b = (const float*)d_in[2];
  const float* c2w = (const float*)d_in[3];  const float* c2b = (const float*)d_in[4];
  const float* c3w = (const float*)d_in[5];  const float* c3b = (const float*)d_in[6];
  const float* emb = (const float*)d_in[7];
  const float* d1w = (const float*)d_in[8];  const float* d1b = (const float*)d_in[9];
  const float* d2w = (const float*)d_in[10]; const float* d2b = (const float*)d_in[11];
  const float* d3w = (const float*)d_in[12]; const float* d3b = (const float*)d_in[13];
  float* out = (float*)d_out;

  float* xrec = out;                 // 16*3*256*256 = 3145728
  float* oidx = out + 3145728;       // 65536
  float* zq   = out + 3211264;       // 16*64*64*64 = 4194304

  // per-batch element strides
  const long XB = 196608;    // 3*256*256
  const long H1B = 2097152;  // 128*128*128 (elems)
  const long H2B = 524288;   // 128*64*64
  const long ZEB = 262144;   // 64*64*64
  const long G2B = 8388608;  // 128*256*256

  // Adaptive workspace plans (bytes). R1 holds h1-group(f32) then g2-group(bf16);
  // R2 holds h2 then g1-group; R3 holds ze; W holds transposed weights (738688 floats).
  const size_t WBYTES = 2954752ULL;
  const size_t PLAN_A = 67108864ULL + 33554432ULL + 16777216ULL + WBYTES; // 120,395,264
  const size_t PLAN_B = 16777216ULL +  4194304ULL + 16777216ULL + WBYTES; //  40,703,488
  const size_t PLAN_C = 16777216ULL +  4194304ULL +  1048576ULL + WBYTES; //  24,974,848

  char* wsb = (char*)d_ws;
  int plan;
  size_t offR2, offR3, offW;
  if (ws_size >= PLAN_A)      { plan = 0; offR2 = 67108864;  offR3 = 100663296; offW = 117440512; }
  else if (ws_size >= PLAN_B) { plan = 1; offR2 = 16777216;  offR3 = 20971520;  offW = 37748736; }
  else if (ws_size >= PLAN_C) { plan = 2; offR2 = 16777216;  offR3 = 20971520;  offW = 22020096; }
  else return;

  float* R1 = (float*)wsb;
  float* R2 = (float*)(wsb + offR2);
  float* ze = (float*)(wsb + offR3);
  float* W  = (float*)(wsb + offW);
  float* w2c1 = W;            // 6144
  float* w2c2 = W + 6144;     // 262144
  float* w2c3 = W + 268288;   // 73728
  float* w2d1 = W + 342016;   // 131072
  float* w2d2 = W + 473088;   // 262144
  float* w2d3 = W + 735232;   // 3456

  // weight reorders
  wtrans_conv  <<<24,   256, 0, stream>>>(c1w, w2c1, 128, 3,   16);
  wtrans_conv  <<<1024, 256, 0, stream>>>(c2w, w2c2, 128, 128, 16);
  wtrans_conv  <<<288,  256, 0, stream>>>(c3w, w2c3, 64,  128, 9);
  wtrans_deconv<<<512,  256, 0, stream>>>(d1w, w2d1, 64,  128, 16);
  wtrans_deconv<<<1024, 256, 0, stream>>>(d2w, w2d2, 128, 128, 16);
  wtrans_deconv<<<14,   256, 0, stream>>>(d3w, w2d3, 128, 3,   9);

  if (plan == 0) {
    // ---- Plan A: groups of 4 batches ----
    for (int g = 0; g < 4; ++g) {
      conv_s2k4<3,  3, true ><<<dim3(16,16,8), 256, 0, stream>>>(
          x + (long)g*4*XB, w2c1, c1b, R1, 256,256,128,128, 128);
      conv_s2k4<128,8, true ><<<dim3(8, 8, 8), 256, 0, stream>>>(
          R1, w2c2, c2b, R2 + (long)g*4*H2B, 128,128, 64, 64, 128);
    }
    conv_s1k3<128,8, false><<<dim3(8, 8, 16), 256, 0, stream>>>(R2, w2c3, c3b, ze, 64, 64, 64);
    vq_kernel<<<256, 256, 0, stream>>>(ze, emb, oidx, zq);
    for (int g = 0; g < 4; ++g) {
      deconv_s2k4<64, 8, true, float,          __hip_bfloat16><<<dim3(8, 8, 16), 256, 0, stream>>>(
          zq + (long)g*4*ZEB, w2d1, d1b, (__hip_bfloat16*)R2, 64, 64, 128,128, 128);
      deconv_s2k4<128,8, true, __hip_bfloat16, __hip_bfloat16><<<dim3(16,16,16), 256, 0, stream>>>(
          (__hip_bfloat16*)R2, w2d2, d2b, (__hip_bfloat16*)R1, 128,128,256,256, 128);
      deconv_s1k3_sig<128,8,   __hip_bfloat16><<<dim3(8, 8, 4), 256, 0, stream>>>(
          (__hip_bfloat16*)R1, w2d3, d3b, xrec + (long)g*4*XB, 256, 256);
    }
  } else {
    // ---- Plans B/C: per-batch ----
    const bool fullVQ = (plan == 1);
    for (int b = 0; b < 16; ++b) {
      conv_s2k4<3,  3, true ><<<dim3(16,16,2), 256, 0, stream>>>(
          x + (long)b*XB, w2c1, c1b, R1, 256,256,128,128, 128);
      conv_s2k4<128,8, true ><<<dim3(8, 8, 2), 256, 0, stream>>>(
          R1, w2c2, c2b, R2, 128,128, 64, 64, 128);
      float* zeb = fullVQ ? (ze + (long)b*ZEB) : ze;
      conv_s1k3<128,8, false><<<dim3(8, 8, 1), 256, 0, stream>>>(R2, w2c3, c3b, zeb, 64, 64, 64);
      if (!fullVQ)
        vq_kernel<<<16, 256, 0, stream>>>(zeb, emb, oidx + (long)b*4096, zq + (long)b*ZEB);
    }
    if (fullVQ)
      vq_kernel<<<256, 256, 0, stream>>>(ze, emb, oidx, zq);
    for (int b = 0; b < 16; ++b) {
      deconv_s2k4<64, 8, true, float,          __hip_bfloat16><<<dim3(8, 8, 4), 256, 0, stream>>>(
          zq + (long)b*ZEB, w2d1, d1b, (__hip_bfloat16*)R2, 64, 64, 128,128, 128);
      deconv_s2k4<128,8, true, __hip_bfloat16, __hip_bfloat16><<<dim3(16,16,4), 256, 0, stream>>>(
          (__hip_bfloat16*)R2, w2d2, d2b, (__hip_bfloat16*)R1, 128,128,256,256, 128);
      deconv_s1k3_sig<128,8,   __hip_bfloat16><<<dim3(8, 8, 1), 256, 0, stream>>>(
          (__hip_bfloat16*)R1, w2d3, d3b, xrec + (long)b*XB, 256, 256);
    }
  }
}

// Round 3
// 2856.870 us; speedup vs baseline: 2.0929x; 2.0929x over previous
//
#include <hip/hip_runtime.h>
#include <hip/hip_bf16.h>

#define DEV __device__ __forceinline__

typedef __attribute__((ext_vector_type(8))) short bf16x8;
typedef __attribute__((ext_vector_type(4))) float f32x4;

DEV float toF(float v){ return v; }
DEV float toF(__hip_bfloat16 v){ return __bfloat162float(v); }
DEV unsigned short bfbits(float v){ __hip_bfloat16 h = __float2bfloat16(v); return *(unsigned short*)&h; }

// ---------------- weight reorder (f32 paths): -> [ci][tap][co] ----------------
__global__ __launch_bounds__(256) void wtrans_conv(const float* __restrict__ w,
    float* __restrict__ w2, int CO, int CI, int KK) {
  int i = blockIdx.x*256 + threadIdx.x;
  int total = CO*CI*KK;
  if (i >= total) return;
  int t = i % KK; int ci = (i/KK) % CI; int co = i/(KK*CI);
  w2[((long)ci*KK + t)*CO + co] = w[i];
}
__global__ __launch_bounds__(256) void wtrans_deconv(const float* __restrict__ w,
    float* __restrict__ w2, int CI, int CO, int KK) {
  int i = blockIdx.x*256 + threadIdx.x;
  int total = CI*CO*KK;
  if (i >= total) return;
  int t = i % KK; int co = (i/KK) % CO; int ci = i/(KK*CO);
  w2[((long)ci*KK + t)*CO + co] = w[i];
}

// ---------------- MFMA deconv weight prep ----------------
// w (torch deconv): [CI][128][4][4]. Out: w2[e][f][co][K] bf16,
// K ordered: chunk(ci>>4)*64 + tap*16 + (ci&15), tap=(a,b), ky=2a+1-e, kx=2b+1-f.
__global__ __launch_bounds__(256) void wprep_deconv_mfma(
    const float* __restrict__ w, unsigned short* __restrict__ w2, int CI) {
  const int K = CI*4;
  int i = blockIdx.x*256 + threadIdx.x;
  if (i >= 512*K) return;
  int k  = i % K;
  int co = (i / K) & 127;
  int f  = (i / (K*128)) & 1;
  int e  = i / (K*256);
  int ci = (k & 15) | ((k >> 6) << 4);
  int tap = (k >> 4) & 3, a = tap >> 1, b = tap & 1;
  float v = w[ (((long)ci*128 + co)*4 + (2*a+1-e))*4 + (2*b+1-f) ];
  w2[i] = bfbits(v);
}

// ---------------- MFMA ConvTranspose2d stride2 k4 pad1 ----------------
// Block: one (batch b, y-parity e, input row ty). M = 2*TX px (both x-parities),
// N = 128 co, K = CIN*4. Output row oy=2ty+e written fully contiguous.
template<int CIN, int TX, bool IN_F32>
struct SmemT {
  union {
    struct {
      __align__(16) unsigned short In[2][TX+2][24];   // [iy'][c][ci16], stride 24
      __align__(16) unsigned short W[2][128][64];     // [f][co][k64], slot-swizzled
    };
    __align__(16) unsigned short Out[128][2*TX];      // [co][ox], xor-swizzled
  };
};

template<int CIN, int TX, bool IN_F32>
__global__ __launch_bounds__(TX*4, 4) void deconv_mfma(
    const void* __restrict__ xin, const unsigned short* __restrict__ w2,
    const float* __restrict__ bias, unsigned short* __restrict__ y) {
  constexpr int NTHR = TX*4;          // 512 (TX=128) / 256 (TX=64)
  constexpr int K    = CIN*4;
  constexpr int TPR  = NTHR/32;       // threads per (ci,iy) staging row
  __shared__ SmemT<CIN,TX,IN_F32> sm;

  const int tid = threadIdx.x;
  const int ty = blockIdx.x, e = blockIdx.y, b = blockIdx.z;
  const int wave = tid >> 6, lane = tid & 63;
  const int wc = wave & 1, wr = wave >> 1;
  const int f = (wr*64) / TX;                 // wave's x-parity
  const int tx_base = (wr*64) & (TX-1);
  const int col_l = lane & 15, kg = lane >> 4;

  // zero padding columns (c=0 <-> ix=-1, c=TX+1 <-> ix=TX): always OOB
  if (tid < 64) {
    int rr = tid & 1, cc = ((tid>>1)&1) ? TX+1 : 0, ci = tid >> 2;
    sm.In[rr][cc][ci] = 0;
  }

  f32x4 acc[4][4] = {};
  const int rowid = tid / TPR, li = tid % TPR; // staging: rowid=(ci,iy), 8 elems/thread
  const int sci = rowid >> 1, srr = rowid & 1;
  const int iy = ty + e - 1 + srr;

  for (int ch = 0; ch < CIN/16; ++ch) {
    __syncthreads();
    // ---- stage input 16ci x 2iy x TX (transpose to ci-inner) ----
    {
      unsigned short vals[8];
      if (iy >= 0 && iy < TX) {
        long gofs = ((long)b*CIN + ch*16 + sci)*TX*TX + (long)iy*TX + li*8;
        if (IN_F32) {
          const float4* s = (const float4*)((const float*)xin + gofs);
          float4 lo = s[0], hi = s[1];
          vals[0]=bfbits(lo.x); vals[1]=bfbits(lo.y); vals[2]=bfbits(lo.z); vals[3]=bfbits(lo.w);
          vals[4]=bfbits(hi.x); vals[5]=bfbits(hi.y); vals[6]=bfbits(hi.z); vals[7]=bfbits(hi.w);
        } else {
          bf16x8 v = *(const bf16x8*)((const unsigned short*)xin + gofs);
          #pragma unroll
          for (int j=0;j<8;j++) vals[j] = ((unsigned short)v[j]);
        }
      } else {
        #pragma unroll
        for (int j=0;j<8;j++) vals[j] = 0;
      }
      #pragma unroll
      for (int j=0;j<8;j++) {
        int jj = (j + li) & 7;                       // stagger to spread banks
        sm.In[srr][1 + li*8 + jj][sci] = vals[jj];
      }
    }
    // ---- stage weights: both f, 128 co, 64 k (16B slots, xor-swizzled) ----
    for (int i = tid; i < 2048; i += NTHR) {
      int s = i & 7, co = (i >> 3) & 127, ff = i >> 10;
      const unsigned short* src = w2 + ((long)((e*2+ff)*128 + co))*K + ch*64 + s*8;
      *(uint4*)&sm.W[ff][co][(s ^ (co & 7))*8] = *(const uint4*)src;
    }
    __syncthreads();
    // ---- compute: 2 MFMA-k slices of 32 ----
    #pragma unroll
    for (int kk = 0; kk < 2; ++kk) {
      bf16x8 aF[4];
      const int tap = kk*2 + (kg >> 1), a = tap >> 1, bb = tap & 1;
      const int cib = (kg & 1)*8;
      #pragma unroll
      for (int mf = 0; mf < 4; ++mf) {
        int tx = tx_base + mf*16 + col_l;
        aF[mf] = *(const bf16x8*)&sm.In[1-a][tx + 1 + f - bb][cib];
      }
      const int slot = kk*4 + kg;
      #pragma unroll
      for (int nf = 0; nf < 4; ++nf) {
        int co_l = nf*16 + col_l;
        bf16x8 bF = *(const bf16x8*)&sm.W[f][wc*64 + co_l][(slot ^ (co_l & 7))*8];
        #pragma unroll
        for (int mf = 0; mf < 4; ++mf)
          acc[mf][nf] = __builtin_amdgcn_mfma_f32_16x16x32_bf16(aF[mf], bF, acc[mf][nf], 0, 0, 0);
      }
    }
  }

  // ---- epilogue: bias+relu -> LDS (swizzled) -> coalesced global ----
  __syncthreads();
  float bv[4];
  #pragma unroll
  for (int nf = 0; nf < 4; ++nf) bv[nf] = bias[wc*64 + nf*16 + col_l];
  #pragma unroll
  for (int mf = 0; mf < 4; ++mf)
  #pragma unroll
  for (int nf = 0; nf < 4; ++nf) {
    int co = wc*64 + nf*16 + col_l;
    #pragma unroll
    for (int r = 0; r < 4; ++r) {
      int tx = tx_base + mf*16 + kg*4 + r;
      float v = fmaxf(acc[mf][nf][r] + bv[nf], 0.f);
      int ox = 2*tx + f;
      sm.Out[co][ox ^ ((co & 15)*8)] = bfbits(v);
    }
  }
  __syncthreads();
  constexpr int CH = 2*TX/8;
  const int oy = 2*ty + e;
  for (int i = tid; i < 128*CH; i += NTHR) {
    int co = i / CH, cx = i % CH;
    uint4 v = *(const uint4*)&sm.Out[co][(cx ^ (co & 15))*8];
    *(uint4*)(y + (((long)b*128 + co)*(2*TX) + oy)*(long)(2*TX) + cx*8) = v;
  }
}

// ---------------- conv stride2 k4 pad1 (f32) ----------------
template<int CIN, int CC, bool RELU>
__global__ __launch_bounds__(256) void conv_s2k4(
    const float* __restrict__ x, const float* __restrict__ w2,
    const float* __restrict__ bias, float* __restrict__ y,
    int Hin, int Win, int Hout, int Wout, int COtot) {
  constexpr int TCO = 64;
  __shared__ __align__(16) float sIn[CC][18][20];
  __shared__ __align__(16) float sW[CC*16*TCO];
  const int tid = threadIdx.x;
  const int cogs = COtot / TCO;
  const int b = blockIdx.z / cogs, cog = blockIdx.z % cogs;
  const int co0 = cog*TCO;
  const int oy0 = blockIdx.y*8, ox0 = blockIdx.x*8;
  const int pg = tid & 15, cg = tid >> 4;
  const int r = pg >> 1, cb4 = (pg & 1)*4;
  float acc[4][4];
  #pragma unroll
  for (int cc=0;cc<4;cc++){ float bv = bias[co0+cg*4+cc];
    #pragma unroll
    for (int j=0;j<4;j++) acc[cc][j]=bv; }
  const float* xb = x + (long)b*CIN*Hin*Win;
  const int iy0 = 2*oy0 - 1, ix0 = 2*ox0 - 1;
  for (int ci0=0; ci0<CIN; ci0+=CC) {
    __syncthreads();
    for (int t=tid; t<CC*18*18; t+=256) {
      int xx = t%18, yy=(t/18)%18, ci=t/(18*18);
      int gy = iy0+yy, gx = ix0+xx;
      float v = 0.f;
      if (gy>=0 && gy<Hin && gx>=0 && gx<Win) v = xb[((long)(ci0+ci)*Hin+gy)*Win+gx];
      sIn[ci][yy][xx] = v;
    }
    const float* wsrc = w2 + (long)ci0*16*COtot + co0;
    for (int t=tid; t<CC*16*TCO; t+=256) {
      int cox = t & 63, rest = t >> 6;
      sW[t] = wsrc[(long)rest*COtot + cox];
    }
    __syncthreads();
    for (int ci=0; ci<CC; ci++) {
      #pragma unroll
      for (int ky=0;ky<4;ky++)
      #pragma unroll
      for (int kx=0;kx<4;kx++) {
        float4 wv = *(const float4*)(&sW[(ci*16 + ky*4+kx)*TCO + cg*4]);
        const int yy = 2*r + ky;
        #pragma unroll
        for (int j=0;j<4;j++) {
          float iv = sIn[ci][yy][2*(cb4+j)+kx];
          acc[0][j] += wv.x*iv; acc[1][j] += wv.y*iv;
          acc[2][j] += wv.z*iv; acc[3][j] += wv.w*iv;
        }
      }
    }
  }
  #pragma unroll
  for (int cc=0;cc<4;cc++)
  #pragma unroll
  for (int j=0;j<4;j++) {
    float v = acc[cc][j];
    if (RELU) v = fmaxf(v, 0.f);
    y[(((long)b*COtot + co0+cg*4+cc)*Hout + oy0+r)*Wout + ox0+cb4+j] = v;
  }
}

// ---------------- conv stride1 k3 pad1 (f32) ----------------
template<int CIN, int CC, bool RELU>
__global__ __launch_bounds__(256) void conv_s1k3(
    const float* __restrict__ x, const float* __restrict__ w2,
    const float* __restrict__ bias, float* __restrict__ y,
    int H, int W, int COtot) {
  constexpr int TCO = 64;
  __shared__ __align__(16) float sIn[CC][10][12];
  __shared__ __align__(16) float sW[CC*9*TCO];
  const int tid = threadIdx.x;
  const int cogs = COtot / TCO;
  const int b = blockIdx.z / cogs, cog = blockIdx.z % cogs;
  const int co0 = cog*TCO;
  const int oy0 = blockIdx.y*8, ox0 = blockIdx.x*8;
  const int pg = tid & 15, cg = tid >> 4;
  const int r = pg >> 1, cb4 = (pg & 1)*4;
  float acc[4][4];
  #pragma unroll
  for (int cc=0;cc<4;cc++){ float bv = bias[co0+cg*4+cc];
    #pragma unroll
    for (int j=0;j<4;j++) acc[cc][j]=bv; }
  const float* xb = x + (long)b*CIN*H*W;
  for (int ci0=0; ci0<CIN; ci0+=CC) {
    __syncthreads();
    for (int t=tid; t<CC*10*10; t+=256) {
      int xx = t%10, yy=(t/10)%10, ci=t/100;
      int gy = oy0-1+yy, gx = ox0-1+xx;
      float v = 0.f;
      if (gy>=0 && gy<H && gx>=0 && gx<W) v = xb[((long)(ci0+ci)*H+gy)*W+gx];
      sIn[ci][yy][xx] = v;
    }
    const float* wsrc = w2 + (long)ci0*9*COtot + co0;
    for (int t=tid; t<CC*9*TCO; t+=256) {
      int cox = t & 63, rest = t >> 6;
      sW[t] = wsrc[(long)rest*COtot + cox];
    }
    __syncthreads();
    for (int ci=0; ci<CC; ci++) {
      #pragma unroll
      for (int ky=0;ky<3;ky++)
      #pragma unroll
      for (int kx=0;kx<3;kx++) {
        float4 wv = *(const float4*)(&sW[(ci*9 + ky*3+kx)*TCO + cg*4]);
        #pragma unroll
        for (int j=0;j<4;j++) {
          float iv = sIn[ci][r+ky][cb4+j+kx];
          acc[0][j] += wv.x*iv; acc[1][j] += wv.y*iv;
          acc[2][j] += wv.z*iv; acc[3][j] += wv.w*iv;
        }
      }
    }
  }
  #pragma unroll
  for (int cc=0;cc<4;cc++)
  #pragma unroll
  for (int j=0;j<4;j++) {
    float v = acc[cc][j];
    if (RELU) v = fmaxf(v, 0.f);
    y[(((long)b*COtot + co0+cg*4+cc)*H + oy0+r)*W + ox0+cb4+j] = v;
  }
}

// ---------------- ConvTranspose2d stride1 k3 pad1 + sigmoid, COUT=3 ----------------
template<int CIN, int CC, typename TIN>
__global__ __launch_bounds__(256) void deconv_s1k3_sig(
    const TIN* __restrict__ x, const float* __restrict__ w2,
    const float* __restrict__ bias, float* __restrict__ y, int H, int W) {
  __shared__ float sIn[CC][34][36];
  __shared__ float sW[CC*9*3];
  const int tid = threadIdx.x;
  const int b = blockIdx.z;
  const int oy0 = blockIdx.y*32, ox0 = blockIdx.x*32;
  const int r = tid >> 3, cB = (tid & 7)*4;
  float acc[3][4];
  #pragma unroll
  for (int co=0;co<3;co++){ float bv = bias[co];
    #pragma unroll
    for (int j=0;j<4;j++) acc[co][j]=bv; }
  const TIN* xb = x + (long)b*CIN*H*W;
  for (int ci0=0; ci0<CIN; ci0+=CC) {
    __syncthreads();
    for (int t=tid; t<CC*34*34; t+=256) {
      int xx = t%34, yy=(t/34)%34, ci=t/(34*34);
      int gy = oy0-1+yy, gx = ox0-1+xx;
      float v = 0.f;
      if (gy>=0 && gy<H && gx>=0 && gx<W) v = toF(xb[((long)(ci0+ci)*H+gy)*W+gx]);
      sIn[ci][yy][xx] = v;
    }
    for (int t=tid; t<CC*9*3; t+=256) sW[t] = w2[(long)ci0*9*3 + t];
    __syncthreads();
    for (int ci=0; ci<CC; ci++) {
      #pragma unroll
      for (int ky=0;ky<3;ky++)
      #pragma unroll
      for (int kx=0;kx<3;kx++) {
        const float* wp = &sW[(ci*9 + ky*3+kx)*3];
        float w0 = wp[0], w1 = wp[1], w2v = wp[2];
        const int yy = r + 2 - ky;
        #pragma unroll
        for (int j=0;j<4;j++) {
          float iv = sIn[ci][yy][cB+j+2-kx];
          acc[0][j] += w0*iv; acc[1][j] += w1*iv; acc[2][j] += w2v*iv;
        }
      }
    }
  }
  #pragma unroll
  for (int co=0;co<3;co++)
  #pragma unroll
  for (int j=0;j<4;j++) {
    float v = acc[co][j];
    v = 1.f/(1.f + expf(-v));
    y[(((long)b*3 + co)*H + oy0+r)*W + ox0+cB+j] = v;
  }
}

// ---------------- vector quantizer ----------------
__global__ __launch_bounds__(256) void vq_kernel(
    const float* __restrict__ ze, const float* __restrict__ emb,
    float* __restrict__ out_idx, float* __restrict__ zq) {
  __shared__ __align__(16) float se[128*64];
  __shared__ float sn[128];
  const int tid = threadIdx.x;
  const long n = (long)blockIdx.x*256 + tid;
  float4 rv[16];
  const float4* zr = (const float4*)(ze + n*64);
  #pragma unroll
  for (int q=0;q<16;q++) rv[q] = zr[q];
  float best = 3.4e38f; int bidx = 0;
  for (int ch=0; ch<4; ch++) {
    __syncthreads();
    #pragma unroll
    for (int i=0;i<32;i++) se[tid + i*256] = emb[ch*8192 + tid + i*256];
    __syncthreads();
    if (tid < 128) {
      float s = 0.f;
      #pragma unroll 8
      for (int d=0; d<64; d++){ float v = se[tid*64+d]; s += v*v; }
      sn[tid] = s;
    }
    __syncthreads();
    for (int k=0; k<128; k++) {
      const float4* ev = (const float4*)&se[k*64];
      float dot = 0.f;
      #pragma unroll
      for (int q=0;q<16;q++){
        float4 e4 = ev[q];
        dot += rv[q].x*e4.x + rv[q].y*e4.y + rv[q].z*e4.z + rv[q].w*e4.w;
      }
      float s = sn[k] - 2.f*dot;
      if (s < best) { best = s; bidx = ch*128 + k; }
    }
  }
  out_idx[n] = (float)bidx;
  const float4* eb = (const float4*)(emb + (long)bidx*64);
  float4* zo = (float4*)(zq + n*64);
  #pragma unroll
  for (int q=0;q<16;q++) zo[q] = eb[q];
}

// ---------------- launch ----------------
extern "C" void kernel_launch(void* const* d_in, const int* in_sizes, int n_in,
                              void* d_out, int out_size, void* d_ws, size_t ws_size,
                              hipStream_t stream) {
  const float* x   = (const float*)d_in[0];
  const float* c1w = (const float*)d_in[1];  const float* c1b = (const float*)d_in[2];
  const float* c2w = (const float*)d_in[3];  const float* c2b = (const float*)d_in[4];
  const float* c3w = (const float*)d_in[5];  const float* c3b = (const float*)d_in[6];
  const float* emb = (const float*)d_in[7];
  const float* d1w = (const float*)d_in[8];  const float* d1b = (const float*)d_in[9];
  const float* d2w = (const float*)d_in[10]; const float* d2b = (const float*)d_in[11];
  const float* d3w = (const float*)d_in[12]; const float* d3b = (const float*)d_in[13];
  float* out = (float*)d_out;

  float* xrec = out;                 // 16*3*256*256
  float* oidx = out + 3145728;       // 65536
  float* zq   = out + 3211264;       // 16*64*64*64

  const long XB  = 196608;   // 3*256*256
  const long H2B = 524288;   // 128*64*64
  const long ZEB = 262144;   // 64*64*64

  // workspace: [0,32M) h1grp / g1grp+g2grp head; [32M,64M) h2; [64M,80M) ze; then weights
  const size_t NEEDED = 86054400ULL;   // known: ws_size >= 120,395,264 (plan A ran in r2)
  if (ws_size < NEEDED) return;
  char* wsb = (char*)d_ws;
  float* h1grp = (float*)wsb;                          // 4*128*128*128 f32 = 32MB
  float* h2    = (float*)(wsb + 33554432);             // 16*128*64*64 f32 = 32MB
  float* ze    = (float*)(wsb + 67108864);             // 16MB
  unsigned short* g1grp = (unsigned short*)wsb;                 // 4*128*128*128 bf16 = 16MB
  unsigned short* g2grp = (unsigned short*)(wsb + 16777216);    // 4*128*256*256 bf16 = 64MB
  char* W = wsb + 83886080;
  float* w2c1 = (float*)(W + 0);                 // 6144 f32
  float* w2c2 = (float*)(W + 24576);             // 262144 f32
  float* w2c3 = (float*)(W + 1073152);           // 73728 f32
  float* w2d3 = (float*)(W + 1368064);           // 3456 f32
  unsigned short* w2d1 = (unsigned short*)(W + 1381888);  // 4*128*256 bf16
  unsigned short* w2d2 = (unsigned short*)(W + 1644032);  // 4*128*512 bf16

  // weight preps
  wtrans_conv  <<<24,   256, 0, stream>>>(c1w, w2c1, 128, 3,   16);
  wtrans_conv  <<<1024, 256, 0, stream>>>(c2w, w2c2, 128, 128, 16);
  wtrans_conv  <<<288,  256, 0, stream>>>(c3w, w2c3, 64,  128, 9);
  wtrans_deconv<<<14,   256, 0, stream>>>(d3w, w2d3, 128, 3,   9);
  wprep_deconv_mfma<<<512,  256, 0, stream>>>(d1w, w2d1, 64);
  wprep_deconv_mfma<<<1024, 256, 0, stream>>>(d2w, w2d2, 128);

  // encoder (f32: argmin exactness)
  for (int g = 0; g < 4; ++g) {
    conv_s2k4<3,  3, true ><<<dim3(16,16,8), 256, 0, stream>>>(
        x + (long)g*4*XB, w2c1, c1b, h1grp, 256,256,128,128, 128);
    conv_s2k4<128,8, true ><<<dim3(8, 8, 8), 256, 0, stream>>>(
        h1grp, w2c2, c2b, h2 + (long)g*4*H2B, 128,128, 64, 64, 128);
  }
  conv_s1k3<128,8, false><<<dim3(8, 8, 16), 256, 0, stream>>>(h2, w2c3, c3b, ze, 64, 64, 64);
  vq_kernel<<<256, 256, 0, stream>>>(ze, emb, oidx, zq);

  // decoder (bf16 MFMA for deconv1/2, grouped by 4 batches)
  for (int g = 0; g < 4; ++g) {
    deconv_mfma<64, 64, true ><<<dim3(64, 2, 4), 256, 0, stream>>>(
        (const void*)(zq + (long)g*4*ZEB), w2d1, d1b, g1grp);
    deconv_mfma<128,128,false><<<dim3(128,2, 4), 512, 0, stream>>>(
        (const void*)g1grp, w2d2, d2b, g2grp);
    deconv_s1k3_sig<128,8, __hip_bfloat16><<<dim3(8, 8, 4), 256, 0, stream>>>(
        (const __hip_bfloat16*)g2grp, w2d3, d3b, xrec + (long)g*4*XB, 256, 256);
  }
}

// Round 4
// 2519.015 us; speedup vs baseline: 2.3736x; 1.1341x over previous
//
#include <hip/hip_runtime.h>
#include <hip/hip_bf16.h>

#define DEV __device__ __forceinline__

typedef __attribute__((ext_vector_type(8))) short bf16x8;
typedef __attribute__((ext_vector_type(4))) float f32x4;
typedef __attribute__((ext_vector_type(4))) unsigned short u16x4;

#define MFMA16(a,b,c) __builtin_amdgcn_mfma_f32_16x16x32_bf16(a,b,c,0,0,0)

DEV float toF(float v){ return v; }
DEV float toF(__hip_bfloat16 v){ return __bfloat162float(v); }
DEV unsigned short bfbits(float v){ __hip_bfloat16 h = __float2bfloat16(v); return *(unsigned short*)&h; }
DEV float bf2f(unsigned short u){ __hip_bfloat16 h = *(__hip_bfloat16*)&u; return __bfloat162float(h); }
DEV void split3(float v, unsigned short& h, unsigned short& m, unsigned short& l) {
  h = bfbits(v);        float r  = v - bf2f(h);
  m = bfbits(r);        float r2 = r - bf2f(m);
  l = bfbits(r2);
}

// ---------------- weight reorders ----------------
__global__ __launch_bounds__(256) void wtrans_conv(const float* __restrict__ w,
    float* __restrict__ w2, int CO, int CI, int KK) {
  int i = blockIdx.x*256 + threadIdx.x;
  int total = CO*CI*KK;
  if (i >= total) return;
  int t = i % KK; int ci = (i/KK) % CI; int co = i/(KK*CI);
  w2[((long)ci*KK + t)*CO + co] = w[i];
}
__global__ __launch_bounds__(256) void wtrans_deconv(const float* __restrict__ w,
    float* __restrict__ w2, int CI, int CO, int KK) {
  int i = blockIdx.x*256 + threadIdx.x;
  int total = CI*CO*KK;
  if (i >= total) return;
  int t = i % KK; int co = (i/KK) % CO; int ci = i/(KK*CO);
  w2[((long)ci*KK + t)*CO + co] = w[i];
}
// deconv MFMA prep (unchanged from r3)
__global__ __launch_bounds__(256) void wprep_deconv_mfma(
    const float* __restrict__ w, unsigned short* __restrict__ w2, int CI) {
  const int K = CI*4;
  int i = blockIdx.x*256 + threadIdx.x;
  if (i >= 512*K) return;
  int k  = i % K;
  int co = (i / K) & 127;
  int f  = (i / (K*128)) & 1;
  int e  = i / (K*256);
  int ci = (k & 15) | ((k >> 6) << 4);
  int tap = (k >> 4) & 3, a = tap >> 1, b = tap & 1;
  float v = w[ (((long)ci*128 + co)*4 + (2*a+1-e))*4 + (2*b+1-f) ];
  w2[i] = bfbits(v);
}
// conv2 MFMA prep: src c2w[co128][ci128][4][4] -> w2[3pl][co][2048]
// k = (ci>>3)*128 + (ky*4+kx)*8 + (ci&7)
__global__ __launch_bounds__(256) void wprep_conv2_mfma(
    const float* __restrict__ w, unsigned short* __restrict__ w2) {
  int i = blockIdx.x*256 + threadIdx.x;          // 262144
  int k = i & 2047, co = i >> 11;
  int ch = k >> 7, rem = k & 127;
  int tap = rem >> 3, cil = rem & 7;
  int ci = ch*8 + cil, ky = tap >> 2, kx = tap & 3;
  float v = w[(((long)co*128 + ci)*4 + ky)*4 + kx];
  unsigned short h,m,l; split3(v,h,m,l);
  w2[i] = h; w2[i + 262144] = m; w2[i + 524288] = l;
}
// conv3 MFMA prep: src c3w[co64][ci128][3][3] -> w2[3pl][co][1536]
// k = (ci>>3)*96 + (ky*4+kx)*8 + (ci&7); kx==3 -> zero pad tap
__global__ __launch_bounds__(256) void wprep_conv3_mfma(
    const float* __restrict__ w, unsigned short* __restrict__ w2) {
  int i = blockIdx.x*256 + threadIdx.x;          // 98304
  int k = i % 1536, co = i / 1536;
  int ch = k / 96, rem = k % 96;
  int tap = rem >> 3, cil = rem & 7;
  int ci = ch*8 + cil, ky = tap >> 2, kx = tap & 3;
  float v = (kx < 3) ? w[(((long)co*128 + ci)*3 + ky)*3 + kx] : 0.f;
  unsigned short h,m,l; split3(v,h,m,l);
  w2[i] = h; w2[i + 98304] = m; w2[i + 196608] = l;
}

// ---------------- conv1: f32 direct, k4 s2 p1, CIN=3, out 3 bf16 planes ----------------
__global__ __launch_bounds__(256) void conv1_split(
    const float* __restrict__ x, const float* __restrict__ w2,
    const float* __restrict__ bias, unsigned short* __restrict__ h1, long PS1) {
  __shared__ __align__(16) float sIn[3][18][20];
  __shared__ __align__(16) float sW[3*16*64];
  const int tid = threadIdx.x;
  const int b = blockIdx.z >> 1, cog = blockIdx.z & 1;
  const int co0 = cog*64;
  const int oy0 = blockIdx.y*8, ox0 = blockIdx.x*8;
  const int pg = tid & 15, cg = tid >> 4;
  const int r = pg >> 1, cb4 = (pg & 1)*4;
  float acc[4][4];
  #pragma unroll
  for (int cc=0;cc<4;cc++){ float bv = bias[co0+cg*4+cc];
    #pragma unroll
    for (int j=0;j<4;j++) acc[cc][j]=bv; }
  const float* xb = x + (long)b*3*256*256;
  const int iy0 = 2*oy0 - 1, ix0 = 2*ox0 - 1;
  for (int t=tid; t<3*18*18; t+=256) {
    int xx = t%18, yy=(t/18)%18, ci=t/324;
    int gy = iy0+yy, gx = ix0+xx;
    float v = 0.f;
    if (gy>=0 && gy<256 && gx>=0 && gx<256) v = xb[((long)ci*256+gy)*256+gx];
    sIn[ci][yy][xx] = v;
  }
  for (int t=tid; t<3*16*64; t+=256) {
    sW[t] = w2[(long)(t>>6)*128 + co0 + (t&63)];
  }
  __syncthreads();
  for (int ci=0; ci<3; ci++) {
    #pragma unroll
    for (int ky=0;ky<4;ky++)
    #pragma unroll
    for (int kx=0;kx<4;kx++) {
      float4 wv = *(const float4*)(&sW[(ci*16 + ky*4+kx)*64 + cg*4]);
      const int yy = 2*r + ky;
      #pragma unroll
      for (int j=0;j<4;j++) {
        float iv = sIn[ci][yy][2*(cb4+j)+kx];
        acc[0][j] += wv.x*iv; acc[1][j] += wv.y*iv;
        acc[2][j] += wv.z*iv; acc[3][j] += wv.w*iv;
      }
    }
  }
  #pragma unroll
  for (int cc=0;cc<4;cc++) {
    u16x4 oh, om, ol;
    #pragma unroll
    for (int j=0;j<4;j++) {
      float v = fmaxf(acc[cc][j], 0.f);
      unsigned short h,m,l; split3(v,h,m,l);
      oh[j]=h; om[j]=m; ol[j]=l;
    }
    long base = ((long)(b*128 + co0+cg*4+cc)*128 + oy0+r)*128 + ox0+cb4;
    *(u16x4*)(h1 + base) = oh;
    *(u16x4*)(h1 + PS1 + base) = om;
    *(u16x4*)(h1 + 2*PS1 + base) = ol;
  }
}

// ---------------- conv2: MFMA 6-term split, k4 s2 p1, 128->128, 128x128 -> 64x64 ----------
// block: one output row oy, 64 co (cog), 1 batch; 256 thr = 4 waves (wr x wc)
__global__ __launch_bounds__(256) void conv2_mfma(
    const unsigned short* __restrict__ h1, long PS1,
    const unsigned short* __restrict__ w2,     // [3][128co][2048]
    const float* __restrict__ bias,
    unsigned short* __restrict__ h2, long PS2) {
  __shared__ __align__(16) unsigned short sA[8*66*24];      // [(rr*2+par)*66+col][24: h|m|l]
  __shared__ __align__(16) unsigned short sB[3*64*16*8];
  const int tid = threadIdx.x;
  const int oy = blockIdx.x, cog = blockIdx.y, b = blockIdx.z;
  const int wave = tid >> 6, lane = tid & 63;
  const int wr = wave >> 1, wc = wave & 1;
  const int col_l = lane & 15, kg = lane >> 4;
  const int kx = kg, par = (kx+1)&1, cofs = (kx+1)>>1;
  f32x4 acc[2][2] = {};
  // zero pad cols 0 and 65 (all rr, par, 24 slots) — never touched by staging
  for (int i = tid; i < 8*2*24; i += 256) {
    int j = i % 24, c = (i/24) & 1, rp = i/48;
    sA[(rp*66 + (c?65:0))*24 + j] = 0;
  }
  const int iy0 = 2*oy - 1;
  for (int ch = 0; ch < 16; ++ch) {
    __syncthreads();
    // ---- stage A: 8ci x 4rr x 128px, 3 planes; 512 units of 8px ----
    #pragma unroll
    for (int u = 0; u < 2; ++u) {
      int unit = tid + u*256;
      int li = unit & 15, rr = (unit>>4)&3, ci = unit>>6;
      int iy = iy0 + rr;
      unsigned short vh[8], vm[8], vl[8];
      if (iy >= 0 && iy < 128) {
        long go = ((long)(b*128 + ch*8 + ci)*128 + iy)*128 + li*8;
        *(uint4*)vh = *(const uint4*)(h1 + go);
        *(uint4*)vm = *(const uint4*)(h1 + PS1 + go);
        *(uint4*)vl = *(const uint4*)(h1 + 2*PS1 + go);
      } else {
        #pragma unroll
        for (int j=0;j<8;j++){ vh[j]=0; vm[j]=0; vl[j]=0; }
      }
      #pragma unroll
      for (int p = 0; p < 8; ++p) {
        int pp = (p + li) & 7;
        int ix = li*8 + pp;
        int colw = (ix>>1) + 1;
        int base = (((rr*2) + (ix&1))*66 + colw)*24 + ci;
        sA[base]      = vh[pp];
        sA[base + 8]  = vm[pp];
        sA[base + 16] = vl[pp];
      }
    }
    // ---- stage B: 3 planes x 64co x 16 slots ----
    for (int i = tid; i < 3072; i += 256) {
      int s = i & 15, co = (i>>4) & 63, pl = i >> 10;
      const unsigned short* src = w2 + ((long)pl*128 + cog*64 + co)*2048 + ch*128 + s*8;
      *(uint4*)&sB[((pl*64 + co)*16 + (s ^ (co & 15)))*8] = *(const uint4*)src;
    }
    __syncthreads();
    #pragma unroll
    for (int s = 0; s < 4; ++s) {        // slice = ky
      bf16x8 aF[2][3]; bf16x8 bF[2][3];
      const int tap = s*4 + kg;
      #pragma unroll
      for (int mf = 0; mf < 2; ++mf) {
        int ox = wr*32 + mf*16 + col_l;
        int base = ((s*2 + par)*66 + ox + cofs)*24;
        aF[mf][0] = *(const bf16x8*)&sA[base];
        aF[mf][1] = *(const bf16x8*)&sA[base+8];
        aF[mf][2] = *(const bf16x8*)&sA[base+16];
      }
      #pragma unroll
      for (int nf = 0; nf < 2; ++nf) {
        int co = wc*32 + nf*16 + col_l;
        int ba = (co*16 + (tap ^ (co&15)))*8;
        bF[nf][0] = *(const bf16x8*)&sB[ba];
        bF[nf][1] = *(const bf16x8*)&sB[ba + 8192];
        bF[nf][2] = *(const bf16x8*)&sB[ba + 16384];
      }
      #pragma unroll
      for (int mf = 0; mf < 2; ++mf)
      #pragma unroll
      for (int nf = 0; nf < 2; ++nf) {
        f32x4 a = acc[mf][nf];
        a = MFMA16(aF[mf][0], bF[nf][0], a);
        a = MFMA16(aF[mf][0], bF[nf][1], a);
        a = MFMA16(aF[mf][1], bF[nf][0], a);
        a = MFMA16(aF[mf][0], bF[nf][2], a);
        a = MFMA16(aF[mf][2], bF[nf][0], a);
        a = MFMA16(aF[mf][1], bF[nf][1], a);
        acc[mf][nf] = a;
      }
    }
  }
  // epilogue: bias + relu, split -> 3 bf16 planes
  #pragma unroll
  for (int nf = 0; nf < 2; ++nf) {
    int co = cog*64 + wc*32 + nf*16 + col_l;
    float bv = bias[co];
    #pragma unroll
    for (int mf = 0; mf < 2; ++mf) {
      int px0 = wr*32 + mf*16 + kg*4;
      u16x4 oh, om, ol;
      #pragma unroll
      for (int r = 0; r < 4; ++r) {
        float v = fmaxf(acc[mf][nf][r] + bv, 0.f);
        unsigned short h,m,l; split3(v,h,m,l);
        oh[r]=h; om[r]=m; ol[r]=l;
      }
      long base = ((long)(b*128 + co)*64 + oy)*64 + px0;
      *(u16x4*)(h2 + base) = oh;
      *(u16x4*)(h2 + PS2 + base) = om;
      *(u16x4*)(h2 + 2*PS2 + base) = ol;
    }
  }
}

// ---------------- conv3: MFMA 6-term split, k3 s1 p1, 128->64, 64x64 ----------------
// block: one output row oy, 64 co, 1 batch of 8; 256 thr = 4 waves
__global__ __launch_bounds__(256) void conv3_mfma(
    const unsigned short* __restrict__ h2, long PS2,
    const unsigned short* __restrict__ w2,     // [3][64co][1536]
    const float* __restrict__ bias, float* __restrict__ ze) {
  __shared__ __align__(16) unsigned short sA[3*67*24];
  __shared__ __align__(16) unsigned short sB[3*64*16*8];
  const int tid = threadIdx.x;
  const int oy = blockIdx.x, b = blockIdx.z;
  const int wave = tid >> 6, lane = tid & 63;
  const int wr = wave >> 1, wc = wave & 1;
  const int col_l = lane & 15, kg = lane >> 4;
  f32x4 acc[2][2] = {};
  // zero cols 0, 65, 66
  for (int i = tid; i < 3*3*24; i += 256) {
    int j = i % 24, c = (i/24) % 3, rr = i/72;
    int col = (c==0) ? 0 : (c==1 ? 65 : 66);
    sA[(rr*67 + col)*24 + j] = 0;
  }
  for (int ch = 0; ch < 16; ++ch) {
    __syncthreads();
    // stage A: 8ci x 3rr x 64px = 192 units of 8px
    {
      int unit = tid;
      if (unit < 192) {
        int li = unit & 7, rr = (unit>>3)%3, ci = unit/24;
        int iy = oy + rr - 1;
        unsigned short vh[8], vm[8], vl[8];
        if (iy >= 0 && iy < 64) {
          long go = ((long)(b*128 + ch*8 + ci)*64 + iy)*64 + li*8;
          *(uint4*)vh = *(const uint4*)(h2 + go);
          *(uint4*)vm = *(const uint4*)(h2 + PS2 + go);
          *(uint4*)vl = *(const uint4*)(h2 + 2*PS2 + go);
        } else {
          #pragma unroll
          for (int j=0;j<8;j++){ vh[j]=0; vm[j]=0; vl[j]=0; }
        }
        #pragma unroll
        for (int p = 0; p < 8; ++p) {
          int pp = (p + li) & 7;
          int col = li*8 + pp + 1;
          int base = (rr*67 + col)*24 + ci;
          sA[base]      = vh[pp];
          sA[base + 8]  = vm[pp];
          sA[base + 16] = vl[pp];
        }
      }
    }
    // stage B: 3 planes x 64co x 12 taps
    for (int i = tid; i < 2304; i += 256) {
      int s = i % 12, co = (i/12) & 63, pl = i/768;
      const unsigned short* src = w2 + ((long)pl*64 + co)*1536 + ch*96 + s*8;
      *(uint4*)&sB[((pl*64 + co)*16 + (s ^ (co & 15)))*8] = *(const uint4*)src;
    }
    __syncthreads();
    #pragma unroll
    for (int s = 0; s < 3; ++s) {        // slice = ky
      bf16x8 aF[2][3]; bf16x8 bF[2][3];
      const int tap = s*4 + kg;
      #pragma unroll
      for (int mf = 0; mf < 2; ++mf) {
        int ox = wr*32 + mf*16 + col_l;
        int base = (s*67 + ox + kg)*24;
        aF[mf][0] = *(const bf16x8*)&sA[base];
        aF[mf][1] = *(const bf16x8*)&sA[base+8];
        aF[mf][2] = *(const bf16x8*)&sA[base+16];
      }
      #pragma unroll
      for (int nf = 0; nf < 2; ++nf) {
        int co = wc*32 + nf*16 + col_l;
        int ba = (co*16 + (tap ^ (co&15)))*8;
        bF[nf][0] = *(const bf16x8*)&sB[ba];
        bF[nf][1] = *(const bf16x8*)&sB[ba + 8192];
        bF[nf][2] = *(const bf16x8*)&sB[ba + 16384];
      }
      #pragma unroll
      for (int mf = 0; mf < 2; ++mf)
      #pragma unroll
      for (int nf = 0; nf < 2; ++nf) {
        f32x4 a = acc[mf][nf];
        a = MFMA16(aF[mf][0], bF[nf][0], a);
        a = MFMA16(aF[mf][0], bF[nf][1], a);
        a = MFMA16(aF[mf][1], bF[nf][0], a);
        a = MFMA16(aF[mf][0], bF[nf][2], a);
        a = MFMA16(aF[mf][2], bF[nf][0], a);
        a = MFMA16(aF[mf][1], bF[nf][1], a);
        acc[mf][nf] = a;
      }
    }
  }
  // epilogue: + bias, f32 out
  #pragma unroll
  for (int nf = 0; nf < 2; ++nf) {
    int co = wc*32 + nf*16 + col_l;
    float bv = bias[co];
    #pragma unroll
    for (int mf = 0; mf < 2; ++mf) {
      int px0 = wr*32 + mf*16 + kg*4;
      float4 o;
      o.x = acc[mf][nf][0] + bv; o.y = acc[mf][nf][1] + bv;
      o.z = acc[mf][nf][2] + bv; o.w = acc[mf][nf][3] + bv;
      *(float4*)(ze + ((long)(b*64 + co)*64 + oy)*64 + px0) = o;
    }
  }
}

// ---------------- MFMA ConvTranspose2d stride2 k4 pad1 (unchanged from r3) ----------------
template<int CIN, int TX, bool IN_F32>
struct SmemT {
  union {
    struct {
      __align__(16) unsigned short In[2][TX+2][24];
      __align__(16) unsigned short W[2][128][64];
    };
    __align__(16) unsigned short Out[128][2*TX];
  };
};

template<int CIN, int TX, bool IN_F32>
__global__ __launch_bounds__(TX*4, 4) void deconv_mfma(
    const void* __restrict__ xin, const unsigned short* __restrict__ w2,
    const float* __restrict__ bias, unsigned short* __restrict__ y) {
  constexpr int NTHR = TX*4;
  constexpr int K    = CIN*4;
  constexpr int TPR  = NTHR/32;
  __shared__ SmemT<CIN,TX,IN_F32> sm;

  const int tid = threadIdx.x;
  const int ty = blockIdx.x, e = blockIdx.y, b = blockIdx.z;
  const int wave = tid >> 6, lane = tid & 63;
  const int wc = wave & 1, wr = wave >> 1;
  const int f = (wr*64) / TX;
  const int tx_base = (wr*64) & (TX-1);
  const int col_l = lane & 15, kg = lane >> 4;

  if (tid < 64) {
    int rr = tid & 1, cc = ((tid>>1)&1) ? TX+1 : 0, ci = tid >> 2;
    sm.In[rr][cc][ci] = 0;
  }

  f32x4 acc[4][4] = {};
  const int rowid = tid / TPR, li = tid % TPR;
  const int sci = rowid >> 1, srr = rowid & 1;
  const int iy = ty + e - 1 + srr;

  for (int ch = 0; ch < CIN/16; ++ch) {
    __syncthreads();
    {
      unsigned short vals[8];
      if (iy >= 0 && iy < TX) {
        long gofs = ((long)b*CIN + ch*16 + sci)*TX*TX + (long)iy*TX + li*8;
        if (IN_F32) {
          const float4* s4 = (const float4*)((const float*)xin + gofs);
          float4 lo = s4[0], hi = s4[1];
          vals[0]=bfbits(lo.x); vals[1]=bfbits(lo.y); vals[2]=bfbits(lo.z); vals[3]=bfbits(lo.w);
          vals[4]=bfbits(hi.x); vals[5]=bfbits(hi.y); vals[6]=bfbits(hi.z); vals[7]=bfbits(hi.w);
        } else {
          bf16x8 v = *(const bf16x8*)((const unsigned short*)xin + gofs);
          #pragma unroll
          for (int j=0;j<8;j++) vals[j] = ((unsigned short)v[j]);
        }
      } else {
        #pragma unroll
        for (int j=0;j<8;j++) vals[j] = 0;
      }
      #pragma unroll
      for (int j=0;j<8;j++) {
        int jj = (j + li) & 7;
        sm.In[srr][1 + li*8 + jj][sci] = vals[jj];
      }
    }
    for (int i = tid; i < 2048; i += NTHR) {
      int s = i & 7, co = (i >> 3) & 127, ff = i >> 10;
      const unsigned short* src = w2 + ((long)((e*2+ff)*128 + co))*K + ch*64 + s*8;
      *(uint4*)&sm.W[ff][co][(s ^ (co & 7))*8] = *(const uint4*)src;
    }
    __syncthreads();
    #pragma unroll
    for (int kk = 0; kk < 2; ++kk) {
      bf16x8 aF[4];
      const int tap = kk*2 + (kg >> 1), a = tap >> 1, bb = tap & 1;
      const int cib = (kg & 1)*8;
      #pragma unroll
      for (int mf = 0; mf < 4; ++mf) {
        int tx = tx_base + mf*16 + col_l;
        aF[mf] = *(const bf16x8*)&sm.In[1-a][tx + 1 + f - bb][cib];
      }
      const int slot = kk*4 + kg;
      #pragma unroll
      for (int nf = 0; nf < 4; ++nf) {
        int co_l = nf*16 + col_l;
        bf16x8 bF = *(const bf16x8*)&sm.W[f][wc*64 + co_l][(slot ^ (co_l & 7))*8];
        #pragma unroll
        for (int mf = 0; mf < 4; ++mf)
          acc[mf][nf] = MFMA16(aF[mf], bF, acc[mf][nf]);
      }
    }
  }

  __syncthreads();
  float bv[4];
  #pragma unroll
  for (int nf = 0; nf < 4; ++nf) bv[nf] = bias[wc*64 + nf*16 + col_l];
  #pragma unroll
  for (int mf = 0; mf < 4; ++mf)
  #pragma unroll
  for (int nf = 0; nf < 4; ++nf) {
    int co = wc*64 + nf*16 + col_l;
    #pragma unroll
    for (int r = 0; r < 4; ++r) {
      int tx = tx_base + mf*16 + kg*4 + r;
      float v = fmaxf(acc[mf][nf][r] + bv[nf], 0.f);
      int ox = 2*tx + f;
      sm.Out[co][ox ^ ((co & 15)*8)] = bfbits(v);
    }
  }
  __syncthreads();
  constexpr int CH = 2*TX/8;
  const int oy = 2*ty + e;
  for (int i = tid; i < 128*CH; i += NTHR) {
    int co = i / CH, cx = i % CH;
    uint4 v = *(const uint4*)&sm.Out[co][(cx ^ (co & 15))*8];
    *(uint4*)(y + (((long)b*128 + co)*(2*TX) + oy)*(long)(2*TX) + cx*8) = v;
  }
}

// ---------------- ConvTranspose2d s1k3 + sigmoid, COUT=3 (unchanged) ----------------
template<int CIN, int CC, typename TIN>
__global__ __launch_bounds__(256) void deconv_s1k3_sig(
    const TIN* __restrict__ x, const float* __restrict__ w2,
    const float* __restrict__ bias, float* __restrict__ y, int H, int W) {
  __shared__ float sIn[CC][34][36];
  __shared__ float sW[CC*9*3];
  const int tid = threadIdx.x;
  const int b = blockIdx.z;
  const int oy0 = blockIdx.y*32, ox0 = blockIdx.x*32;
  const int r = tid >> 3, cB = (tid & 7)*4;
  float acc[3][4];
  #pragma unroll
  for (int co=0;co<3;co++){ float bv = bias[co];
    #pragma unroll
    for (int j=0;j<4;j++) acc[co][j]=bv; }
  const TIN* xb = x + (long)b*CIN*H*W;
  for (int ci0=0; ci0<CIN; ci0+=CC) {
    __syncthreads();
    for (int t=tid; t<CC*34*34; t+=256) {
      int xx = t%34, yy=(t/34)%34, ci=t/(34*34);
      int gy = oy0-1+yy, gx = ox0-1+xx;
      float v = 0.f;
      if (gy>=0 && gy<H && gx>=0 && gx<W) v = toF(xb[((long)(ci0+ci)*H+gy)*W+gx]);
      sIn[ci][yy][xx] = v;
    }
    for (int t=tid; t<CC*9*3; t+=256) sW[t] = w2[(long)ci0*9*3 + t];
    __syncthreads();
    for (int ci=0; ci<CC; ci++) {
      #pragma unroll
      for (int ky=0;ky<3;ky++)
      #pragma unroll
      for (int kx=0;kx<3;kx++) {
        const float* wp = &sW[(ci*9 + ky*3+kx)*3];
        float w0 = wp[0], w1 = wp[1], w2v = wp[2];
        const int yy = r + 2 - ky;
        #pragma unroll
        for (int j=0;j<4;j++) {
          float iv = sIn[ci][yy][cB+j+2-kx];
          acc[0][j] += w0*iv; acc[1][j] += w1*iv; acc[2][j] += w2v*iv;
        }
      }
    }
  }
  #pragma unroll
  for (int co=0;co<3;co++)
  #pragma unroll
  for (int j=0;j<4;j++) {
    float v = acc[co][j];
    v = 1.f/(1.f + expf(-v));
    y[(((long)b*3 + co)*H + oy0+r)*W + ox0+cB+j] = v;
  }
}

// ---------------- vector quantizer: 4 threads/row, 16 waves/CU ----------------
__global__ __launch_bounds__(256, 4) void vq_kernel(
    const float* __restrict__ ze, const float* __restrict__ emb,
    float* __restrict__ out_idx, float* __restrict__ zq) {
  __shared__ __align__(16) float se[128][68];
  __shared__ float sn[128];
  const int tid = threadIdx.x;
  const int row = tid >> 2, sub = tid & 3;
  const long n = (long)blockIdx.x*64 + row;
  float4 rv[16];
  const float4* zr = (const float4*)(ze + n*64);
  #pragma unroll
  for (int q=0;q<16;q++) rv[q] = zr[q];
  float best = 3.4e38f; int bidx = 0;
  for (int ch=0; ch<4; ch++) {
    __syncthreads();
    for (int i = tid; i < 2048; i += 256) {
      int k = i >> 4, q = i & 15;
      *(float4*)&se[k][q*4] = *(const float4*)(emb + ((long)ch*128 + k)*64 + q*4);
    }
    __syncthreads();
    if (tid < 128) {
      float s = 0.f;
      const float4* ev = (const float4*)&se[tid][0];
      #pragma unroll
      for (int q=0;q<16;q++){ float4 e4 = ev[q];
        s += e4.x*e4.x + e4.y*e4.y + e4.z*e4.z + e4.w*e4.w; }
      sn[tid] = s;
    }
    __syncthreads();
    for (int kk = 0; kk < 32; ++kk) {
      int k = kk*4 + sub;
      const float4* ev = (const float4*)&se[k][0];
      float dot = 0.f;
      #pragma unroll
      for (int q=0;q<16;q++){
        float4 e4 = ev[q];
        dot += rv[q].x*e4.x + rv[q].y*e4.y + rv[q].z*e4.z + rv[q].w*e4.w;
      }
      float s = sn[k] - 2.f*dot;
      if (s < best) { best = s; bidx = ch*128 + k; }
    }
  }
  #pragma unroll
  for (int off = 1; off < 4; off <<= 1) {
    float ob = __shfl_xor(best, off);
    int oi = __shfl_xor(bidx, off);
    if (ob < best || (ob == best && oi < bidx)) { best = ob; bidx = oi; }
  }
  if (sub == 0) out_idx[n] = (float)bidx;
  const float4* eb = (const float4*)(emb + (long)bidx*64);
  float4* zo = (float4*)(zq + n*64);
  #pragma unroll
  for (int q=0;q<4;q++) zo[sub*4+q] = eb[sub*4+q];
}

// ---------------- launch ----------------
extern "C" void kernel_launch(void* const* d_in, const int* in_sizes, int n_in,
                              void* d_out, int out_size, void* d_ws, size_t ws_size,
                              hipStream_t stream) {
  const float* x   = (const float*)d_in[0];
  const float* c1w = (const float*)d_in[1];  const float* c1b = (const float*)d_in[2];
  const float* c2w = (const float*)d_in[3];  const float* c2b = (const float*)d_in[4];
  const float* c3w = (const float*)d_in[5];  const float* c3b = (const float*)d_in[6];
  const float* emb = (const float*)d_in[7];
  const float* d1w = (const float*)d_in[8];  const float* d1b = (const float*)d_in[9];
  const float* d2w = (const float*)d_in[10]; const float* d2b = (const float*)d_in[11];
  const float* d3w = (const float*)d_in[12]; const float* d3b = (const float*)d_in[13];
  float* out = (float*)d_out;

  float* xrec = out;                 // 16*3*256*256
  float* oidx = out + 3145728;       // 65536
  float* zq   = out + 3211264;       // 16*64*64*64

  const long XB  = 196608;   // 3*256*256
  const long ZEB = 262144;   // 64*64*64
  const long PS1 = 8388608;  // 4b*128*128*128 (elems, per plane)
  const long PS2 = 4194304;  // 8b*128*64*64

  const size_t NEEDED = 112039424ULL;  // known: ws_size >= 120,395,264
  if (ws_size < NEEDED) return;
  char* wsb = (char*)d_ws;
  // R1 [0,64M): h1grp 3-plane (50.3MB) / g2grp (64MB)
  unsigned short* h1grp = (unsigned short*)wsb;
  unsigned short* g2grp = (unsigned short*)wsb;
  // R2 [64M, 88M): h2grp8 3-plane (24MB) / g1grp (16MB)
  unsigned short* h2grp = (unsigned short*)(wsb + 67108864);
  unsigned short* g1grp = (unsigned short*)(wsb + 67108864);
  // ze [88M, 104M)
  float* ze = (float*)(wsb + 92274688);
  // weights
  char* W = wsb + 109051904;
  float* w2c1          = (float*)(W);                       // 6144 f32
  unsigned short* w2c2 = (unsigned short*)(W + 24576);      // 3*262144 bf16
  unsigned short* w2c3 = (unsigned short*)(W + 1597440);    // 3*98304 bf16
  unsigned short* w2d1 = (unsigned short*)(W + 2187264);    // 131072 bf16
  unsigned short* w2d2 = (unsigned short*)(W + 2449408);    // 262144 bf16
  float* w2d3          = (float*)(W + 2973696);             // 3456 f32

  // weight preps
  wtrans_conv      <<<24,   256, 0, stream>>>(c1w, w2c1, 128, 3, 16);
  wprep_conv2_mfma <<<1024, 256, 0, stream>>>(c2w, w2c2);
  wprep_conv3_mfma <<<384,  256, 0, stream>>>(c3w, w2c3);
  wprep_deconv_mfma<<<512,  256, 0, stream>>>(d1w, w2d1, 64);
  wprep_deconv_mfma<<<1024, 256, 0, stream>>>(d2w, w2d2, 128);
  wtrans_deconv    <<<14,   256, 0, stream>>>(d3w, w2d3, 128, 3, 9);

  // encoder
  for (int g = 0; g < 4; ++g) {
    conv1_split<<<dim3(16,16,8), 256, 0, stream>>>(
        x + (long)g*4*XB, w2c1, c1b, h1grp, PS1);
    conv2_mfma<<<dim3(64,2,4), 256, 0, stream>>>(
        h1grp, PS1, w2c2, c2b, h2grp + (long)(g&1)*4*524288, PS2);
    if (g & 1)
      conv3_mfma<<<dim3(64,1,8), 256, 0, stream>>>(
          h2grp, PS2, w2c3, c3b, ze + (long)(g>>1)*8*ZEB);
  }
  vq_kernel<<<1024, 256, 0, stream>>>(ze, emb, oidx, zq);

  // decoder
  for (int g = 0; g < 4; ++g) {
    deconv_mfma<64, 64, true ><<<dim3(64, 2, 4), 256, 0, stream>>>(
        (const void*)(zq + (long)g*4*ZEB), w2d1, d1b, g1grp);
    deconv_mfma<128,128,false><<<dim3(128,2,4), 512, 0, stream>>>(
        (const void*)g1grp, w2d2, d2b, g2grp);
    deconv_s1k3_sig<128,8, __hip_bfloat16><<<dim3(8,8,4), 256, 0, stream>>>(
        (const __hip_bfloat16*)g2grp, w2d3, d3b, xrec + (long)g*4*XB, 256, 256);
  }
}

// Round 5
// 1780.928 us; speedup vs baseline: 3.3573x; 1.4144x over previous
//
#include <hip/hip_runtime.h>
#include <hip/hip_bf16.h>

#define DEV __device__ __forceinline__

typedef __attribute__((ext_vector_type(8))) short bf16x8;
typedef __attribute__((ext_vector_type(4))) float f32x4;
typedef __attribute__((ext_vector_type(4))) unsigned short u16x4;

#define MFMA16(a,b,c) __builtin_amdgcn_mfma_f32_16x16x32_bf16(a,b,c,0,0,0)

DEV float toF(float v){ return v; }
DEV float toF(__hip_bfloat16 v){ return __bfloat162float(v); }
DEV unsigned short bfbits(float v){ __hip_bfloat16 h = __float2bfloat16(v); return *(unsigned short*)&h; }
DEV float bf2f(unsigned short u){ __hip_bfloat16 h = *(__hip_bfloat16*)&u; return __bfloat162float(h); }
DEV void split3(float v, unsigned short& h, unsigned short& m, unsigned short& l) {
  h = bfbits(v);        float r  = v - bf2f(h);
  m = bfbits(r);        float r2 = r - bf2f(m);
  l = bfbits(r2);
}

// ---------------- weight reorders ----------------
__global__ __launch_bounds__(256) void wtrans_conv(const float* __restrict__ w,
    float* __restrict__ w2, int CO, int CI, int KK) {
  int i = blockIdx.x*256 + threadIdx.x;
  int total = CO*CI*KK;
  if (i >= total) return;
  int t = i % KK; int ci = (i/KK) % CI; int co = i/(KK*CI);
  w2[((long)ci*KK + t)*CO + co] = w[i];
}
// deconv1/2 MFMA prep
__global__ __launch_bounds__(256) void wprep_deconv_mfma(
    const float* __restrict__ w, unsigned short* __restrict__ w2, int CI) {
  const int K = CI*4;
  int i = blockIdx.x*256 + threadIdx.x;
  if (i >= 512*K) return;
  int k  = i % K;
  int co = (i / K) & 127;
  int f  = (i / (K*128)) & 1;
  int e  = i / (K*256);
  int ci = (k & 15) | ((k >> 6) << 4);
  int tap = (k >> 4) & 3, a = tap >> 1, b = tap & 1;
  float v = w[ (((long)ci*128 + co)*4 + (2*a+1-e))*4 + (2*b+1-f) ];
  w2[i] = bfbits(v);
}
// conv2 MFMA prep: src c2w[co128][ci128][4][4] -> w2[3pl][co][2048]
__global__ __launch_bounds__(256) void wprep_conv2_mfma(
    const float* __restrict__ w, unsigned short* __restrict__ w2) {
  int i = blockIdx.x*256 + threadIdx.x;          // 262144
  int k = i & 2047, co = i >> 11;
  int ch = k >> 7, rem = k & 127;
  int tap = rem >> 3, cil = rem & 7;
  int ci = ch*8 + cil, ky = tap >> 2, kx = tap & 3;
  float v = w[(((long)co*128 + ci)*4 + ky)*4 + kx];
  unsigned short h,m,l; split3(v,h,m,l);
  w2[i] = h; w2[i + 262144] = m; w2[i + 524288] = l;
}
// conv3 MFMA prep: src c3w[co64][ci128][3][3] -> w2[3pl][co][1536]
__global__ __launch_bounds__(256) void wprep_conv3_mfma(
    const float* __restrict__ w, unsigned short* __restrict__ w2) {
  int i = blockIdx.x*256 + threadIdx.x;          // 98304
  int k = i % 1536, co = i / 1536;
  int ch = k / 96, rem = k % 96;
  int tap = rem >> 3, cil = rem & 7;
  int ci = ch*8 + cil, ky = tap >> 2, kx = tap & 3;
  float v = (kx < 3) ? w[(((long)co*128 + ci)*3 + ky)*3 + kx] : 0.f;
  unsigned short h,m,l; split3(v,h,m,l);
  w2[i] = h; w2[i + 98304] = m; w2[i + 196608] = l;
}
// deconv3 MFMA prep: src d3w[ci128][co3][3][3] -> w2[co16][1536] bf16
// k = ch*96 + tap*8 + cil; tap=(ky,kx) with kx==3 or co>=3 -> 0
__global__ __launch_bounds__(256) void wprep_deconv3_mfma(
    const float* __restrict__ w, unsigned short* __restrict__ w2) {
  int i = blockIdx.x*256 + threadIdx.x;          // 24576
  if (i >= 24576) return;
  int k = i % 1536, co = i / 1536;
  int ch = k / 96, rem = k % 96;
  int tap = rem >> 3, cil = rem & 7;
  int ci = ch*8 + cil, ky = tap >> 2, kx = tap & 3;
  float v = (co < 3 && kx < 3) ? w[(((long)ci*3 + co)*3 + ky)*3 + kx] : 0.f;
  w2[i] = bfbits(v);
}

// ---------------- conv1: f32 direct, k4 s2 p1, CIN=3, out 3 bf16 planes ----------------
__global__ __launch_bounds__(256) void conv1_split(
    const float* __restrict__ x, const float* __restrict__ w2,
    const float* __restrict__ bias, unsigned short* __restrict__ h1, long PS1) {
  __shared__ __align__(16) float sIn[3][18][20];
  __shared__ __align__(16) float sW[3*16*64];
  const int tid = threadIdx.x;
  const int b = blockIdx.z >> 1, cog = blockIdx.z & 1;
  const int co0 = cog*64;
  const int oy0 = blockIdx.y*8, ox0 = blockIdx.x*8;
  const int pg = tid & 15, cg = tid >> 4;
  const int r = pg >> 1, cb4 = (pg & 1)*4;
  float acc[4][4];
  #pragma unroll
  for (int cc=0;cc<4;cc++){ float bv = bias[co0+cg*4+cc];
    #pragma unroll
    for (int j=0;j<4;j++) acc[cc][j]=bv; }
  const float* xb = x + (long)b*3*256*256;
  const int iy0 = 2*oy0 - 1, ix0 = 2*ox0 - 1;
  for (int t=tid; t<3*18*18; t+=256) {
    int xx = t%18, yy=(t/18)%18, ci=t/324;
    int gy = iy0+yy, gx = ix0+xx;
    float v = 0.f;
    if (gy>=0 && gy<256 && gx>=0 && gx<256) v = xb[((long)ci*256+gy)*256+gx];
    sIn[ci][yy][xx] = v;
  }
  for (int t=tid; t<3*16*64; t+=256) {
    sW[t] = w2[(long)(t>>6)*128 + co0 + (t&63)];
  }
  __syncthreads();
  for (int ci=0; ci<3; ci++) {
    #pragma unroll
    for (int ky=0;ky<4;ky++)
    #pragma unroll
    for (int kx=0;kx<4;kx++) {
      float4 wv = *(const float4*)(&sW[(ci*16 + ky*4+kx)*64 + cg*4]);
      const int yy = 2*r + ky;
      #pragma unroll
      for (int j=0;j<4;j++) {
        float iv = sIn[ci][yy][2*(cb4+j)+kx];
        acc[0][j] += wv.x*iv; acc[1][j] += wv.y*iv;
        acc[2][j] += wv.z*iv; acc[3][j] += wv.w*iv;
      }
    }
  }
  #pragma unroll
  for (int cc=0;cc<4;cc++) {
    u16x4 oh, om, ol;
    #pragma unroll
    for (int j=0;j<4;j++) {
      float v = fmaxf(acc[cc][j], 0.f);
      unsigned short h,m,l; split3(v,h,m,l);
      oh[j]=h; om[j]=m; ol[j]=l;
    }
    long base = ((long)(b*128 + co0+cg*4+cc)*128 + oy0+r)*128 + ox0+cb4;
    *(u16x4*)(h1 + base) = oh;
    *(u16x4*)(h1 + PS1 + base) = om;
    *(u16x4*)(h1 + 2*PS1 + base) = ol;
  }
}

// ---------------- conv2: MFMA 6-term split, k4 s2 p1, 128->128 ----------
__global__ __launch_bounds__(256) void conv2_mfma(
    const unsigned short* __restrict__ h1, long PS1,
    const unsigned short* __restrict__ w2,
    const float* __restrict__ bias,
    unsigned short* __restrict__ h2, long PS2) {
  __shared__ __align__(16) unsigned short sA[8*66*24];
  __shared__ __align__(16) unsigned short sB[3*64*16*8];
  const int tid = threadIdx.x;
  const int oy = blockIdx.x, cog = blockIdx.y, b = blockIdx.z;
  const int wave = tid >> 6, lane = tid & 63;
  const int wr = wave >> 1, wc = wave & 1;
  const int col_l = lane & 15, kg = lane >> 4;
  const int kx = kg, par = (kx+1)&1, cofs = (kx+1)>>1;
  f32x4 acc[2][2] = {};
  for (int i = tid; i < 8*2*24; i += 256) {
    int j = i % 24, c = (i/24) & 1, rp = i/48;
    sA[(rp*66 + (c?65:0))*24 + j] = 0;
  }
  const int iy0 = 2*oy - 1;
  for (int ch = 0; ch < 16; ++ch) {
    __syncthreads();
    #pragma unroll
    for (int u = 0; u < 2; ++u) {
      int unit = tid + u*256;
      int li = unit & 15, rr = (unit>>4)&3, ci = unit>>6;
      int iy = iy0 + rr;
      unsigned short vh[8], vm[8], vl[8];
      if (iy >= 0 && iy < 128) {
        long go = ((long)(b*128 + ch*8 + ci)*128 + iy)*128 + li*8;
        *(uint4*)vh = *(const uint4*)(h1 + go);
        *(uint4*)vm = *(const uint4*)(h1 + PS1 + go);
        *(uint4*)vl = *(const uint4*)(h1 + 2*PS1 + go);
      } else {
        #pragma unroll
        for (int j=0;j<8;j++){ vh[j]=0; vm[j]=0; vl[j]=0; }
      }
      #pragma unroll
      for (int p = 0; p < 8; ++p) {
        int pp = (p + li) & 7;
        int ix = li*8 + pp;
        int colw = (ix>>1) + 1;
        int base = (((rr*2) + (ix&1))*66 + colw)*24 + ci;
        sA[base]      = vh[pp];
        sA[base + 8]  = vm[pp];
        sA[base + 16] = vl[pp];
      }
    }
    for (int i = tid; i < 3072; i += 256) {
      int s = i & 15, co = (i>>4) & 63, pl = i >> 10;
      const unsigned short* src = w2 + ((long)pl*128 + cog*64 + co)*2048 + ch*128 + s*8;
      *(uint4*)&sB[((pl*64 + co)*16 + (s ^ (co & 15)))*8] = *(const uint4*)src;
    }
    __syncthreads();
    #pragma unroll
    for (int s = 0; s < 4; ++s) {
      bf16x8 aF[2][3]; bf16x8 bF[2][3];
      const int tap = s*4 + kg;
      #pragma unroll
      for (int mf = 0; mf < 2; ++mf) {
        int ox = wr*32 + mf*16 + col_l;
        int base = ((s*2 + par)*66 + ox + cofs)*24;
        aF[mf][0] = *(const bf16x8*)&sA[base];
        aF[mf][1] = *(const bf16x8*)&sA[base+8];
        aF[mf][2] = *(const bf16x8*)&sA[base+16];
      }
      #pragma unroll
      for (int nf = 0; nf < 2; ++nf) {
        int co = wc*32 + nf*16 + col_l;
        int ba = (co*16 + (tap ^ (co&15)))*8;
        bF[nf][0] = *(const bf16x8*)&sB[ba];
        bF[nf][1] = *(const bf16x8*)&sB[ba + 8192];
        bF[nf][2] = *(const bf16x8*)&sB[ba + 16384];
      }
      #pragma unroll
      for (int mf = 0; mf < 2; ++mf)
      #pragma unroll
      for (int nf = 0; nf < 2; ++nf) {
        f32x4 a = acc[mf][nf];
        a = MFMA16(aF[mf][0], bF[nf][0], a);
        a = MFMA16(aF[mf][0], bF[nf][1], a);
        a = MFMA16(aF[mf][1], bF[nf][0], a);
        a = MFMA16(aF[mf][0], bF[nf][2], a);
        a = MFMA16(aF[mf][2], bF[nf][0], a);
        a = MFMA16(aF[mf][1], bF[nf][1], a);
        acc[mf][nf] = a;
      }
    }
  }
  #pragma unroll
  for (int nf = 0; nf < 2; ++nf) {
    int co = cog*64 + wc*32 + nf*16 + col_l;
    float bv = bias[co];
    #pragma unroll
    for (int mf = 0; mf < 2; ++mf) {
      int px0 = wr*32 + mf*16 + kg*4;
      u16x4 oh, om, ol;
      #pragma unroll
      for (int r = 0; r < 4; ++r) {
        float v = fmaxf(acc[mf][nf][r] + bv, 0.f);
        unsigned short h,m,l; split3(v,h,m,l);
        oh[r]=h; om[r]=m; ol[r]=l;
      }
      long base = ((long)(b*128 + co)*64 + oy)*64 + px0;
      *(u16x4*)(h2 + base) = oh;
      *(u16x4*)(h2 + PS2 + base) = om;
      *(u16x4*)(h2 + 2*PS2 + base) = ol;
    }
  }
}

// ---------------- conv3: MFMA 6-term split, k3 s1 p1, 128->64 ----------------
__global__ __launch_bounds__(256) void conv3_mfma(
    const unsigned short* __restrict__ h2, long PS2,
    const unsigned short* __restrict__ w2,
    const float* __restrict__ bias, float* __restrict__ ze) {
  __shared__ __align__(16) unsigned short sA[3*67*24];
  __shared__ __align__(16) unsigned short sB[3*64*16*8];
  const int tid = threadIdx.x;
  const int oy = blockIdx.x, b = blockIdx.z;
  const int wave = tid >> 6, lane = tid & 63;
  const int wr = wave >> 1, wc = wave & 1;
  const int col_l = lane & 15, kg = lane >> 4;
  f32x4 acc[2][2] = {};
  for (int i = tid; i < 3*3*24; i += 256) {
    int j = i % 24, c = (i/24) % 3, rr = i/72;
    int col = (c==0) ? 0 : (c==1 ? 65 : 66);
    sA[(rr*67 + col)*24 + j] = 0;
  }
  for (int ch = 0; ch < 16; ++ch) {
    __syncthreads();
    {
      int unit = tid;
      if (unit < 192) {
        int li = unit & 7, rr = (unit>>3)%3, ci = unit/24;
        int iy = oy + rr - 1;
        unsigned short vh[8], vm[8], vl[8];
        if (iy >= 0 && iy < 64) {
          long go = ((long)(b*128 + ch*8 + ci)*64 + iy)*64 + li*8;
          *(uint4*)vh = *(const uint4*)(h2 + go);
          *(uint4*)vm = *(const uint4*)(h2 + PS2 + go);
          *(uint4*)vl = *(const uint4*)(h2 + 2*PS2 + go);
        } else {
          #pragma unroll
          for (int j=0;j<8;j++){ vh[j]=0; vm[j]=0; vl[j]=0; }
        }
        #pragma unroll
        for (int p = 0; p < 8; ++p) {
          int pp = (p + li) & 7;
          int col = li*8 + pp + 1;
          int base = (rr*67 + col)*24 + ci;
          sA[base]      = vh[pp];
          sA[base + 8]  = vm[pp];
          sA[base + 16] = vl[pp];
        }
      }
    }
    for (int i = tid; i < 2304; i += 256) {
      int s = i % 12, co = (i/12) & 63, pl = i/768;
      const unsigned short* src = w2 + ((long)pl*64 + co)*1536 + ch*96 + s*8;
      *(uint4*)&sB[((pl*64 + co)*16 + (s ^ (co & 15)))*8] = *(const uint4*)src;
    }
    __syncthreads();
    #pragma unroll
    for (int s = 0; s < 3; ++s) {
      bf16x8 aF[2][3]; bf16x8 bF[2][3];
      const int tap = s*4 + kg;
      #pragma unroll
      for (int mf = 0; mf < 2; ++mf) {
        int ox = wr*32 + mf*16 + col_l;
        int base = (s*67 + ox + kg)*24;
        aF[mf][0] = *(const bf16x8*)&sA[base];
        aF[mf][1] = *(const bf16x8*)&sA[base+8];
        aF[mf][2] = *(const bf16x8*)&sA[base+16];
      }
      #pragma unroll
      for (int nf = 0; nf < 2; ++nf) {
        int co = wc*32 + nf*16 + col_l;
        int ba = (co*16 + (tap ^ (co&15)))*8;
        bF[nf][0] = *(const bf16x8*)&sB[ba];
        bF[nf][1] = *(const bf16x8*)&sB[ba + 8192];
        bF[nf][2] = *(const bf16x8*)&sB[ba + 16384];
      }
      #pragma unroll
      for (int mf = 0; mf < 2; ++mf)
      #pragma unroll
      for (int nf = 0; nf < 2; ++nf) {
        f32x4 a = acc[mf][nf];
        a = MFMA16(aF[mf][0], bF[nf][0], a);
        a = MFMA16(aF[mf][0], bF[nf][1], a);
        a = MFMA16(aF[mf][1], bF[nf][0], a);
        a = MFMA16(aF[mf][0], bF[nf][2], a);
        a = MFMA16(aF[mf][2], bF[nf][0], a);
        a = MFMA16(aF[mf][1], bF[nf][1], a);
        acc[mf][nf] = a;
      }
    }
  }
  #pragma unroll
  for (int nf = 0; nf < 2; ++nf) {
    int co = wc*32 + nf*16 + col_l;
    float bv = bias[co];
    #pragma unroll
    for (int mf = 0; mf < 2; ++mf) {
      int px0 = wr*32 + mf*16 + kg*4;
      float4 o;
      o.x = acc[mf][nf][0] + bv; o.y = acc[mf][nf][1] + bv;
      o.z = acc[mf][nf][2] + bv; o.w = acc[mf][nf][3] + bv;
      *(float4*)(ze + ((long)(b*64 + co)*64 + oy)*64 + px0) = o;
    }
  }
}

// ---------------- MFMA ConvTranspose2d stride2 k4 pad1 ----------------
template<int CIN, int TX, bool IN_F32>
struct SmemT {
  union {
    struct {
      __align__(16) unsigned short In[2][TX+2][24];
      __align__(16) unsigned short W[2][128][64];
    };
    __align__(16) unsigned short Out[128][2*TX];
  };
};

template<int CIN, int TX, bool IN_F32>
__global__ __launch_bounds__(TX*4, 4) void deconv_mfma(
    const void* __restrict__ xin, const unsigned short* __restrict__ w2,
    const float* __restrict__ bias, unsigned short* __restrict__ y) {
  constexpr int NTHR = TX*4;
  constexpr int K    = CIN*4;
  constexpr int TPR  = NTHR/32;
  __shared__ SmemT<CIN,TX,IN_F32> sm;

  const int tid = threadIdx.x;
  const int ty = blockIdx.x, e = blockIdx.y, b = blockIdx.z;
  const int wave = tid >> 6, lane = tid & 63;
  const int wc = wave & 1, wr = wave >> 1;
  const int f = (wr*64) / TX;
  const int tx_base = (wr*64) & (TX-1);
  const int col_l = lane & 15, kg = lane >> 4;

  if (tid < 64) {
    int rr = tid & 1, cc = ((tid>>1)&1) ? TX+1 : 0, ci = tid >> 2;
    sm.In[rr][cc][ci] = 0;
  }

  f32x4 acc[4][4] = {};
  const int rowid = tid / TPR, li = tid % TPR;
  const int sci = rowid >> 1, srr = rowid & 1;
  const int iy = ty + e - 1 + srr;

  for (int ch = 0; ch < CIN/16; ++ch) {
    __syncthreads();
    {
      unsigned short vals[8];
      if (iy >= 0 && iy < TX) {
        long gofs = ((long)b*CIN + ch*16 + sci)*TX*TX + (long)iy*TX + li*8;
        if (IN_F32) {
          const float4* s4 = (const float4*)((const float*)xin + gofs);
          float4 lo = s4[0], hi = s4[1];
          vals[0]=bfbits(lo.x); vals[1]=bfbits(lo.y); vals[2]=bfbits(lo.z); vals[3]=bfbits(lo.w);
          vals[4]=bfbits(hi.x); vals[5]=bfbits(hi.y); vals[6]=bfbits(hi.z); vals[7]=bfbits(hi.w);
        } else {
          bf16x8 v = *(const bf16x8*)((const unsigned short*)xin + gofs);
          #pragma unroll
          for (int j=0;j<8;j++) vals[j] = ((unsigned short)v[j]);
        }
      } else {
        #pragma unroll
        for (int j=0;j<8;j++) vals[j] = 0;
      }
      #pragma unroll
      for (int j=0;j<8;j++) {
        int jj = (j + li) & 7;
        sm.In[srr][1 + li*8 + jj][sci] = vals[jj];
      }
    }
    for (int i = tid; i < 2048; i += NTHR) {
      int s = i & 7, co = (i >> 3) & 127, ff = i >> 10;
      const unsigned short* src = w2 + ((long)((e*2+ff)*128 + co))*K + ch*64 + s*8;
      *(uint4*)&sm.W[ff][co][(s ^ (co & 7))*8] = *(const uint4*)src;
    }
    __syncthreads();
    #pragma unroll
    for (int kk = 0; kk < 2; ++kk) {
      bf16x8 aF[4];
      const int tap = kk*2 + (kg >> 1), a = tap >> 1, bb = tap & 1;
      const int cib = (kg & 1)*8;
      #pragma unroll
      for (int mf = 0; mf < 4; ++mf) {
        int tx = tx_base + mf*16 + col_l;
        aF[mf] = *(const bf16x8*)&sm.In[1-a][tx + 1 + f - bb][cib];
      }
      const int slot = kk*4 + kg;
      #pragma unroll
      for (int nf = 0; nf < 4; ++nf) {
        int co_l = nf*16 + col_l;
        bf16x8 bF = *(const bf16x8*)&sm.W[f][wc*64 + co_l][(slot ^ (co_l & 7))*8];
        #pragma unroll
        for (int mf = 0; mf < 4; ++mf)
          acc[mf][nf] = MFMA16(aF[mf], bF, acc[mf][nf]);
      }
    }
  }

  __syncthreads();
  float bv[4];
  #pragma unroll
  for (int nf = 0; nf < 4; ++nf) bv[nf] = bias[wc*64 + nf*16 + col_l];
  #pragma unroll
  for (int mf = 0; mf < 4; ++mf)
  #pragma unroll
  for (int nf = 0; nf < 4; ++nf) {
    int co = wc*64 + nf*16 + col_l;
    #pragma unroll
    for (int r = 0; r < 4; ++r) {
      int tx = tx_base + mf*16 + kg*4 + r;
      float v = fmaxf(acc[mf][nf][r] + bv[nf], 0.f);
      int ox = 2*tx + f;
      sm.Out[co][ox ^ ((co & 15)*8)] = bfbits(v);
    }
  }
  __syncthreads();
  constexpr int CH = 2*TX/8;
  const int oy = 2*ty + e;
  for (int i = tid; i < 128*CH; i += NTHR) {
    int co = i / CH, cx = i % CH;
    uint4 v = *(const uint4*)&sm.Out[co][(cx ^ (co & 15))*8];
    *(uint4*)(y + (((long)b*128 + co)*(2*TX) + oy)*(long)(2*TX) + cx*8) = v;
  }
}

// ---------------- deconv3: MFMA, s1 k3 p1, 128->3(pad16) + sigmoid ----------------
// block: one output row oy (M=256 px, 4 waves x 64), one batch of the group.
// deconv flip: iy = oy+1-ky (dy=2-ky), ix = ox+1-kx (A col = px+3-kx).
__global__ __launch_bounds__(256) void deconv3_mfma(
    const unsigned short* __restrict__ g2,   // [4][128][256][256] bf16
    const unsigned short* __restrict__ w2,   // [co16][1536]
    const float* __restrict__ bias, float* __restrict__ y) {
  __shared__ __align__(16) unsigned short sA[3][260][8];
  __shared__ __align__(16) unsigned short sB[16*12*16*8];   // [ch][tap][co][cil]
  const int tid = threadIdx.x;
  const int oy = blockIdx.x, b = blockIdx.y;
  const int wave = tid >> 6, lane = tid & 63;
  const int col_l = lane & 15, kg = lane >> 4;
  const int pxb = wave*64;
  // whole weight tensor into LDS once (conflict-free layout: co contiguous 16B)
  for (int i = tid; i < 3072; i += 256) {
    int co = i & 15, tap = (i>>4) % 12, ch = i/192;
    *(uint4*)&sB[((ch*12+tap)*16+co)*8] = *(const uint4*)(w2 + (long)co*1536 + ch*96 + tap*8);
  }
  // zero pad cols {0,1,258,259}
  if (tid < 96) {
    int ci = tid & 7, c = (tid>>3)&3, dy = tid>>5;
    int col = (c<2) ? c : (256+c);
    sA[dy][col][ci] = 0;
  }
  f32x4 acc[4] = {};
  for (int ch = 0; ch < 16; ++ch) {
    __syncthreads();
    // stage A: 8ci x 3dy x 256px = 768 units of 8px
    #pragma unroll
    for (int u = 0; u < 3; ++u) {
      int unit = tid + u*256;
      int li = unit & 31, dy = (unit>>5)%3, ci = unit/96;
      int iy = oy - 1 + dy;
      unsigned short v[8];
      if (iy >= 0 && iy < 256) {
        *(uint4*)v = *(const uint4*)(g2 + ((long)(b*128 + ch*8+ci)*256 + iy)*256 + li*8);
      } else {
        #pragma unroll
        for (int j=0;j<8;j++) v[j]=0;
      }
      #pragma unroll
      for (int p = 0; p < 8; ++p) {
        int pp = (p + li) & 7;
        sA[dy][2 + li*8 + pp][ci] = v[pp];
      }
    }
    __syncthreads();
    #pragma unroll
    for (int s = 0; s < 3; ++s) {      // s = ky
      bf16x8 bF = *(const bf16x8*)&sB[((ch*12 + s*4 + kg)*16 + col_l)*8];
      #pragma unroll
      for (int mf = 0; mf < 4; ++mf) {
        int px = pxb + mf*16 + col_l;
        bf16x8 aF = *(const bf16x8*)&sA[2-s][px + 3 - kg][0];
        acc[mf] = MFMA16(aF, bF, acc[mf]);
      }
    }
  }
  // epilogue: bias + sigmoid, co<3 lanes store float4
  if (col_l < 3) {
    float bv = bias[col_l];
    #pragma unroll
    for (int mf = 0; mf < 4; ++mf) {
      int px = pxb + mf*16 + kg*4;
      float4 o;
      o.x = 1.f/(1.f + expf(-(acc[mf][0] + bv)));
      o.y = 1.f/(1.f + expf(-(acc[mf][1] + bv)));
      o.z = 1.f/(1.f + expf(-(acc[mf][2] + bv)));
      o.w = 1.f/(1.f + expf(-(acc[mf][3] + bv)));
      *(float4*)(y + ((long)(b*3 + col_l)*256 + oy)*256 + px) = o;
    }
  }
}

// ---------------- vector quantizer: 4 threads/row ----------------
__global__ __launch_bounds__(256, 4) void vq_kernel(
    const float* __restrict__ ze, const float* __restrict__ emb,
    float* __restrict__ out_idx, float* __restrict__ zq) {
  __shared__ __align__(16) float se[128][68];
  __shared__ float sn[128];
  const int tid = threadIdx.x;
  const int row = tid >> 2, sub = tid & 3;
  const long n = (long)blockIdx.x*64 + row;
  float4 rv[16];
  const float4* zr = (const float4*)(ze + n*64);
  #pragma unroll
  for (int q=0;q<16;q++) rv[q] = zr[q];
  float best = 3.4e38f; int bidx = 0;
  for (int ch=0; ch<4; ch++) {
    __syncthreads();
    for (int i = tid; i < 2048; i += 256) {
      int k = i >> 4, q = i & 15;
      *(float4*)&se[k][q*4] = *(const float4*)(emb + ((long)ch*128 + k)*64 + q*4);
    }
    __syncthreads();
    if (tid < 128) {
      float s = 0.f;
      const float4* ev = (const float4*)&se[tid][0];
      #pragma unroll
      for (int q=0;q<16;q++){ float4 e4 = ev[q];
        s += e4.x*e4.x + e4.y*e4.y + e4.z*e4.z + e4.w*e4.w; }
      sn[tid] = s;
    }
    __syncthreads();
    for (int kk = 0; kk < 32; ++kk) {
      int k = kk*4 + sub;
      const float4* ev = (const float4*)&se[k][0];
      float dot = 0.f;
      #pragma unroll
      for (int q=0;q<16;q++){
        float4 e4 = ev[q];
        dot += rv[q].x*e4.x + rv[q].y*e4.y + rv[q].z*e4.z + rv[q].w*e4.w;
      }
      float s = sn[k] - 2.f*dot;
      if (s < best) { best = s; bidx = ch*128 + k; }
    }
  }
  #pragma unroll
  for (int off = 1; off < 4; off <<= 1) {
    float ob = __shfl_xor(best, off);
    int oi = __shfl_xor(bidx, off);
    if (ob < best || (ob == best && oi < bidx)) { best = ob; bidx = oi; }
  }
  if (sub == 0) out_idx[n] = (float)bidx;
  const float4* eb = (const float4*)(emb + (long)bidx*64);
  float4* zo = (float4*)(zq + n*64);
  #pragma unroll
  for (int q=0;q<4;q++) zo[sub*4+q] = eb[sub*4+q];
}

// ---------------- launch ----------------
extern "C" void kernel_launch(void* const* d_in, const int* in_sizes, int n_in,
                              void* d_out, int out_size, void* d_ws, size_t ws_size,
                              hipStream_t stream) {
  const float* x   = (const float*)d_in[0];
  const float* c1w = (const float*)d_in[1];  const float* c1b = (const float*)d_in[2];
  const float* c2w = (const float*)d_in[3];  const float* c2b = (const float*)d_in[4];
  const float* c3w = (const float*)d_in[5];  const float* c3b = (const float*)d_in[6];
  const float* emb = (const float*)d_in[7];
  const float* d1w = (const float*)d_in[8];  const float* d1b = (const float*)d_in[9];
  const float* d2w = (const float*)d_in[10]; const float* d2b = (const float*)d_in[11];
  const float* d3w = (const float*)d_in[12]; const float* d3b = (const float*)d_in[13];
  float* out = (float*)d_out;

  float* xrec = out;                 // 16*3*256*256
  float* oidx = out + 3145728;       // 65536
  float* zq   = out + 3211264;       // 16*64*64*64

  const long XB  = 196608;   // 3*256*256
  const long ZEB = 262144;   // 64*64*64
  const long PS1 = 8388608;  // 4b*128*128*128 (elems, per plane)
  const long PS2 = 4194304;  // 8b*128*64*64

  const size_t NEEDED = 112074752ULL;  // known: ws_size >= 120,395,264
  if (ws_size < NEEDED) return;
  char* wsb = (char*)d_ws;
  // R1 [0,64M): h1grp 3-plane (50.3MB) / g2grp (64MB)
  unsigned short* h1grp = (unsigned short*)wsb;
  unsigned short* g2grp = (unsigned short*)wsb;
  // R2 [64M, 88M): h2grp8 3-plane (24MB) / g1grp (16MB)
  unsigned short* h2grp = (unsigned short*)(wsb + 67108864);
  unsigned short* g1grp = (unsigned short*)(wsb + 67108864);
  // ze [88M, 104M)
  float* ze = (float*)(wsb + 92274688);
  // weights
  char* W = wsb + 109051904;
  float* w2c1          = (float*)(W);                       // 6144 f32
  unsigned short* w2c2 = (unsigned short*)(W + 24576);      // 3*262144 bf16
  unsigned short* w2c3 = (unsigned short*)(W + 1597440);    // 3*98304 bf16
  unsigned short* w2d1 = (unsigned short*)(W + 2187264);    // 131072 bf16
  unsigned short* w2d2 = (unsigned short*)(W + 2449408);    // 262144 bf16
  unsigned short* w2d3 = (unsigned short*)(W + 2973696);    // 24576 bf16

  // weight preps
  wtrans_conv       <<<24,   256, 0, stream>>>(c1w, w2c1, 128, 3, 16);
  wprep_conv2_mfma  <<<1024, 256, 0, stream>>>(c2w, w2c2);
  wprep_conv3_mfma  <<<384,  256, 0, stream>>>(c3w, w2c3);
  wprep_deconv_mfma <<<512,  256, 0, stream>>>(d1w, w2d1, 64);
  wprep_deconv_mfma <<<1024, 256, 0, stream>>>(d2w, w2d2, 128);
  wprep_deconv3_mfma<<<96,   256, 0, stream>>>(d3w, w2d3);

  // encoder
  for (int g = 0; g < 4; ++g) {
    conv1_split<<<dim3(16,16,8), 256, 0, stream>>>(
        x + (long)g*4*XB, w2c1, c1b, h1grp, PS1);
    conv2_mfma<<<dim3(64,2,4), 256, 0, stream>>>(
        h1grp, PS1, w2c2, c2b, h2grp + (long)(g&1)*4*524288, PS2);
    if (g & 1)
      conv3_mfma<<<dim3(64,1,8), 256, 0, stream>>>(
          h2grp, PS2, w2c3, c3b, ze + (long)(g>>1)*8*ZEB);
  }
  vq_kernel<<<1024, 256, 0, stream>>>(ze, emb, oidx, zq);

  // decoder
  for (int g = 0; g < 4; ++g) {
    deconv_mfma<64, 64, true ><<<dim3(64, 2, 4), 256, 0, stream>>>(
        (const void*)(zq + (long)g*4*ZEB), w2d1, d1b, g1grp);
    deconv_mfma<128,128,false><<<dim3(128,2,4), 512, 0, stream>>>(
        (const void*)g1grp, w2d2, d2b, g2grp);
    deconv3_mfma<<<dim3(256,4), 256, 0, stream>>>(
        g2grp, w2d3, d3b, xrec + (long)g*4*XB);
  }
}

// Round 6
// 1655.645 us; speedup vs baseline: 3.6113x; 1.0757x over previous
//
#include <hip/hip_runtime.h>
#include <hip/hip_bf16.h>

#define DEV __device__ __forceinline__

typedef __attribute__((ext_vector_type(8))) short bf16x8;
typedef __attribute__((ext_vector_type(4))) float f32x4;
typedef __attribute__((ext_vector_type(4))) unsigned short u16x4;

#define MFMA16(a,b,c) __builtin_amdgcn_mfma_f32_16x16x32_bf16(a,b,c,0,0,0)

DEV unsigned short bfbits(float v){ __hip_bfloat16 h = __float2bfloat16(v); return *(unsigned short*)&h; }
DEV float bf2f(unsigned short u){ __hip_bfloat16 h = *(__hip_bfloat16*)&u; return __bfloat162float(h); }
DEV void split3(float v, unsigned short& h, unsigned short& m, unsigned short& l) {
  h = bfbits(v);        float r  = v - bf2f(h);
  m = bfbits(r);        float r2 = r - bf2f(m);
  l = bfbits(r2);
}
DEV uint4 zero4(){ uint4 z; z.x=0; z.y=0; z.z=0; z.w=0; return z; }

// ---------------- weight preps ----------------
__global__ __launch_bounds__(256) void wtrans_conv(const float* __restrict__ w,
    float* __restrict__ w2, int CO, int CI, int KK) {
  int i = blockIdx.x*256 + threadIdx.x;
  int total = CO*CI*KK;
  if (i >= total) return;
  int t = i % KK; int ci = (i/KK) % CI; int co = i/(KK*CI);
  w2[((long)ci*KK + t)*CO + co] = w[i];
}
__global__ __launch_bounds__(256) void wprep_deconv_mfma(
    const float* __restrict__ w, unsigned short* __restrict__ w2, int CI) {
  const int K = CI*4;
  int i = blockIdx.x*256 + threadIdx.x;
  if (i >= 512*K) return;
  int k  = i % K;
  int co = (i / K) & 127;
  int f  = (i / (K*128)) & 1;
  int e  = i / (K*256);
  int ci = (k & 15) | ((k >> 6) << 4);
  int tap = (k >> 4) & 3, a = tap >> 1, b = tap & 1;
  float v = w[ (((long)ci*128 + co)*4 + (2*a+1-e))*4 + (2*b+1-f) ];
  w2[i] = bfbits(v);
}
__global__ __launch_bounds__(256) void wprep_conv2_mfma(
    const float* __restrict__ w, unsigned short* __restrict__ w2) {
  int i = blockIdx.x*256 + threadIdx.x;          // 262144
  int k = i & 2047, co = i >> 11;
  int ch = k >> 7, rem = k & 127;
  int tap = rem >> 3, cil = rem & 7;
  int ci = ch*8 + cil, ky = tap >> 2, kx = tap & 3;
  float v = w[(((long)co*128 + ci)*4 + ky)*4 + kx];
  unsigned short h,m,l; split3(v,h,m,l);
  w2[i] = h; w2[i + 262144] = m; w2[i + 524288] = l;
}
__global__ __launch_bounds__(256) void wprep_conv3_mfma(
    const float* __restrict__ w, unsigned short* __restrict__ w2) {
  int i = blockIdx.x*256 + threadIdx.x;          // 98304
  int k = i % 1536, co = i / 1536;
  int ch = k / 96, rem = k % 96;
  int tap = rem >> 3, cil = rem & 7;
  int ci = ch*8 + cil, ky = tap >> 2, kx = tap & 3;
  float v = (kx < 3) ? w[(((long)co*128 + ci)*3 + ky)*3 + kx] : 0.f;
  unsigned short h,m,l; split3(v,h,m,l);
  w2[i] = h; w2[i + 98304] = m; w2[i + 196608] = l;
}
__global__ __launch_bounds__(256) void wprep_deconv3_mfma(
    const float* __restrict__ w, unsigned short* __restrict__ w2) {
  int i = blockIdx.x*256 + threadIdx.x;          // 24576
  if (i >= 24576) return;
  int k = i % 1536, co = i / 1536;
  int ch = k / 96, rem = k % 96;
  int tap = rem >> 3, cil = rem & 7;
  int ci = ch*8 + cil, ky = tap >> 2, kx = tap & 3;
  float v = (co < 3 && kx < 3) ? w[(((long)ci*3 + co)*3 + ky)*3 + kx] : 0.f;
  w2[i] = bfbits(v);
}

// ---------------- conv1: f32 direct, out 3 bf16 planes INTERLEAVED [b][row][ch][px][ci8] ----
__global__ __launch_bounds__(256) void conv1_split(
    const float* __restrict__ x, const float* __restrict__ w2,
    const float* __restrict__ bias, unsigned short* __restrict__ h1, long PS1) {
  __shared__ __align__(16) float sIn[3][18][20];
  __shared__ __align__(16) float sW[3*16*64];
  const int tid = threadIdx.x;
  const int b = blockIdx.z >> 1, cog = blockIdx.z & 1;
  const int co0 = cog*64;
  const int oy0 = blockIdx.y*8, ox0 = blockIdx.x*8;
  const int cg2 = tid >> 5;            // 8-co block
  const int pg2 = tid & 31;
  const int r = pg2 >> 2, pxp = (pg2 & 3)*2;
  float acc[8][2];
  #pragma unroll
  for (int c=0;c<8;c++){ float bv = bias[co0 + cg2*8 + c];
    acc[c][0]=bv; acc[c][1]=bv; }
  const float* xb = x + (long)b*3*256*256;
  const int iy0 = 2*oy0 - 1, ix0 = 2*ox0 - 1;
  for (int t=tid; t<3*18*18; t+=256) {
    int xx = t%18, yy=(t/18)%18, ci=t/324;
    int gy = iy0+yy, gx = ix0+xx;
    float v = 0.f;
    if (gy>=0 && gy<256 && gx>=0 && gx<256) v = xb[((long)ci*256+gy)*256+gx];
    sIn[ci][yy][xx] = v;
  }
  for (int t=tid; t<3*16*64; t+=256) {
    sW[t] = w2[(long)(t>>6)*128 + co0 + (t&63)];
  }
  __syncthreads();
  for (int ci=0; ci<3; ci++) {
    #pragma unroll
    for (int ky=0;ky<4;ky++)
    #pragma unroll
    for (int kx=0;kx<4;kx++) {
      const float* wp = &sW[(ci*16 + ky*4+kx)*64 + cg2*8];
      float4 w0 = *(const float4*)wp;
      float4 w1 = *(const float4*)(wp+4);
      const int yy = 2*r + ky;
      #pragma unroll
      for (int p=0;p<2;p++) {
        float iv = sIn[ci][yy][2*(pxp+p)+kx];
        acc[0][p] += w0.x*iv; acc[1][p] += w0.y*iv;
        acc[2][p] += w0.z*iv; acc[3][p] += w0.w*iv;
        acc[4][p] += w1.x*iv; acc[5][p] += w1.y*iv;
        acc[6][p] += w1.z*iv; acc[7][p] += w1.w*iv;
      }
    }
  }
  const int chg = cog*8 + cg2;
  #pragma unroll
  for (int p=0;p<2;p++) {
    unsigned short th[8], tm[8], tl[8];
    #pragma unroll
    for (int c=0;c<8;c++) {
      float v = fmaxf(acc[c][p], 0.f);
      split3(v, th[c], tm[c], tl[c]);
    }
    long base = (((long)(b*128 + oy0+r)*16 + chg)*128 + ox0+pxp+p)*8;
    *(uint4*)(h1 + base)          = *(uint4*)th;
    *(uint4*)(h1 + PS1 + base)    = *(uint4*)tm;
    *(uint4*)(h1 + 2*PS1 + base)  = *(uint4*)tl;
  }
}

// ---------------- conv2: MFMA 6-term split, k4 s2 p1, interleaved input, prefetch ----------
__global__ __launch_bounds__(256, 2) void conv2_mfma(
    const unsigned short* __restrict__ h1, long PS1,
    const unsigned short* __restrict__ w2,
    const float* __restrict__ bias,
    unsigned short* __restrict__ h2, long PS2) {
  __shared__ __align__(16) unsigned short sA[3][4][130][8];
  __shared__ __align__(16) unsigned short sB[3*64*16*8];
  const int tid = threadIdx.x;
  const int oy = blockIdx.x, cog = blockIdx.y, b = blockIdx.z;
  const int wave = tid >> 6, lane = tid & 63;
  const int wr = wave >> 1, wc = wave & 1;
  const int col_l = lane & 15, kg = lane >> 4;
  const int iy0 = 2*oy - 1;
  f32x4 acc[2][2] = {};
  unsigned short* sAf = &sA[0][0][0][0];

  // prefetch descriptors
  int aOff[6], aLdsO[6]; bool aOk[6];
  #pragma unroll
  for (int j = 0; j < 6; ++j) {
    int idx = tid + j*256;
    int px = idx & 127, rr = (idx >> 7) & 3, pl = idx >> 9;
    int iy = iy0 + rr;
    aOk[j] = (iy >= 0 && iy < 128);
    aOff[j] = (int)(pl*PS1 + (long)(b*128 + (aOk[j]?iy:0))*16384 + px*8);
    aLdsO[j] = ((pl*4 + rr)*130 + px + 1)*8;
  }
  int bOff[12], bLdsO[12];
  #pragma unroll
  for (int j = 0; j < 12; ++j) {
    int i = tid + j*256;
    int s = i & 15, co = (i >> 4) & 63, pl = i >> 10;
    bOff[j] = (pl*128 + cog*64 + co)*2048 + s*8;
    bLdsO[j] = ((pl*64 + co)*16 + (s ^ (co & 15)))*8;
  }
  uint4 pA[6], pB[12];
  #pragma unroll
  for (int j=0;j<6;j++)  pA[j] = aOk[j] ? *(const uint4*)(h1 + aOff[j]) : zero4();
  #pragma unroll
  for (int j=0;j<12;j++) pB[j] = *(const uint4*)(w2 + bOff[j]);

  if (tid < 24) {       // zero pad slots col 0 and 129
    int pl = tid>>3, rr=(tid>>1)&3, c=tid&1;
    *(uint4*)&sA[pl][rr][c?129:0][0] = zero4();
  }

  for (int ch = 0; ch < 16; ++ch) {
    __syncthreads();
    #pragma unroll
    for (int j=0;j<6;j++)  *(uint4*)(sAf + aLdsO[j]) = pA[j];
    #pragma unroll
    for (int j=0;j<12;j++) *(uint4*)(&sB[bLdsO[j]]) = pB[j];
    if (ch < 15) {
      #pragma unroll
      for (int j=0;j<6;j++)  pA[j] = aOk[j] ? *(const uint4*)(h1 + aOff[j] + (ch+1)*1024) : zero4();
      #pragma unroll
      for (int j=0;j<12;j++) pB[j] = *(const uint4*)(w2 + bOff[j] + (ch+1)*128);
    }
    __syncthreads();
    #pragma unroll
    for (int s = 0; s < 4; ++s) {        // s = ky
      bf16x8 aF[2][3]; bf16x8 bF[2][3];
      const int tap = s*4 + kg;
      #pragma unroll
      for (int mf = 0; mf < 2; ++mf) {
        int ox = wr*32 + mf*16 + col_l;
        #pragma unroll
        for (int pl = 0; pl < 3; ++pl)
          aF[mf][pl] = *(const bf16x8*)&sA[pl][s][2*ox + kg][0];
      }
      #pragma unroll
      for (int nf = 0; nf < 2; ++nf) {
        int co = wc*32 + nf*16 + col_l;
        int ba = (co*16 + (tap ^ (co&15)))*8;
        bF[nf][0] = *(const bf16x8*)&sB[ba];
        bF[nf][1] = *(const bf16x8*)&sB[ba + 8192];
        bF[nf][2] = *(const bf16x8*)&sB[ba + 16384];
      }
      #pragma unroll
      for (int mf = 0; mf < 2; ++mf)
      #pragma unroll
      for (int nf = 0; nf < 2; ++nf) {
        f32x4 a = acc[mf][nf];
        a = MFMA16(aF[mf][0], bF[nf][0], a);
        a = MFMA16(aF[mf][0], bF[nf][1], a);
        a = MFMA16(aF[mf][1], bF[nf][0], a);
        a = MFMA16(aF[mf][0], bF[nf][2], a);
        a = MFMA16(aF[mf][2], bF[nf][0], a);
        a = MFMA16(aF[mf][1], bF[nf][1], a);
        acc[mf][nf] = a;
      }
    }
  }
  // epilogue: h2 stays 3-plane planar (conv3 consumes it)
  #pragma unroll
  for (int nf = 0; nf < 2; ++nf) {
    int co = cog*64 + wc*32 + nf*16 + col_l;
    float bv = bias[co];
    #pragma unroll
    for (int mf = 0; mf < 2; ++mf) {
      int px0 = wr*32 + mf*16 + kg*4;
      u16x4 oh, om, ol;
      #pragma unroll
      for (int r = 0; r < 4; ++r) {
        float v = fmaxf(acc[mf][nf][r] + bv, 0.f);
        unsigned short h,m,l; split3(v,h,m,l);
        oh[r]=h; om[r]=m; ol[r]=l;
      }
      long base = ((long)(b*128 + co)*64 + oy)*64 + px0;
      *(u16x4*)(h2 + base) = oh;
      *(u16x4*)(h2 + PS2 + base) = om;
      *(u16x4*)(h2 + 2*PS2 + base) = ol;
    }
  }
}

// ---------------- conv3: MFMA 6-term split, k3 s1 p1, 128->64, prefetch ----------------
__global__ __launch_bounds__(256, 2) void conv3_mfma(
    const unsigned short* __restrict__ h2, long PS2,
    const unsigned short* __restrict__ w2,
    const float* __restrict__ bias, float* __restrict__ ze) {
  __shared__ __align__(16) unsigned short sA[3*67*24];
  __shared__ __align__(16) unsigned short sB[3*64*16*8];
  const int tid = threadIdx.x;
  const int oy = blockIdx.x, b = blockIdx.z;
  const int wave = tid >> 6, lane = tid & 63;
  const int wr = wave >> 1, wc = wave & 1;
  const int col_l = lane & 15, kg = lane >> 4;
  f32x4 acc[2][2] = {};
  for (int i = tid; i < 3*3*24; i += 256) {
    int j = i % 24, c = (i/24) % 3, rr = i/72;
    int col = (c==0) ? 0 : (c==1 ? 65 : 66);
    sA[(rr*67 + col)*24 + j] = 0;
  }
  // prefetch descriptors
  const int li = tid & 7, rrA = (tid>>3)%3, ciA = tid/24;
  const int iyA = oy + rrA - 1;
  const bool aAct = (tid < 192);
  const bool aOk = aAct && (iyA >= 0 && iyA < 64);
  const long aBase = ((long)(b*128 + ciA)*64 + (aOk?iyA:0))*64 + li*8;
  int bOff[9], bLdsO[9];
  #pragma unroll
  for (int j = 0; j < 9; ++j) {
    int i = tid + j*256;
    int s = i % 12, co = (i/12) & 63, pl = i/768;
    bOff[j] = (pl*64 + co)*1536 + s*8;
    bLdsO[j] = ((pl*64 + co)*16 + (s ^ (co & 15)))*8;
  }
  uint4 ph, pm, pl4, pB[9];
  ph = aOk ? *(const uint4*)(h2 + aBase) : zero4();
  pm = aOk ? *(const uint4*)(h2 + PS2 + aBase) : zero4();
  pl4 = aOk ? *(const uint4*)(h2 + 2*PS2 + aBase) : zero4();
  #pragma unroll
  for (int j=0;j<9;j++) pB[j] = *(const uint4*)(w2 + bOff[j]);

  for (int ch = 0; ch < 16; ++ch) {
    __syncthreads();
    if (aAct) {
      const unsigned short* vh = (const unsigned short*)&ph;
      const unsigned short* vm = (const unsigned short*)&pm;
      const unsigned short* vl = (const unsigned short*)&pl4;
      #pragma unroll
      for (int p = 0; p < 8; ++p) {
        int pp = (p + li) & 7;
        int col = li*8 + pp + 1;
        int base = (rrA*67 + col)*24 + ciA;
        sA[base]      = vh[pp];
        sA[base + 8]  = vm[pp];
        sA[base + 16] = vl[pp];
      }
    }
    #pragma unroll
    for (int j=0;j<9;j++) *(uint4*)(&sB[bLdsO[j]]) = pB[j];
    if (ch < 15) {
      long nb = aBase + (long)(ch+1)*32768;
      ph = aOk ? *(const uint4*)(h2 + nb) : zero4();
      pm = aOk ? *(const uint4*)(h2 + PS2 + nb) : zero4();
      pl4 = aOk ? *(const uint4*)(h2 + 2*PS2 + nb) : zero4();
      #pragma unroll
      for (int j=0;j<9;j++) pB[j] = *(const uint4*)(w2 + bOff[j] + (ch+1)*96);
    }
    __syncthreads();
    #pragma unroll
    for (int s = 0; s < 3; ++s) {
      bf16x8 aF[2][3]; bf16x8 bF[2][3];
      const int tap = s*4 + kg;
      #pragma unroll
      for (int mf = 0; mf < 2; ++mf) {
        int ox = wr*32 + mf*16 + col_l;
        int base = (s*67 + ox + kg)*24;
        aF[mf][0] = *(const bf16x8*)&sA[base];
        aF[mf][1] = *(const bf16x8*)&sA[base+8];
        aF[mf][2] = *(const bf16x8*)&sA[base+16];
      }
      #pragma unroll
      for (int nf = 0; nf < 2; ++nf) {
        int co = wc*32 + nf*16 + col_l;
        int ba = (co*16 + (tap ^ (co&15)))*8;
        bF[nf][0] = *(const bf16x8*)&sB[ba];
        bF[nf][1] = *(const bf16x8*)&sB[ba + 8192];
        bF[nf][2] = *(const bf16x8*)&sB[ba + 16384];
      }
      #pragma unroll
      for (int mf = 0; mf < 2; ++mf)
      #pragma unroll
      for (int nf = 0; nf < 2; ++nf) {
        f32x4 a = acc[mf][nf];
        a = MFMA16(aF[mf][0], bF[nf][0], a);
        a = MFMA16(aF[mf][0], bF[nf][1], a);
        a = MFMA16(aF[mf][1], bF[nf][0], a);
        a = MFMA16(aF[mf][0], bF[nf][2], a);
        a = MFMA16(aF[mf][2], bF[nf][0], a);
        a = MFMA16(aF[mf][1], bF[nf][1], a);
        acc[mf][nf] = a;
      }
    }
  }
  #pragma unroll
  for (int nf = 0; nf < 2; ++nf) {
    int co = wc*32 + nf*16 + col_l;
    float bv = bias[co];
    #pragma unroll
    for (int mf = 0; mf < 2; ++mf) {
      int px0 = wr*32 + mf*16 + kg*4;
      float4 o;
      o.x = acc[mf][nf][0] + bv; o.y = acc[mf][nf][1] + bv;
      o.z = acc[mf][nf][2] + bv; o.w = acc[mf][nf][3] + bv;
      *(float4*)(ze + ((long)(b*64 + co)*64 + oy)*64 + px0) = o;
    }
  }
}

// ---------------- MFMA ConvTranspose2d stride2 k4 pad1, prefetch, interleaved out ----------
// MODE 0: f32 planar input (old stagger staging). MODE 1: bf16 interleaved input.
template<int TX, int MODE>
struct SmemD {
  union {
    struct { __align__(16) unsigned short In[2][TX+2][24];
             __align__(16) unsigned short W[2*128*64]; } o;
    struct { __align__(16) unsigned short In[2][TX+2][16];
             __align__(16) unsigned short W[2*128*64]; } v;
    __align__(16) unsigned short Out[2*TX][136];
  };
};

template<int CIN, int TX, int MODE>
__global__ __launch_bounds__(TX*4, (TX==64)?3:4) void deconv_mfma(
    const void* __restrict__ xin, const unsigned short* __restrict__ w2,
    const float* __restrict__ bias, unsigned short* __restrict__ yI) {
  constexpr int NTHR = TX*4;
  constexpr int K    = CIN*4;
  constexpr int NW   = 2048/NTHR;
  __shared__ SmemD<TX,MODE> sm;
  unsigned short* Wb = MODE ? &sm.v.W[0] : &sm.o.W[0];

  const int tid = threadIdx.x;
  const int ty = blockIdx.x, e = blockIdx.y, b = blockIdx.z;
  const int wave = tid >> 6, lane = tid & 63;
  const int wc = wave & 1, wr = wave >> 1;
  const int f = (wr*64) / TX;
  const int tx_base = (wr*64) & (TX-1);
  const int col_l = lane & 15, kg = lane >> 4;

  // W prefetch descriptors
  int wOff[NW], wLdsO[NW];
  #pragma unroll
  for (int j = 0; j < NW; ++j) {
    int i = tid + j*NTHR;
    int s = i & 7, co = (i >> 3) & 127, ff = i >> 10;
    wOff[j] = ((e*2+ff)*128 + co)*K + s*8;
    wLdsO[j] = (ff*128 + co)*64 + (s ^ (co & 7))*8;
  }
  uint4 pW[NW];
  #pragma unroll
  for (int j=0;j<NW;j++) pW[j] = *(const uint4*)(w2 + wOff[j]);

  // A prefetch descriptors
  constexpr int TPR = NTHR/32;
  const int rowid = tid / TPR, liO = tid % TPR;
  const int sci = rowid >> 1, srr = rowid & 1;
  float4 pLo, pHi; uint4 pIn;
  long aBase = 0; bool aOk = false;
  int pxV = 0, halfV = 0, rrV = 0;
  if (MODE == 0) {
    int iy = ty + e - 1 + srr;
    aOk = (iy >= 0 && iy < TX);
    aBase = ((long)b*CIN + sci)*TX*TX + (long)(aOk?iy:0)*TX + liO*8;
    if (aOk) { const float4* s4 = (const float4*)((const float*)xin + aBase);
               pLo = s4[0]; pHi = s4[1]; }
  } else {
    halfV = tid & 1; pxV = (tid >> 1) & (TX-1); rrV = tid >> 8;
    int iy = ty + e - 1 + rrV;
    aOk = (iy >= 0 && iy < TX);
    aBase = ((long)b*TX + (aOk?iy:0))*((long)(CIN/8)*TX*8) + (long)halfV*TX*8 + pxV*8;
    pIn = aOk ? *(const uint4*)((const unsigned short*)xin + aBase) : zero4();
  }

  // zero pads
  if (MODE == 0) {
    if (tid < 64) {
      int rr = tid & 1, cc = ((tid>>1)&1) ? TX+1 : 0, ci = tid >> 2;
      sm.o.In[rr][cc][ci] = 0;
    }
  } else {
    if (tid < 8) {
      int rr = tid & 1, c = (tid>>1)&1, hf = (tid>>2)&1;
      *(uint4*)&sm.v.In[rr][c?TX+1:0][hf*8] = zero4();
    }
  }

  f32x4 acc[4][4] = {};
  for (int ch = 0; ch < CIN/16; ++ch) {
    __syncthreads();
    if (MODE == 0) {
      unsigned short vals[8];
      if (aOk) {
        float4 lo = pLo, hi = pHi;
        vals[0]=bfbits(lo.x); vals[1]=bfbits(lo.y); vals[2]=bfbits(lo.z); vals[3]=bfbits(lo.w);
        vals[4]=bfbits(hi.x); vals[5]=bfbits(hi.y); vals[6]=bfbits(hi.z); vals[7]=bfbits(hi.w);
      } else {
        #pragma unroll
        for (int j=0;j<8;j++) vals[j] = 0;
      }
      #pragma unroll
      for (int j=0;j<8;j++) {
        int jj = (j + liO) & 7;
        sm.o.In[srr][1 + liO*8 + jj][sci] = vals[jj];
      }
    } else {
      *(uint4*)&sm.v.In[rrV][pxV+1][halfV*8] = pIn;
    }
    #pragma unroll
    for (int j=0;j<NW;j++) *(uint4*)(Wb + wLdsO[j]) = pW[j];
    if (ch + 1 < CIN/16) {
      if (MODE == 0) {
        if (aOk) { const float4* s4 = (const float4*)((const float*)xin + aBase + (long)(ch+1)*16*TX*TX);
                   pLo = s4[0]; pHi = s4[1]; }
      } else {
        pIn = aOk ? *(const uint4*)((const unsigned short*)xin + aBase + (ch+1)*2*TX*8) : zero4();
      }
      #pragma unroll
      for (int j=0;j<NW;j++) pW[j] = *(const uint4*)(w2 + wOff[j] + (ch+1)*64);
    }
    __syncthreads();
    #pragma unroll
    for (int kk = 0; kk < 2; ++kk) {
      bf16x8 aF[4];
      const int tap = kk*2 + (kg >> 1), a = tap >> 1, bb = tap & 1;
      #pragma unroll
      for (int mf = 0; mf < 4; ++mf) {
        int tx = tx_base + mf*16 + col_l;
        if (MODE == 0) aF[mf] = *(const bf16x8*)&sm.o.In[1-a][tx + 1 + f - bb][(kg&1)*8];
        else           aF[mf] = *(const bf16x8*)&sm.v.In[1-a][tx + 1 + f - bb][(kg&1)*8];
      }
      const int slot = kk*4 + kg;
      #pragma unroll
      for (int nf = 0; nf < 4; ++nf) {
        int co_l = nf*16 + col_l;
        bf16x8 bF = *(const bf16x8*)(Wb + (f*128 + wc*64 + co_l)*64 + (slot ^ (co_l & 7))*8);
        #pragma unroll
        for (int mf = 0; mf < 4; ++mf)
          acc[mf][nf] = MFMA16(aF[mf], bF, acc[mf][nf]);
      }
    }
  }

  // epilogue -> Out[ox][co-swizzled] -> interleaved global [b][oy][ch][px][ci8]
  __syncthreads();
  float bv[4];
  #pragma unroll
  for (int nf = 0; nf < 4; ++nf) bv[nf] = bias[wc*64 + nf*16 + col_l];
  #pragma unroll
  for (int mf = 0; mf < 4; ++mf)
  #pragma unroll
  for (int nf = 0; nf < 4; ++nf) {
    int co = wc*64 + nf*16 + col_l;
    #pragma unroll
    for (int r = 0; r < 4; ++r) {
      int tx = tx_base + mf*16 + kg*4 + r;
      float v = fmaxf(acc[mf][nf][r] + bv[nf], 0.f);
      int ox = 2*tx + f;
      sm.Out[ox][co ^ (((ox>>3)&7)<<3)] = bfbits(v);
    }
  }
  __syncthreads();
  const int oy = 2*ty + e;
  #pragma unroll
  for (int j = 0; j < 8; ++j) {
    int i = tid + j*NTHR;
    int px = i & (2*TX-1), chn = i / (2*TX);
    uint4 vv = *(const uint4*)&sm.Out[px][(chn*8) ^ (((px>>3)&7)<<3)];
    *(uint4*)(yI + ((((long)b*(2*TX) + oy)*16 + chn)*(2*TX) + px)*8) = vv;
  }
}

// ---------------- deconv3: MFMA, s1 k3 p1, 128->3(pad16) + sigmoid, interleaved in ----------
__global__ __launch_bounds__(256, 2) void deconv3_mfma(
    const unsigned short* __restrict__ g2I,  // [4][row256][ch16][px256][ci8]
    const unsigned short* __restrict__ w2,   // [co16][1536]
    const float* __restrict__ bias, float* __restrict__ y) {
  __shared__ __align__(16) unsigned short sA[3][260][8];
  __shared__ __align__(16) unsigned short sB[16*12*16*8];
  const int tid = threadIdx.x;
  const int oy = blockIdx.x, b = blockIdx.y;
  const int wave = tid >> 6, lane = tid & 63;
  const int col_l = lane & 15, kg = lane >> 4;
  const int pxb = wave*64;
  for (int i = tid; i < 3072; i += 256) {
    int co = i & 15, tap = (i>>4) % 12, ch = i/192;
    *(uint4*)&sB[((ch*12+tap)*16+co)*8] = *(const uint4*)(w2 + (long)co*1536 + ch*96 + tap*8);
  }
  if (tid < 12) {           // zero cols {0,1,258,259}
    int dy = tid >> 2, c = tid & 3;
    *(uint4*)&sA[dy][(c<2)?c:(256+c)][0] = zero4();
  }
  // A prefetch: 3 units
  long aBase[3]; int aLdsO[3]; bool aOk[3];
  #pragma unroll
  for (int u = 0; u < 3; ++u) {
    int idx = tid + u*256;
    int px = idx & 255, dy = idx >> 8;
    int iy = oy - 1 + dy;
    aOk[u] = (iy >= 0 && iy < 256);
    aBase[u] = ((long)(b*256 + (aOk[u]?iy:0)))*32768 + px*8;
    aLdsO[u] = (dy*260 + px + 2)*8;
  }
  uint4 pA[3];
  #pragma unroll
  for (int u=0;u<3;u++) pA[u] = aOk[u] ? *(const uint4*)(g2I + aBase[u]) : zero4();

  unsigned short* sAf = &sA[0][0][0];
  f32x4 acc[4] = {};
  for (int ch = 0; ch < 16; ++ch) {
    __syncthreads();
    #pragma unroll
    for (int u=0;u<3;u++) *(uint4*)(sAf + aLdsO[u]) = pA[u];
    if (ch < 15) {
      #pragma unroll
      for (int u=0;u<3;u++)
        pA[u] = aOk[u] ? *(const uint4*)(g2I + aBase[u] + (ch+1)*2048) : zero4();
    }
    __syncthreads();
    #pragma unroll
    for (int s = 0; s < 3; ++s) {      // s = ky
      bf16x8 bF = *(const bf16x8*)&sB[((ch*12 + s*4 + kg)*16 + col_l)*8];
      #pragma unroll
      for (int mf = 0; mf < 4; ++mf) {
        int px = pxb + mf*16 + col_l;
        bf16x8 aF = *(const bf16x8*)&sA[2-s][px + 3 - kg][0];
        acc[mf] = MFMA16(aF, bF, acc[mf]);
      }
    }
  }
  if (col_l < 3) {
    float bv = bias[col_l];
    #pragma unroll
    for (int mf = 0; mf < 4; ++mf) {
      int px = pxb + mf*16 + kg*4;
      float4 o;
      o.x = 1.f/(1.f + expf(-(acc[mf][0] + bv)));
      o.y = 1.f/(1.f + expf(-(acc[mf][1] + bv)));
      o.z = 1.f/(1.f + expf(-(acc[mf][2] + bv)));
      o.w = 1.f/(1.f + expf(-(acc[mf][3] + bv)));
      *(float4*)(y + ((long)(b*3 + col_l)*256 + oy)*256 + px) = o;
    }
  }
}

// ---------------- vector quantizer: 4 threads/row ----------------
__global__ __launch_bounds__(256, 4) void vq_kernel(
    const float* __restrict__ ze, const float* __restrict__ emb,
    float* __restrict__ out_idx, float* __restrict__ zq) {
  __shared__ __align__(16) float se[128][68];
  __shared__ float sn[128];
  const int tid = threadIdx.x;
  const int row = tid >> 2, sub = tid & 3;
  const long n = (long)blockIdx.x*64 + row;
  float4 rv[16];
  const float4* zr = (const float4*)(ze + n*64);
  #pragma unroll
  for (int q=0;q<16;q++) rv[q] = zr[q];
  float best = 3.4e38f; int bidx = 0;
  for (int ch=0; ch<4; ch++) {
    __syncthreads();
    for (int i = tid; i < 2048; i += 256) {
      int k = i >> 4, q = i & 15;
      *(float4*)&se[k][q*4] = *(const float4*)(emb + ((long)ch*128 + k)*64 + q*4);
    }
    __syncthreads();
    if (tid < 128) {
      float s = 0.f;
      const float4* ev = (const float4*)&se[tid][0];
      #pragma unroll
      for (int q=0;q<16;q++){ float4 e4 = ev[q];
        s += e4.x*e4.x + e4.y*e4.y + e4.z*e4.z + e4.w*e4.w; }
      sn[tid] = s;
    }
    __syncthreads();
    for (int kk = 0; kk < 32; ++kk) {
      int k = kk*4 + sub;
      const float4* ev = (const float4*)&se[k][0];
      float dot = 0.f;
      #pragma unroll
      for (int q=0;q<16;q++){
        float4 e4 = ev[q];
        dot += rv[q].x*e4.x + rv[q].y*e4.y + rv[q].z*e4.z + rv[q].w*e4.w;
      }
      float s = sn[k] - 2.f*dot;
      if (s < best) { best = s; bidx = ch*128 + k; }
    }
  }
  #pragma unroll
  for (int off = 1; off < 4; off <<= 1) {
    float ob = __shfl_xor(best, off);
    int oi = __shfl_xor(bidx, off);
    if (ob < best || (ob == best && oi < bidx)) { best = ob; bidx = oi; }
  }
  if (sub == 0) out_idx[n] = (float)bidx;
  const float4* eb = (const float4*)(emb + (long)bidx*64);
  float4* zo = (float4*)(zq + n*64);
  #pragma unroll
  for (int q=0;q<4;q++) zo[sub*4+q] = eb[sub*4+q];
}

// ---------------- launch ----------------
extern "C" void kernel_launch(void* const* d_in, const int* in_sizes, int n_in,
                              void* d_out, int out_size, void* d_ws, size_t ws_size,
                              hipStream_t stream) {
  const float* x   = (const float*)d_in[0];
  const float* c1w = (const float*)d_in[1];  const float* c1b = (const float*)d_in[2];
  const float* c2w = (const float*)d_in[3];  const float* c2b = (const float*)d_in[4];
  const float* c3w = (const float*)d_in[5];  const float* c3b = (const float*)d_in[6];
  const float* emb = (const float*)d_in[7];
  const float* d1w = (const float*)d_in[8];  const float* d1b = (const float*)d_in[9];
  const float* d2w = (const float*)d_in[10]; const float* d2b = (const float*)d_in[11];
  const float* d3w = (const float*)d_in[12]; const float* d3b = (const float*)d_in[13];
  float* out = (float*)d_out;

  float* xrec = out;
  float* oidx = out + 3145728;
  float* zq   = out + 3211264;

  const long XB  = 196608;   // 3*256*256
  const long ZEB = 262144;   // 64*64*64
  const long PS1 = 8388608;  // per-plane h1 (4b, interleaved) in shorts
  const long PS2 = 4194304;  // per-plane h2 (8b) in shorts

  const size_t NEEDED = 112074752ULL;  // known: ws_size >= 120,395,264
  if (ws_size < NEEDED) return;
  char* wsb = (char*)d_ws;
  unsigned short* h1grp = (unsigned short*)wsb;              // interleaved, 50.3MB
  unsigned short* g2grp = (unsigned short*)wsb;              // interleaved, 64MB
  unsigned short* h2grp = (unsigned short*)(wsb + 67108864); // planar 3-plane, 24MB
  unsigned short* g1grp = (unsigned short*)(wsb + 67108864); // interleaved, 16MB
  float* ze = (float*)(wsb + 92274688);
  char* W = wsb + 109051904;
  float* w2c1          = (float*)(W);
  unsigned short* w2c2 = (unsigned short*)(W + 24576);
  unsigned short* w2c3 = (unsigned short*)(W + 1597440);
  unsigned short* w2d1 = (unsigned short*)(W + 2187264);
  unsigned short* w2d2 = (unsigned short*)(W + 2449408);
  unsigned short* w2d3 = (unsigned short*)(W + 2973696);

  wtrans_conv       <<<24,   256, 0, stream>>>(c1w, w2c1, 128, 3, 16);
  wprep_conv2_mfma  <<<1024, 256, 0, stream>>>(c2w, w2c2);
  wprep_conv3_mfma  <<<384,  256, 0, stream>>>(c3w, w2c3);
  wprep_deconv_mfma <<<512,  256, 0, stream>>>(d1w, w2d1, 64);
  wprep_deconv_mfma <<<1024, 256, 0, stream>>>(d2w, w2d2, 128);
  wprep_deconv3_mfma<<<96,   256, 0, stream>>>(d3w, w2d3);

  // encoder
  for (int g = 0; g < 4; ++g) {
    conv1_split<<<dim3(16,16,8), 256, 0, stream>>>(
        x + (long)g*4*XB, w2c1, c1b, h1grp, PS1);
    conv2_mfma<<<dim3(64,2,4), 256, 0, stream>>>(
        h1grp, PS1, w2c2, c2b, h2grp + (long)(g&1)*4*524288, PS2);
    if (g & 1)
      conv3_mfma<<<dim3(64,1,8), 256, 0, stream>>>(
          h2grp, PS2, w2c3, c3b, ze + (long)(g>>1)*8*ZEB);
  }
  vq_kernel<<<1024, 256, 0, stream>>>(ze, emb, oidx, zq);

  // decoder
  for (int g = 0; g < 4; ++g) {
    deconv_mfma<64, 64, 0 ><<<dim3(64, 2, 4), 256, 0, stream>>>(
        (const void*)(zq + (long)g*4*ZEB), w2d1, d1b, g1grp);
    deconv_mfma<128,128,1 ><<<dim3(128,2,4), 512, 0, stream>>>(
        (const void*)g1grp, w2d2, d2b, g2grp);
    deconv3_mfma<<<dim3(256,4), 256, 0, stream>>>(
        g2grp, w2d3, d3b, xrec + (long)g*4*XB);
  }
}

// Round 7
// 1583.126 us; speedup vs baseline: 3.7767x; 1.0458x over previous
//
#include <hip/hip_runtime.h>
#include <hip/hip_bf16.h>

#define DEV __device__ __forceinline__

typedef __attribute__((ext_vector_type(8))) short bf16x8;
typedef __attribute__((ext_vector_type(4))) float f32x4;
typedef __attribute__((ext_vector_type(4))) unsigned short u16x4;

#define MFMA16(a,b,c) __builtin_amdgcn_mfma_f32_16x16x32_bf16(a,b,c,0,0,0)

DEV unsigned short bfbits(float v){ __hip_bfloat16 h = __float2bfloat16(v); return *(unsigned short*)&h; }
DEV float bf2f(unsigned short u){ __hip_bfloat16 h = *(__hip_bfloat16*)&u; return __bfloat162float(h); }
DEV void split3(float v, unsigned short& h, unsigned short& m, unsigned short& l) {
  h = bfbits(v);        float r  = v - bf2f(h);
  m = bfbits(r);        float r2 = r - bf2f(m);
  l = bfbits(r2);
}
DEV uint4 zero4(){ uint4 z; z.x=0; z.y=0; z.z=0; z.w=0; return z; }

// ---------------- fused weight prep (one dispatch, 3064 blocks) ----------------
DEV void prep_deconv12(int i, int CI, const float* __restrict__ w, unsigned short* __restrict__ w2) {
  const int K = CI*4;
  int k  = i % K;
  int co = (i / K) & 127;
  int f  = (i / (K*128)) & 1;
  int e  = i / (K*256);
  int ci = (k & 15) | ((k >> 6) << 4);
  int tap = (k >> 4) & 3, a = tap >> 1, b = tap & 1;
  float v = w[ (((long)ci*128 + co)*4 + (2*a+1-e))*4 + (2*b+1-f) ];
  w2[i] = bfbits(v);
}
__global__ __launch_bounds__(256) void wprep_all(
    const float* __restrict__ c1w, float* __restrict__ w2c1,
    const float* __restrict__ c2w, unsigned short* __restrict__ w2c2,
    const float* __restrict__ c3w, unsigned short* __restrict__ w2c3,
    const float* __restrict__ d1w, unsigned short* __restrict__ w2d1,
    const float* __restrict__ d2w, unsigned short* __restrict__ w2d2,
    const float* __restrict__ d3w, unsigned short* __restrict__ w2d3) {
  const int bx = blockIdx.x, t = threadIdx.x;
  if (bx < 24) {                         // conv1 transpose: 6144
    int i = bx*256 + t;
    if (i < 6144) {
      int tap = i & 15, ci = (i>>4) % 3, co = i / 48;
      w2c1[((long)ci*16 + tap)*128 + co] = c1w[i];
    }
  } else if (bx < 1048) {                // conv2 split prep: 262144
    int i = (bx-24)*256 + t;
    int k = i & 2047, co = i >> 11;
    int ch = k >> 7, rem = k & 127;
    int tap = rem >> 3, cil = rem & 7;
    int ci = ch*8 + cil, ky = tap >> 2, kx = tap & 3;
    float v = c2w[(((long)co*128 + ci)*4 + ky)*4 + kx];
    unsigned short h,m,l; split3(v,h,m,l);
    w2c2[i] = h; w2c2[i + 262144] = m; w2c2[i + 524288] = l;
  } else if (bx < 1432) {                // conv3 split prep: 98304
    int i = (bx-1048)*256 + t;
    int k = i % 1536, co = i / 1536;
    int ch = k / 96, rem = k % 96;
    int tap = rem >> 3, cil = rem & 7;
    int ci = ch*8 + cil, ky = tap >> 2, kx = tap & 3;
    float v = (kx < 3) ? c3w[(((long)co*128 + ci)*3 + ky)*3 + kx] : 0.f;
    unsigned short h,m,l; split3(v,h,m,l);
    w2c3[i] = h; w2c3[i + 98304] = m; w2c3[i + 196608] = l;
  } else if (bx < 1944) {                // deconv1: 131072 (CI=64)
    prep_deconv12((bx-1432)*256 + t, 64, d1w, w2d1);
  } else if (bx < 2968) {                // deconv2: 262144 (CI=128)
    prep_deconv12((bx-1944)*256 + t, 128, d2w, w2d2);
  } else {                               // deconv3: 24576
    int i = (bx-2968)*256 + t;
    if (i < 24576) {
      int k = i % 1536, co = i / 1536;
      int ch = k / 96, rem = k % 96;
      int tap = rem >> 3, cil = rem & 7;
      int ci = ch*8 + cil, ky = tap >> 2, kx = tap & 3;
      float v = (co < 3 && kx < 3) ? d3w[(((long)ci*3 + co)*3 + ky)*3 + kx] : 0.f;
      w2d3[i] = bfbits(v);
    }
  }
}

// ---------------- conv1: f32 direct, out 3 bf16 planes INTERLEAVED [b][row][ch][px][ci8] ----
__global__ __launch_bounds__(256) void conv1_split(
    const float* __restrict__ x, const float* __restrict__ w2,
    const float* __restrict__ bias, unsigned short* __restrict__ h1, long PS1) {
  __shared__ __align__(16) float sIn[3][18][20];
  __shared__ __align__(16) float sW[3*16*64];
  const int tid = threadIdx.x;
  const int b = blockIdx.z >> 1, cog = blockIdx.z & 1;
  const int co0 = cog*64;
  const int oy0 = blockIdx.y*8, ox0 = blockIdx.x*8;
  const int cg2 = tid >> 5;            // 8-co block
  const int pg2 = tid & 31;
  const int r = pg2 >> 2, pxp = (pg2 & 3)*2;
  float acc[8][2];
  #pragma unroll
  for (int c=0;c<8;c++){ float bv = bias[co0 + cg2*8 + c];
    acc[c][0]=bv; acc[c][1]=bv; }
  const float* xb = x + (long)b*3*256*256;
  const int iy0 = 2*oy0 - 1, ix0 = 2*ox0 - 1;
  for (int t=tid; t<3*18*18; t+=256) {
    int xx = t%18, yy=(t/18)%18, ci=t/324;
    int gy = iy0+yy, gx = ix0+xx;
    float v = 0.f;
    if (gy>=0 && gy<256 && gx>=0 && gx<256) v = xb[((long)ci*256+gy)*256+gx];
    sIn[ci][yy][xx] = v;
  }
  for (int t=tid; t<3*16*64; t+=256) {
    sW[t] = w2[(long)(t>>6)*128 + co0 + (t&63)];
  }
  __syncthreads();
  for (int ci=0; ci<3; ci++) {
    #pragma unroll
    for (int ky=0;ky<4;ky++)
    #pragma unroll
    for (int kx=0;kx<4;kx++) {
      const float* wp = &sW[(ci*16 + ky*4+kx)*64 + cg2*8];
      float4 w0 = *(const float4*)wp;
      float4 w1 = *(const float4*)(wp+4);
      const int yy = 2*r + ky;
      #pragma unroll
      for (int p=0;p<2;p++) {
        float iv = sIn[ci][yy][2*(pxp+p)+kx];
        acc[0][p] += w0.x*iv; acc[1][p] += w0.y*iv;
        acc[2][p] += w0.z*iv; acc[3][p] += w0.w*iv;
        acc[4][p] += w1.x*iv; acc[5][p] += w1.y*iv;
        acc[6][p] += w1.z*iv; acc[7][p] += w1.w*iv;
      }
    }
  }
  const int chg = cog*8 + cg2;
  #pragma unroll
  for (int p=0;p<2;p++) {
    unsigned short th[8], tm[8], tl[8];
    #pragma unroll
    for (int c=0;c<8;c++) {
      float v = fmaxf(acc[c][p], 0.f);
      split3(v, th[c], tm[c], tl[c]);
    }
    long base = (((long)(b*128 + oy0+r)*16 + chg)*128 + ox0+pxp+p)*8;
    *(uint4*)(h1 + base)          = *(uint4*)th;
    *(uint4*)(h1 + PS1 + base)    = *(uint4*)tm;
    *(uint4*)(h1 + 2*PS1 + base)  = *(uint4*)tl;
  }
}

// ---------------- conv2: MFMA 6-term split, k4 s2 p1, interleaved input, prefetch ----------
__global__ __launch_bounds__(256, 2) void conv2_mfma(
    const unsigned short* __restrict__ h1, long PS1,
    const unsigned short* __restrict__ w2,
    const float* __restrict__ bias,
    unsigned short* __restrict__ h2, long PS2) {
  __shared__ __align__(16) unsigned short sA[3][4][130][8];
  __shared__ __align__(16) unsigned short sB[3*64*16*8];
  const int tid = threadIdx.x;
  const int oy = blockIdx.x, cog = blockIdx.y, b = blockIdx.z;
  const int wave = tid >> 6, lane = tid & 63;
  const int wr = wave >> 1, wc = wave & 1;
  const int col_l = lane & 15, kg = lane >> 4;
  const int iy0 = 2*oy - 1;
  f32x4 acc[2][2] = {};
  unsigned short* sAf = &sA[0][0][0][0];

  // prefetch descriptors
  int aOff[6], aLdsO[6]; bool aOk[6];
  #pragma unroll
  for (int j = 0; j < 6; ++j) {
    int idx = tid + j*256;
    int px = idx & 127, rr = (idx >> 7) & 3, pl = idx >> 9;
    int iy = iy0 + rr;
    aOk[j] = (iy >= 0 && iy < 128);
    aOff[j] = (int)(pl*PS1 + (long)(b*128 + (aOk[j]?iy:0))*16384 + px*8);
    aLdsO[j] = ((pl*4 + rr)*130 + px + 1)*8;
  }
  int bOff[12], bLdsO[12];
  #pragma unroll
  for (int j = 0; j < 12; ++j) {
    int i = tid + j*256;
    int s = i & 15, co = (i >> 4) & 63, pl = i >> 10;
    bOff[j] = (pl*128 + cog*64 + co)*2048 + s*8;
    bLdsO[j] = ((pl*64 + co)*16 + (s ^ (co & 15)))*8;
  }
  uint4 pA[6], pB[12];
  #pragma unroll
  for (int j=0;j<6;j++)  pA[j] = aOk[j] ? *(const uint4*)(h1 + aOff[j]) : zero4();
  #pragma unroll
  for (int j=0;j<12;j++) pB[j] = *(const uint4*)(w2 + bOff[j]);

  if (tid < 24) {       // zero pad slots col 0 and 129
    int pl = tid>>3, rr=(tid>>1)&3, c=tid&1;
    *(uint4*)&sA[pl][rr][c?129:0][0] = zero4();
  }

  for (int ch = 0; ch < 16; ++ch) {
    __syncthreads();
    #pragma unroll
    for (int j=0;j<6;j++)  *(uint4*)(sAf + aLdsO[j]) = pA[j];
    #pragma unroll
    for (int j=0;j<12;j++) *(uint4*)(&sB[bLdsO[j]]) = pB[j];
    if (ch < 15) {
      #pragma unroll
      for (int j=0;j<6;j++)  pA[j] = aOk[j] ? *(const uint4*)(h1 + aOff[j] + (ch+1)*1024) : zero4();
      #pragma unroll
      for (int j=0;j<12;j++) pB[j] = *(const uint4*)(w2 + bOff[j] + (ch+1)*128);
    }
    __syncthreads();
    #pragma unroll
    for (int s = 0; s < 4; ++s) {        // s = ky
      bf16x8 aF[2][3]; bf16x8 bF[2][3];
      const int tap = s*4 + kg;
      #pragma unroll
      for (int mf = 0; mf < 2; ++mf) {
        int ox = wr*32 + mf*16 + col_l;
        #pragma unroll
        for (int pl = 0; pl < 3; ++pl)
          aF[mf][pl] = *(const bf16x8*)&sA[pl][s][2*ox + kg][0];
      }
      #pragma unroll
      for (int nf = 0; nf < 2; ++nf) {
        int co = wc*32 + nf*16 + col_l;
        int ba = (co*16 + (tap ^ (co&15)))*8;
        bF[nf][0] = *(const bf16x8*)&sB[ba];
        bF[nf][1] = *(const bf16x8*)&sB[ba + 8192];
        bF[nf][2] = *(const bf16x8*)&sB[ba + 16384];
      }
      __builtin_amdgcn_s_setprio(1);
      #pragma unroll
      for (int mf = 0; mf < 2; ++mf)
      #pragma unroll
      for (int nf = 0; nf < 2; ++nf) {
        f32x4 a = acc[mf][nf];
        a = MFMA16(aF[mf][0], bF[nf][0], a);
        a = MFMA16(aF[mf][0], bF[nf][1], a);
        a = MFMA16(aF[mf][1], bF[nf][0], a);
        a = MFMA16(aF[mf][0], bF[nf][2], a);
        a = MFMA16(aF[mf][2], bF[nf][0], a);
        a = MFMA16(aF[mf][1], bF[nf][1], a);
        acc[mf][nf] = a;
      }
      __builtin_amdgcn_s_setprio(0);
    }
  }
  // epilogue: h2 stays 3-plane planar (conv3 consumes it)
  #pragma unroll
  for (int nf = 0; nf < 2; ++nf) {
    int co = cog*64 + wc*32 + nf*16 + col_l;
    float bv = bias[co];
    #pragma unroll
    for (int mf = 0; mf < 2; ++mf) {
      int px0 = wr*32 + mf*16 + kg*4;
      u16x4 oh, om, ol;
      #pragma unroll
      for (int r = 0; r < 4; ++r) {
        float v = fmaxf(acc[mf][nf][r] + bv, 0.f);
        unsigned short h,m,l; split3(v,h,m,l);
        oh[r]=h; om[r]=m; ol[r]=l;
      }
      long base = ((long)(b*128 + co)*64 + oy)*64 + px0;
      *(u16x4*)(h2 + base) = oh;
      *(u16x4*)(h2 + PS2 + base) = om;
      *(u16x4*)(h2 + 2*PS2 + base) = ol;
    }
  }
}

// ---------------- conv3: MFMA 6-term split, k3 s1 p1, 128->64, prefetch ----------------
__global__ __launch_bounds__(256, 2) void conv3_mfma(
    const unsigned short* __restrict__ h2, long PS2,
    const unsigned short* __restrict__ w2,
    const float* __restrict__ bias, float* __restrict__ ze) {
  __shared__ __align__(16) unsigned short sA[3*67*24];
  __shared__ __align__(16) unsigned short sB[3*64*16*8];
  const int tid = threadIdx.x;
  const int oy = blockIdx.x, b = blockIdx.z;
  const int wave = tid >> 6, lane = tid & 63;
  const int wr = wave >> 1, wc = wave & 1;
  const int col_l = lane & 15, kg = lane >> 4;
  f32x4 acc[2][2] = {};
  for (int i = tid; i < 3*3*24; i += 256) {
    int j = i % 24, c = (i/24) % 3, rr = i/72;
    int col = (c==0) ? 0 : (c==1 ? 65 : 66);
    sA[(rr*67 + col)*24 + j] = 0;
  }
  // prefetch descriptors
  const int li = tid & 7, rrA = (tid>>3)%3, ciA = tid/24;
  const int iyA = oy + rrA - 1;
  const bool aAct = (tid < 192);
  const bool aOk = aAct && (iyA >= 0 && iyA < 64);
  const long aBase = ((long)(b*128 + ciA)*64 + (aOk?iyA:0))*64 + li*8;
  int bOff[9], bLdsO[9];
  #pragma unroll
  for (int j = 0; j < 9; ++j) {
    int i = tid + j*256;
    int s = i % 12, co = (i/12) & 63, pl = i/768;
    bOff[j] = (pl*64 + co)*1536 + s*8;
    bLdsO[j] = ((pl*64 + co)*16 + (s ^ (co & 15)))*8;
  }
  uint4 ph, pm, pl4, pB[9];
  ph = aOk ? *(const uint4*)(h2 + aBase) : zero4();
  pm = aOk ? *(const uint4*)(h2 + PS2 + aBase) : zero4();
  pl4 = aOk ? *(const uint4*)(h2 + 2*PS2 + aBase) : zero4();
  #pragma unroll
  for (int j=0;j<9;j++) pB[j] = *(const uint4*)(w2 + bOff[j]);

  for (int ch = 0; ch < 16; ++ch) {
    __syncthreads();
    if (aAct) {
      const unsigned short* vh = (const unsigned short*)&ph;
      const unsigned short* vm = (const unsigned short*)&pm;
      const unsigned short* vl = (const unsigned short*)&pl4;
      #pragma unroll
      for (int p = 0; p < 8; ++p) {
        int pp = (p + li) & 7;
        int col = li*8 + pp + 1;
        int base = (rrA*67 + col)*24 + ciA;
        sA[base]      = vh[pp];
        sA[base + 8]  = vm[pp];
        sA[base + 16] = vl[pp];
      }
    }
    #pragma unroll
    for (int j=0;j<9;j++) *(uint4*)(&sB[bLdsO[j]]) = pB[j];
    if (ch < 15) {
      long nb = aBase + (long)(ch+1)*32768;
      ph = aOk ? *(const uint4*)(h2 + nb) : zero4();
      pm = aOk ? *(const uint4*)(h2 + PS2 + nb) : zero4();
      pl4 = aOk ? *(const uint4*)(h2 + 2*PS2 + nb) : zero4();
      #pragma unroll
      for (int j=0;j<9;j++) pB[j] = *(const uint4*)(w2 + bOff[j] + (ch+1)*96);
    }
    __syncthreads();
    #pragma unroll
    for (int s = 0; s < 3; ++s) {
      bf16x8 aF[2][3]; bf16x8 bF[2][3];
      const int tap = s*4 + kg;
      #pragma unroll
      for (int mf = 0; mf < 2; ++mf) {
        int ox = wr*32 + mf*16 + col_l;
        int base = (s*67 + ox + kg)*24;
        aF[mf][0] = *(const bf16x8*)&sA[base];
        aF[mf][1] = *(const bf16x8*)&sA[base+8];
        aF[mf][2] = *(const bf16x8*)&sA[base+16];
      }
      #pragma unroll
      for (int nf = 0; nf < 2; ++nf) {
        int co = wc*32 + nf*16 + col_l;
        int ba = (co*16 + (tap ^ (co&15)))*8;
        bF[nf][0] = *(const bf16x8*)&sB[ba];
        bF[nf][1] = *(const bf16x8*)&sB[ba + 8192];
        bF[nf][2] = *(const bf16x8*)&sB[ba + 16384];
      }
      __builtin_amdgcn_s_setprio(1);
      #pragma unroll
      for (int mf = 0; mf < 2; ++mf)
      #pragma unroll
      for (int nf = 0; nf < 2; ++nf) {
        f32x4 a = acc[mf][nf];
        a = MFMA16(aF[mf][0], bF[nf][0], a);
        a = MFMA16(aF[mf][0], bF[nf][1], a);
        a = MFMA16(aF[mf][1], bF[nf][0], a);
        a = MFMA16(aF[mf][0], bF[nf][2], a);
        a = MFMA16(aF[mf][2], bF[nf][0], a);
        a = MFMA16(aF[mf][1], bF[nf][1], a);
        acc[mf][nf] = a;
      }
      __builtin_amdgcn_s_setprio(0);
    }
  }
  #pragma unroll
  for (int nf = 0; nf < 2; ++nf) {
    int co = wc*32 + nf*16 + col_l;
    float bv = bias[co];
    #pragma unroll
    for (int mf = 0; mf < 2; ++mf) {
      int px0 = wr*32 + mf*16 + kg*4;
      float4 o;
      o.x = acc[mf][nf][0] + bv; o.y = acc[mf][nf][1] + bv;
      o.z = acc[mf][nf][2] + bv; o.w = acc[mf][nf][3] + bv;
      *(float4*)(ze + ((long)(b*64 + co)*64 + oy)*64 + px0) = o;
    }
  }
}

// ---------------- MFMA ConvTranspose2d stride2 k4 pad1, prefetch, interleaved out ----------
// MODE 0: f32 planar input (stagger staging). MODE 1: bf16 interleaved input.
template<int TX, int MODE>
struct SmemD {
  union {
    struct { __align__(16) unsigned short In[2][TX+2][24];
             __align__(16) unsigned short W[2*128*64]; } o;
    struct { __align__(16) unsigned short In[2][TX+2][16];
             __align__(16) unsigned short W[2*128*64]; } v;
    __align__(16) unsigned short Out[2*TX][136];
  };
};

template<int CIN, int TX, int MODE>
__global__ __launch_bounds__(TX*4, (TX==64)?3:4) void deconv_mfma(
    const void* __restrict__ xin, const unsigned short* __restrict__ w2,
    const float* __restrict__ bias, unsigned short* __restrict__ yI) {
  constexpr int NTHR = TX*4;
  constexpr int K    = CIN*4;
  constexpr int NW   = 2048/NTHR;
  __shared__ SmemD<TX,MODE> sm;
  unsigned short* Wb = MODE ? &sm.v.W[0] : &sm.o.W[0];

  const int tid = threadIdx.x;
  const int ty = blockIdx.x, e = blockIdx.y, b = blockIdx.z;
  const int wave = tid >> 6, lane = tid & 63;
  const int wc = wave & 1, wr = wave >> 1;
  const int f = (wr*64) / TX;
  const int tx_base = (wr*64) & (TX-1);
  const int col_l = lane & 15, kg = lane >> 4;

  // W prefetch descriptors
  int wOff[NW], wLdsO[NW];
  #pragma unroll
  for (int j = 0; j < NW; ++j) {
    int i = tid + j*NTHR;
    int s = i & 7, co = (i >> 3) & 127, ff = i >> 10;
    wOff[j] = ((e*2+ff)*128 + co)*K + s*8;
    wLdsO[j] = (ff*128 + co)*64 + (s ^ (co & 7))*8;
  }
  uint4 pW[NW];
  #pragma unroll
  for (int j=0;j<NW;j++) pW[j] = *(const uint4*)(w2 + wOff[j]);

  // A prefetch descriptors
  constexpr int TPR = NTHR/32;
  const int rowid = tid / TPR, liO = tid % TPR;
  const int sci = rowid >> 1, srr = rowid & 1;
  float4 pLo, pHi; uint4 pIn;
  long aBase = 0; bool aOk = false;
  int pxV = 0, halfV = 0, rrV = 0;
  if (MODE == 0) {
    int iy = ty + e - 1 + srr;
    aOk = (iy >= 0 && iy < TX);
    aBase = ((long)b*CIN + sci)*TX*TX + (long)(aOk?iy:0)*TX + liO*8;
    if (aOk) { const float4* s4 = (const float4*)((const float*)xin + aBase);
               pLo = s4[0]; pHi = s4[1]; }
  } else {
    halfV = tid & 1; pxV = (tid >> 1) & (TX-1); rrV = tid >> 8;
    int iy = ty + e - 1 + rrV;
    aOk = (iy >= 0 && iy < TX);
    aBase = ((long)b*TX + (aOk?iy:0))*((long)(CIN/8)*TX*8) + (long)halfV*TX*8 + pxV*8;
    pIn = aOk ? *(const uint4*)((const unsigned short*)xin + aBase) : zero4();
  }

  // zero pads
  if (MODE == 0) {
    if (tid < 64) {
      int rr = tid & 1, cc = ((tid>>1)&1) ? TX+1 : 0, ci = tid >> 2;
      sm.o.In[rr][cc][ci] = 0;
    }
  } else {
    if (tid < 8) {
      int rr = tid & 1, c = (tid>>1)&1, hf = (tid>>2)&1;
      *(uint4*)&sm.v.In[rr][c?TX+1:0][hf*8] = zero4();
    }
  }

  f32x4 acc[4][4] = {};
  for (int ch = 0; ch < CIN/16; ++ch) {
    __syncthreads();
    if (MODE == 0) {
      unsigned short vals[8];
      if (aOk) {
        float4 lo = pLo, hi = pHi;
        vals[0]=bfbits(lo.x); vals[1]=bfbits(lo.y); vals[2]=bfbits(lo.z); vals[3]=bfbits(lo.w);
        vals[4]=bfbits(hi.x); vals[5]=bfbits(hi.y); vals[6]=bfbits(hi.z); vals[7]=bfbits(hi.w);
      } else {
        #pragma unroll
        for (int j=0;j<8;j++) vals[j] = 0;
      }
      #pragma unroll
      for (int j=0;j<8;j++) {
        int jj = (j + liO) & 7;
        sm.o.In[srr][1 + liO*8 + jj][sci] = vals[jj];
      }
    } else {
      *(uint4*)&sm.v.In[rrV][pxV+1][halfV*8] = pIn;
    }
    #pragma unroll
    for (int j=0;j<NW;j++) *(uint4*)(Wb + wLdsO[j]) = pW[j];
    if (ch + 1 < CIN/16) {
      if (MODE == 0) {
        if (aOk) { const float4* s4 = (const float4*)((const float*)xin + aBase + (long)(ch+1)*16*TX*TX);
                   pLo = s4[0]; pHi = s4[1]; }
      } else {
        pIn = aOk ? *(const uint4*)((const unsigned short*)xin + aBase + (ch+1)*2*TX*8) : zero4();
      }
      #pragma unroll
      for (int j=0;j<NW;j++) pW[j] = *(const uint4*)(w2 + wOff[j] + (ch+1)*64);
    }
    __syncthreads();
    #pragma unroll
    for (int kk = 0; kk < 2; ++kk) {
      bf16x8 aF[4];
      const int tap = kk*2 + (kg >> 1), a = tap >> 1, bb = tap & 1;
      #pragma unroll
      for (int mf = 0; mf < 4; ++mf) {
        int tx = tx_base + mf*16 + col_l;
        if (MODE == 0) aF[mf] = *(const bf16x8*)&sm.o.In[1-a][tx + 1 + f - bb][(kg&1)*8];
        else           aF[mf] = *(const bf16x8*)&sm.v.In[1-a][tx + 1 + f - bb][(kg&1)*8];
      }
      const int slot = kk*4 + kg;
      __builtin_amdgcn_s_setprio(1);
      #pragma unroll
      for (int nf = 0; nf < 4; ++nf) {
        int co_l = nf*16 + col_l;
        bf16x8 bF = *(const bf16x8*)(Wb + (f*128 + wc*64 + co_l)*64 + (slot ^ (co_l & 7))*8);
        #pragma unroll
        for (int mf = 0; mf < 4; ++mf)
          acc[mf][nf] = MFMA16(aF[mf], bF, acc[mf][nf]);
      }
      __builtin_amdgcn_s_setprio(0);
    }
  }

  // epilogue -> Out[ox][co-swizzled] -> interleaved global [b][oy][ch][px][ci8]
  __syncthreads();
  float bv[4];
  #pragma unroll
  for (int nf = 0; nf < 4; ++nf) bv[nf] = bias[wc*64 + nf*16 + col_l];
  #pragma unroll
  for (int mf = 0; mf < 4; ++mf)
  #pragma unroll
  for (int nf = 0; nf < 4; ++nf) {
    int co = wc*64 + nf*16 + col_l;
    #pragma unroll
    for (int r = 0; r < 4; ++r) {
      int tx = tx_base + mf*16 + kg*4 + r;
      float v = fmaxf(acc[mf][nf][r] + bv[nf], 0.f);
      int ox = 2*tx + f;
      sm.Out[ox][co ^ (((ox>>3)&7)<<3)] = bfbits(v);
    }
  }
  __syncthreads();
  const int oy = 2*ty + e;
  #pragma unroll
  for (int j = 0; j < 8; ++j) {
    int i = tid + j*NTHR;
    int px = i & (2*TX-1), chn = i / (2*TX);
    uint4 vv = *(const uint4*)&sm.Out[px][(chn*8) ^ (((px>>3)&7)<<3)];
    *(uint4*)(yI + ((((long)b*(2*TX) + oy)*16 + chn)*(2*TX) + px)*8) = vv;
  }
}

// ---------------- deconv3: MFMA, s1 k3 p1, 128->3(pad16) + sigmoid, interleaved in ----------
__global__ __launch_bounds__(256, 2) void deconv3_mfma(
    const unsigned short* __restrict__ g2I,  // [4][row256][ch16][px256][ci8]
    const unsigned short* __restrict__ w2,   // [co16][1536]
    const float* __restrict__ bias, float* __restrict__ y) {
  __shared__ __align__(16) unsigned short sA[3][260][8];
  __shared__ __align__(16) unsigned short sB[16*12*16*8];
  const int tid = threadIdx.x;
  const int oy = blockIdx.x, b = blockIdx.y;
  const int wave = tid >> 6, lane = tid & 63;
  const int col_l = lane & 15, kg = lane >> 4;
  const int pxb = wave*64;
  for (int i = tid; i < 3072; i += 256) {
    int co = i & 15, tap = (i>>4) % 12, ch = i/192;
    *(uint4*)&sB[((ch*12+tap)*16+co)*8] = *(const uint4*)(w2 + (long)co*1536 + ch*96 + tap*8);
  }
  if (tid < 12) {           // zero cols {0,1,258,259}
    int dy = tid >> 2, c = tid & 3;
    *(uint4*)&sA[dy][(c<2)?c:(256+c)][0] = zero4();
  }
  // A prefetch: 3 units
  long aBase[3]; int aLdsO[3]; bool aOk[3];
  #pragma unroll
  for (int u = 0; u < 3; ++u) {
    int idx = tid + u*256;
    int px = idx & 255, dy = idx >> 8;
    int iy = oy - 1 + dy;
    aOk[u] = (iy >= 0 && iy < 256);
    aBase[u] = ((long)(b*256 + (aOk[u]?iy:0)))*32768 + px*8;
    aLdsO[u] = (dy*260 + px + 2)*8;
  }
  uint4 pA[3];
  #pragma unroll
  for (int u=0;u<3;u++) pA[u] = aOk[u] ? *(const uint4*)(g2I + aBase[u]) : zero4();

  unsigned short* sAf = &sA[0][0][0];
  f32x4 acc[4] = {};
  for (int ch = 0; ch < 16; ++ch) {
    __syncthreads();
    #pragma unroll
    for (int u=0;u<3;u++) *(uint4*)(sAf + aLdsO[u]) = pA[u];
    if (ch < 15) {
      #pragma unroll
      for (int u=0;u<3;u++)
        pA[u] = aOk[u] ? *(const uint4*)(g2I + aBase[u] + (ch+1)*2048) : zero4();
    }
    __syncthreads();
    #pragma unroll
    for (int s = 0; s < 3; ++s) {      // s = ky
      bf16x8 bF = *(const bf16x8*)&sB[((ch*12 + s*4 + kg)*16 + col_l)*8];
      __builtin_amdgcn_s_setprio(1);
      #pragma unroll
      for (int mf = 0; mf < 4; ++mf) {
        int px = pxb + mf*16 + col_l;
        bf16x8 aF = *(const bf16x8*)&sA[2-s][px + 3 - kg][0];
        acc[mf] = MFMA16(aF, bF, acc[mf]);
      }
      __builtin_amdgcn_s_setprio(0);
    }
  }
  if (col_l < 3) {
    float bv = bias[col_l];
    #pragma unroll
    for (int mf = 0; mf < 4; ++mf) {
      int px = pxb + mf*16 + kg*4;
      float4 o;
      o.x = 1.f/(1.f + expf(-(acc[mf][0] + bv)));
      o.y = 1.f/(1.f + expf(-(acc[mf][1] + bv)));
      o.z = 1.f/(1.f + expf(-(acc[mf][2] + bv)));
      o.w = 1.f/(1.f + expf(-(acc[mf][3] + bv)));
      *(float4*)(y + ((long)(b*3 + col_l)*256 + oy)*256 + px) = o;
    }
  }
}

// ---------------- vector quantizer: 4 threads/row, 2 codes/iter, 8 FMA chains ----------------
__global__ __launch_bounds__(256, 4) void vq_kernel(
    const float* __restrict__ ze, const float* __restrict__ emb,
    float* __restrict__ out_idx, float* __restrict__ zq) {
  __shared__ __align__(16) float se[128][68];
  __shared__ float sn[128];
  const int tid = threadIdx.x;
  const int row = tid >> 2, sub = tid & 3;
  const long n = (long)blockIdx.x*64 + row;
  float4 rv[16];
  const float4* zr = (const float4*)(ze + n*64);
  #pragma unroll
  for (int q=0;q<16;q++) rv[q] = zr[q];
  float best = 3.4e38f; int bidx = 0;
  for (int ch=0; ch<4; ch++) {
    __syncthreads();
    for (int i = tid; i < 2048; i += 256) {
      int k = i >> 4, q = i & 15;
      *(float4*)&se[k][q*4] = *(const float4*)(emb + ((long)ch*128 + k)*64 + q*4);
    }
    __syncthreads();
    if (tid < 128) {
      float s = 0.f;
      const float4* ev = (const float4*)&se[tid][0];
      #pragma unroll
      for (int q=0;q<16;q++){ float4 e4 = ev[q];
        s += e4.x*e4.x + e4.y*e4.y + e4.z*e4.z + e4.w*e4.w; }
      sn[tid] = s;
    }
    __syncthreads();
    for (int kk = 0; kk < 16; ++kk) {
      const int k0 = kk*8 + sub*2;          // this thread: codes k0, k0+1 (ascending)
      const float4* e0 = (const float4*)&se[k0][0];
      const float4* e1 = (const float4*)&se[k0+1][0];
      float a0=0.f,a1=0.f,a2=0.f,a3=0.f;
      float c0=0.f,c1=0.f,c2=0.f,c3=0.f;
      #pragma unroll
      for (int q=0;q<4;q++) {
        float4 r0=rv[4*q], r1=rv[4*q+1], r2=rv[4*q+2], r3=rv[4*q+3];
        float4 x0=e0[4*q], x1=e0[4*q+1], x2=e0[4*q+2], x3=e0[4*q+3];
        float4 y0=e1[4*q], y1=e1[4*q+1], y2=e1[4*q+2], y3=e1[4*q+3];
        a0 += r0.x*x0.x + r0.y*x0.y + r0.z*x0.z + r0.w*x0.w;
        a1 += r1.x*x1.x + r1.y*x1.y + r1.z*x1.z + r1.w*x1.w;
        a2 += r2.x*x2.x + r2.y*x2.y + r2.z*x2.z + r2.w*x2.w;
        a3 += r3.x*x3.x + r3.y*x3.y + r3.z*x3.z + r3.w*x3.w;
        c0 += r0.x*y0.x + r0.y*y0.y + r0.z*y0.z + r0.w*y0.w;
        c1 += r1.x*y1.x + r1.y*y1.y + r1.z*y1.z + r1.w*y1.w;
        c2 += r2.x*y2.x + r2.y*y2.y + r2.z*y2.z + r2.w*y2.w;
        c3 += r3.x*y3.x + r3.y*y3.y + r3.z*y3.z + r3.w*y3.w;
      }
      float s0 = sn[k0]   - 2.f*(((a0+a1)+(a2+a3)));
      float s1 = sn[k0+1] - 2.f*(((c0+c1)+(c2+c3)));
      if (s0 < best) { best = s0; bidx = ch*128 + k0; }
      if (s1 < best) { best = s1; bidx = ch*128 + k0 + 1; }
    }
  }
  #pragma unroll
  for (int off = 1; off < 4; off <<= 1) {
    float ob = __shfl_xor(best, off);
    int oi = __shfl_xor(bidx, off);
    if (ob < best || (ob == best && oi < bidx)) { best = ob; bidx = oi; }
  }
  if (sub == 0) out_idx[n] = (float)bidx;
  const float4* eb = (const float4*)(emb + (long)bidx*64);
  float4* zo = (float4*)(zq + n*64);
  #pragma unroll
  for (int q=0;q<4;q++) zo[sub*4+q] = eb[sub*4+q];
}

// ---------------- launch ----------------
extern "C" void kernel_launch(void* const* d_in, const int* in_sizes, int n_in,
                              void* d_out, int out_size, void* d_ws, size_t ws_size,
                              hipStream_t stream) {
  const float* x   = (const float*)d_in[0];
  const float* c1w = (const float*)d_in[1];  const float* c1b = (const float*)d_in[2];
  const float* c2w = (const float*)d_in[3];  const float* c2b = (const float*)d_in[4];
  const float* c3w = (const float*)d_in[5];  const float* c3b = (const float*)d_in[6];
  const float* emb = (const float*)d_in[7];
  const float* d1w = (const float*)d_in[8];  const float* d1b = (const float*)d_in[9];
  const float* d2w = (const float*)d_in[10]; const float* d2b = (const float*)d_in[11];
  const float* d3w = (const float*)d_in[12]; const float* d3b = (const float*)d_in[13];
  float* out = (float*)d_out;

  float* xrec = out;
  float* oidx = out + 3145728;
  float* zq   = out + 3211264;

  const long XB  = 196608;   // 3*256*256
  const long ZEB = 262144;   // 64*64*64
  const long PS1 = 8388608;  // per-plane h1 (4b, interleaved) in shorts
  const long PS2 = 4194304;  // per-plane h2 (8b) in shorts

  const size_t NEEDED = 112074752ULL;  // known: ws_size >= 120,395,264
  if (ws_size < NEEDED) return;
  char* wsb = (char*)d_ws;
  unsigned short* h1grp = (unsigned short*)wsb;              // interleaved, 50.3MB
  unsigned short* g2grp = (unsigned short*)wsb;              // interleaved, 64MB
  unsigned short* h2grp = (unsigned short*)(wsb + 67108864); // planar 3-plane, 24MB
  unsigned short* g1grp = (unsigned short*)(wsb + 67108864); // interleaved, 16MB
  float* ze = (float*)(wsb + 92274688);
  char* W = wsb + 109051904;
  float* w2c1          = (float*)(W);
  unsigned short* w2c2 = (unsigned short*)(W + 24576);
  unsigned short* w2c3 = (unsigned short*)(W + 1597440);
  unsigned short* w2d1 = (unsigned short*)(W + 2187264);
  unsigned short* w2d2 = (unsigned short*)(W + 2449408);
  unsigned short* w2d3 = (unsigned short*)(W + 2973696);

  // single fused weight-prep dispatch
  wprep_all<<<3064, 256, 0, stream>>>(c1w, w2c1, c2w, w2c2, c3w, w2c3,
                                      d1w, w2d1, d2w, w2d2, d3w, w2d3);

  // encoder
  for (int g = 0; g < 4; ++g) {
    conv1_split<<<dim3(16,16,8), 256, 0, stream>>>(
        x + (long)g*4*XB, w2c1, c1b, h1grp, PS1);
    conv2_mfma<<<dim3(64,2,4), 256, 0, stream>>>(
        h1grp, PS1, w2c2, c2b, h2grp + (long)(g&1)*4*524288, PS2);
    if (g & 1)
      conv3_mfma<<<dim3(64,1,8), 256, 0, stream>>>(
          h2grp, PS2, w2c3, c3b, ze + (long)(g>>1)*8*ZEB);
  }
  vq_kernel<<<1024, 256, 0, stream>>>(ze, emb, oidx, zq);

  // decoder
  for (int g = 0; g < 4; ++g) {
    deconv_mfma<64, 64, 0 ><<<dim3(64, 2, 4), 256, 0, stream>>>(
        (const void*)(zq + (long)g*4*ZEB), w2d1, d1b, g1grp);
    deconv_mfma<128,128,1 ><<<dim3(128,2,4), 512, 0, stream>>>(
        (const void*)g1grp, w2d2, d2b, g2grp);
    deconv3_mfma<<<dim3(256,4), 256, 0, stream>>>(
        g2grp, w2d3, d3b, xrec + (long)g*4*XB);
  }
}

// Round 8
// 1494.955 us; speedup vs baseline: 3.9995x; 1.0590x over previous
//
#include <hip/hip_runtime.h>
#include <hip/hip_bf16.h>

#define DEV __device__ __forceinline__

typedef __attribute__((ext_vector_type(8))) short bf16x8;
typedef __attribute__((ext_vector_type(4))) float f32x4;
typedef __attribute__((ext_vector_type(4))) unsigned short u16x4;

#define MFMA16(a,b,c) __builtin_amdgcn_mfma_f32_16x16x32_bf16(a,b,c,0,0,0)

DEV unsigned short bfbits(float v){ __hip_bfloat16 h = __float2bfloat16(v); return *(unsigned short*)&h; }
DEV float bf2f(unsigned short u){ __hip_bfloat16 h = *(__hip_bfloat16*)&u; return __bfloat162float(h); }
DEV void split3(float v, unsigned short& h, unsigned short& m, unsigned short& l) {
  h = bfbits(v);        float r  = v - bf2f(h);
  m = bfbits(r);        float r2 = r - bf2f(m);
  l = bfbits(r2);
}
DEV uint4 zero4(){ uint4 z; z.x=0; z.y=0; z.z=0; z.w=0; return z; }

// ---------------- fused weight prep (one dispatch, 3066 blocks) ----------------
DEV void prep_deconv12(int i, int CI, const float* __restrict__ w, unsigned short* __restrict__ w2) {
  const int K = CI*4;
  int k  = i % K;
  int co = (i / K) & 127;
  int f  = (i / (K*128)) & 1;
  int e  = i / (K*256);
  int ci = (k & 15) | ((k >> 6) << 4);
  int tap = (k >> 4) & 3, a = tap >> 1, b = tap & 1;
  float v = w[ (((long)ci*128 + co)*4 + (2*a+1-e))*4 + (2*b+1-f) ];
  w2[i] = bfbits(v);
}
__global__ __launch_bounds__(256) void wprep_all(
    const float* __restrict__ c1w, float* __restrict__ w2c1,
    const float* __restrict__ c2w, unsigned short* __restrict__ w2c2,
    const float* __restrict__ c3w, unsigned short* __restrict__ w2c3,
    const float* __restrict__ d1w, unsigned short* __restrict__ w2d1,
    const float* __restrict__ d2w, unsigned short* __restrict__ w2d2,
    const float* __restrict__ d3w, unsigned short* __restrict__ w2d3,
    const float* __restrict__ emb, float* __restrict__ esq) {
  const int bx = blockIdx.x, t = threadIdx.x;
  if (bx < 24) {                         // conv1 transpose: 6144
    int i = bx*256 + t;
    if (i < 6144) {
      int tap = i & 15, ci = (i>>4) % 3, co = i / 48;
      w2c1[((long)ci*16 + tap)*128 + co] = c1w[i];
    }
  } else if (bx < 1048) {                // conv2 split prep: 262144
    int i = (bx-24)*256 + t;
    int k = i & 2047, co = i >> 11;
    int ch = k >> 7, rem = k & 127;
    int tap = rem >> 3, cil = rem & 7;
    int ci = ch*8 + cil, ky = tap >> 2, kx = tap & 3;
    float v = c2w[(((long)co*128 + ci)*4 + ky)*4 + kx];
    unsigned short h,m,l; split3(v,h,m,l);
    w2c2[i] = h; w2c2[i + 262144] = m; w2c2[i + 524288] = l;
  } else if (bx < 1432) {                // conv3 split prep: 98304
    int i = (bx-1048)*256 + t;
    int k = i % 1536, co = i / 1536;
    int ch = k / 96, rem = k % 96;
    int tap = rem >> 3, cil = rem & 7;
    int ci = ch*8 + cil, ky = tap >> 2, kx = tap & 3;
    float v = (kx < 3) ? c3w[(((long)co*128 + ci)*3 + ky)*3 + kx] : 0.f;
    unsigned short h,m,l; split3(v,h,m,l);
    w2c3[i] = h; w2c3[i + 98304] = m; w2c3[i + 196608] = l;
  } else if (bx < 1944) {                // deconv1: 131072 (CI=64)
    prep_deconv12((bx-1432)*256 + t, 64, d1w, w2d1);
  } else if (bx < 2968) {                // deconv2: 262144 (CI=128)
    prep_deconv12((bx-1944)*256 + t, 128, d2w, w2d2);
  } else if (bx < 3064) {                // deconv3: 24576
    int i = (bx-2968)*256 + t;
    if (i < 24576) {
      int k = i % 1536, co = i / 1536;
      int ch = k / 96, rem = k % 96;
      int tap = rem >> 3, cil = rem & 7;
      int ci = ch*8 + cil, ky = tap >> 2, kx = tap & 3;
      float v = (co < 3 && kx < 3) ? d3w[(((long)ci*3 + co)*3 + ky)*3 + kx] : 0.f;
      w2d3[i] = bfbits(v);
    }
  } else {                               // esq: 512 codes
    int code = (bx-3064)*256 + t;
    if (code < 512) {
      const float4* ev = (const float4*)(emb + (long)code*64);
      float s = 0.f;
      #pragma unroll
      for (int q=0;q<16;q++){ float4 e4 = ev[q];
        s += e4.x*e4.x + e4.y*e4.y + e4.z*e4.z + e4.w*e4.w; }
      esq[code] = s;
    }
  }
}

// ---------------- conv1: f32 direct, out 3 bf16 planes INTERLEAVED [b][row][ch][px][ci8] ----
__global__ __launch_bounds__(256) void conv1_split(
    const float* __restrict__ x, const float* __restrict__ w2,
    const float* __restrict__ bias, unsigned short* __restrict__ h1, long PS1) {
  __shared__ __align__(16) float sIn[3][18][20];
  __shared__ __align__(16) float sW[3*16*64];
  const int tid = threadIdx.x;
  const int b = blockIdx.z >> 1, cog = blockIdx.z & 1;
  const int co0 = cog*64;
  const int oy0 = blockIdx.y*8, ox0 = blockIdx.x*8;
  const int cg2 = tid >> 5;
  const int pg2 = tid & 31;
  const int r = pg2 >> 2, pxp = (pg2 & 3)*2;
  float acc[8][2];
  #pragma unroll
  for (int c=0;c<8;c++){ float bv = bias[co0 + cg2*8 + c];
    acc[c][0]=bv; acc[c][1]=bv; }
  const float* xb = x + (long)b*3*256*256;
  const int iy0 = 2*oy0 - 1, ix0 = 2*ox0 - 1;
  for (int t=tid; t<3*18*18; t+=256) {
    int xx = t%18, yy=(t/18)%18, ci=t/324;
    int gy = iy0+yy, gx = ix0+xx;
    float v = 0.f;
    if (gy>=0 && gy<256 && gx>=0 && gx<256) v = xb[((long)ci*256+gy)*256+gx];
    sIn[ci][yy][xx] = v;
  }
  for (int t=tid; t<3*16*64; t+=256) {
    sW[t] = w2[(long)(t>>6)*128 + co0 + (t&63)];
  }
  __syncthreads();
  for (int ci=0; ci<3; ci++) {
    #pragma unroll
    for (int ky=0;ky<4;ky++)
    #pragma unroll
    for (int kx=0;kx<4;kx++) {
      const float* wp = &sW[(ci*16 + ky*4+kx)*64 + cg2*8];
      float4 w0 = *(const float4*)wp;
      float4 w1 = *(const float4*)(wp+4);
      const int yy = 2*r + ky;
      #pragma unroll
      for (int p=0;p<2;p++) {
        float iv = sIn[ci][yy][2*(pxp+p)+kx];
        acc[0][p] += w0.x*iv; acc[1][p] += w0.y*iv;
        acc[2][p] += w0.z*iv; acc[3][p] += w0.w*iv;
        acc[4][p] += w1.x*iv; acc[5][p] += w1.y*iv;
        acc[6][p] += w1.z*iv; acc[7][p] += w1.w*iv;
      }
    }
  }
  const int chg = cog*8 + cg2;
  #pragma unroll
  for (int p=0;p<2;p++) {
    unsigned short th[8], tm[8], tl[8];
    #pragma unroll
    for (int c=0;c<8;c++) {
      float v = fmaxf(acc[c][p], 0.f);
      split3(v, th[c], tm[c], tl[c]);
    }
    long base = (((long)(b*128 + oy0+r)*16 + chg)*128 + ox0+pxp+p)*8;
    *(uint4*)(h1 + base)          = *(uint4*)th;
    *(uint4*)(h1 + PS1 + base)    = *(uint4*)tm;
    *(uint4*)(h1 + 2*PS1 + base)  = *(uint4*)tl;
  }
}

// ---------------- conv2: MFMA 6-term split, k4 s2 p1, interleaved input, prefetch ----------
__global__ __launch_bounds__(256, 2) void conv2_mfma(
    const unsigned short* __restrict__ h1, long PS1,
    const unsigned short* __restrict__ w2,
    const float* __restrict__ bias,
    unsigned short* __restrict__ h2, long PS2) {
  __shared__ __align__(16) unsigned short sA[3][4][130][8];
  __shared__ __align__(16) unsigned short sB[3*64*16*8];
  const int tid = threadIdx.x;
  const int oy = blockIdx.x, cog = blockIdx.y, b = blockIdx.z;
  const int wave = tid >> 6, lane = tid & 63;
  const int wr = wave >> 1, wc = wave & 1;
  const int col_l = lane & 15, kg = lane >> 4;
  const int kx = kg, par = (kx+1)&1, cofs = (kx+1)>>1;
  const int iy0 = 2*oy - 1;
  f32x4 acc[2][2] = {};
  unsigned short* sAf = &sA[0][0][0][0];

  int aOff[6], aLdsO[6]; bool aOk[6];
  #pragma unroll
  for (int j = 0; j < 6; ++j) {
    int idx = tid + j*256;
    int px = idx & 127, rr = (idx >> 7) & 3, pl = idx >> 9;
    int iy = iy0 + rr;
    aOk[j] = (iy >= 0 && iy < 128);
    aOff[j] = (int)(pl*PS1 + (long)(b*128 + (aOk[j]?iy:0))*16384 + px*8);
    aLdsO[j] = ((pl*4 + rr)*130 + px + 1)*8;
  }
  int bOff[12], bLdsO[12];
  #pragma unroll
  for (int j = 0; j < 12; ++j) {
    int i = tid + j*256;
    int s = i & 15, co = (i >> 4) & 63, pl = i >> 10;
    bOff[j] = (pl*128 + cog*64 + co)*2048 + s*8;
    bLdsO[j] = ((pl*64 + co)*16 + (s ^ (co & 15)))*8;
  }
  uint4 pA[6], pB[12];
  #pragma unroll
  for (int j=0;j<6;j++)  pA[j] = aOk[j] ? *(const uint4*)(h1 + aOff[j]) : zero4();
  #pragma unroll
  for (int j=0;j<12;j++) pB[j] = *(const uint4*)(w2 + bOff[j]);

  if (tid < 24) {
    int pl = tid>>3, rr=(tid>>1)&3, c=tid&1;
    *(uint4*)&sA[pl][rr][c?129:0][0] = zero4();
  }

  for (int ch = 0; ch < 16; ++ch) {
    __syncthreads();
    #pragma unroll
    for (int j=0;j<6;j++)  *(uint4*)(sAf + aLdsO[j]) = pA[j];
    #pragma unroll
    for (int j=0;j<12;j++) *(uint4*)(&sB[bLdsO[j]]) = pB[j];
    if (ch < 15) {
      #pragma unroll
      for (int j=0;j<6;j++)  pA[j] = aOk[j] ? *(const uint4*)(h1 + aOff[j] + (ch+1)*1024) : zero4();
      #pragma unroll
      for (int j=0;j<12;j++) pB[j] = *(const uint4*)(w2 + bOff[j] + (ch+1)*128);
    }
    __syncthreads();
    #pragma unroll
    for (int s = 0; s < 4; ++s) {
      bf16x8 aF[2][3]; bf16x8 bF[2][3];
      const int tap = s*4 + kg;
      #pragma unroll
      for (int mf = 0; mf < 2; ++mf) {
        int ox = wr*32 + mf*16 + col_l;
        #pragma unroll
        for (int pl = 0; pl < 3; ++pl)
          aF[mf][pl] = *(const bf16x8*)&sA[pl][s][2*ox + kg][0];
      }
      #pragma unroll
      for (int nf = 0; nf < 2; ++nf) {
        int co = wc*32 + nf*16 + col_l;
        int ba = (co*16 + (tap ^ (co&15)))*8;
        bF[nf][0] = *(const bf16x8*)&sB[ba];
        bF[nf][1] = *(const bf16x8*)&sB[ba + 8192];
        bF[nf][2] = *(const bf16x8*)&sB[ba + 16384];
      }
      __builtin_amdgcn_s_setprio(1);
      #pragma unroll
      for (int mf = 0; mf < 2; ++mf)
      #pragma unroll
      for (int nf = 0; nf < 2; ++nf) {
        f32x4 a = acc[mf][nf];
        a = MFMA16(aF[mf][0], bF[nf][0], a);
        a = MFMA16(aF[mf][0], bF[nf][1], a);
        a = MFMA16(aF[mf][1], bF[nf][0], a);
        a = MFMA16(aF[mf][0], bF[nf][2], a);
        a = MFMA16(aF[mf][2], bF[nf][0], a);
        a = MFMA16(aF[mf][1], bF[nf][1], a);
        acc[mf][nf] = a;
      }
      __builtin_amdgcn_s_setprio(0);
    }
  }
  #pragma unroll
  for (int nf = 0; nf < 2; ++nf) {
    int co = cog*64 + wc*32 + nf*16 + col_l;
    float bv = bias[co];
    #pragma unroll
    for (int mf = 0; mf < 2; ++mf) {
      int px0 = wr*32 + mf*16 + kg*4;
      u16x4 oh, om, ol;
      #pragma unroll
      for (int r = 0; r < 4; ++r) {
        float v = fmaxf(acc[mf][nf][r] + bv, 0.f);
        unsigned short h,m,l; split3(v,h,m,l);
        oh[r]=h; om[r]=m; ol[r]=l;
      }
      long base = ((long)(b*128 + co)*64 + oy)*64 + px0;
      *(u16x4*)(h2 + base) = oh;
      *(u16x4*)(h2 + PS2 + base) = om;
      *(u16x4*)(h2 + 2*PS2 + base) = ol;
    }
  }
}

// ---------------- conv3: MFMA 6-term split, k3 s1 p1, 128->64, out 3 bf16 ze planes --------
__global__ __launch_bounds__(256, 2) void conv3_mfma(
    const unsigned short* __restrict__ h2, long PS2,
    const unsigned short* __restrict__ w2,
    const float* __restrict__ bias,
    unsigned short* __restrict__ zeH, unsigned short* __restrict__ zeM,
    unsigned short* __restrict__ zeL) {
  __shared__ __align__(16) unsigned short sA[3*67*24];
  __shared__ __align__(16) unsigned short sB[3*64*16*8];
  const int tid = threadIdx.x;
  const int oy = blockIdx.x, b = blockIdx.z;
  const int wave = tid >> 6, lane = tid & 63;
  const int wr = wave >> 1, wc = wave & 1;
  const int col_l = lane & 15, kg = lane >> 4;
  f32x4 acc[2][2] = {};
  for (int i = tid; i < 3*3*24; i += 256) {
    int j = i % 24, c = (i/24) % 3, rr = i/72;
    int col = (c==0) ? 0 : (c==1 ? 65 : 66);
    sA[(rr*67 + col)*24 + j] = 0;
  }
  const int li = tid & 7, rrA = (tid>>3)%3, ciA = tid/24;
  const int iyA = oy + rrA - 1;
  const bool aAct = (tid < 192);
  const bool aOk = aAct && (iyA >= 0 && iyA < 64);
  const long aBase = ((long)(b*128 + ciA)*64 + (aOk?iyA:0))*64 + li*8;
  int bOff[9], bLdsO[9];
  #pragma unroll
  for (int j = 0; j < 9; ++j) {
    int i = tid + j*256;
    int s = i % 12, co = (i/12) & 63, pl = i/768;
    bOff[j] = (pl*64 + co)*1536 + s*8;
    bLdsO[j] = ((pl*64 + co)*16 + (s ^ (co & 15)))*8;
  }
  uint4 ph, pm, pl4, pB[9];
  ph = aOk ? *(const uint4*)(h2 + aBase) : zero4();
  pm = aOk ? *(const uint4*)(h2 + PS2 + aBase) : zero4();
  pl4 = aOk ? *(const uint4*)(h2 + 2*PS2 + aBase) : zero4();
  #pragma unroll
  for (int j=0;j<9;j++) pB[j] = *(const uint4*)(w2 + bOff[j]);

  for (int ch = 0; ch < 16; ++ch) {
    __syncthreads();
    if (aAct) {
      const unsigned short* vh = (const unsigned short*)&ph;
      const unsigned short* vm = (const unsigned short*)&pm;
      const unsigned short* vl = (const unsigned short*)&pl4;
      #pragma unroll
      for (int p = 0; p < 8; ++p) {
        int pp = (p + li) & 7;
        int col = li*8 + pp + 1;
        int base = (rrA*67 + col)*24 + ciA;
        sA[base]      = vh[pp];
        sA[base + 8]  = vm[pp];
        sA[base + 16] = vl[pp];
      }
    }
    #pragma unroll
    for (int j=0;j<9;j++) *(uint4*)(&sB[bLdsO[j]]) = pB[j];
    if (ch < 15) {
      long nb = aBase + (long)(ch+1)*32768;
      ph = aOk ? *(const uint4*)(h2 + nb) : zero4();
      pm = aOk ? *(const uint4*)(h2 + PS2 + nb) : zero4();
      pl4 = aOk ? *(const uint4*)(h2 + 2*PS2 + nb) : zero4();
      #pragma unroll
      for (int j=0;j<9;j++) pB[j] = *(const uint4*)(w2 + bOff[j] + (ch+1)*96);
    }
    __syncthreads();
    #pragma unroll
    for (int s = 0; s < 3; ++s) {
      bf16x8 aF[2][3]; bf16x8 bF[2][3];
      const int tap = s*4 + kg;
      #pragma unroll
      for (int mf = 0; mf < 2; ++mf) {
        int ox = wr*32 + mf*16 + col_l;
        int base = (s*67 + ox + kg)*24;
        aF[mf][0] = *(const bf16x8*)&sA[base];
        aF[mf][1] = *(const bf16x8*)&sA[base+8];
        aF[mf][2] = *(const bf16x8*)&sA[base+16];
      }
      #pragma unroll
      for (int nf = 0; nf < 2; ++nf) {
        int co = wc*32 + nf*16 + col_l;
        int ba = (co*16 + (tap ^ (co&15)))*8;
        bF[nf][0] = *(const bf16x8*)&sB[ba];
        bF[nf][1] = *(const bf16x8*)&sB[ba + 8192];
        bF[nf][2] = *(const bf16x8*)&sB[ba + 16384];
      }
      __builtin_amdgcn_s_setprio(1);
      #pragma unroll
      for (int mf = 0; mf < 2; ++mf)
      #pragma unroll
      for (int nf = 0; nf < 2; ++nf) {
        f32x4 a = acc[mf][nf];
        a = MFMA16(aF[mf][0], bF[nf][0], a);
        a = MFMA16(aF[mf][0], bF[nf][1], a);
        a = MFMA16(aF[mf][1], bF[nf][0], a);
        a = MFMA16(aF[mf][0], bF[nf][2], a);
        a = MFMA16(aF[mf][2], bF[nf][0], a);
        a = MFMA16(aF[mf][1], bF[nf][1], a);
        acc[mf][nf] = a;
      }
      __builtin_amdgcn_s_setprio(0);
    }
  }
  // epilogue: + bias, split3 -> ze planes (row n = (b*64+co)*64+oy, k = px)
  #pragma unroll
  for (int nf = 0; nf < 2; ++nf) {
    int co = wc*32 + nf*16 + col_l;
    float bv = bias[co];
    #pragma unroll
    for (int mf = 0; mf < 2; ++mf) {
      int px0 = wr*32 + mf*16 + kg*4;
      u16x4 oh, om, ol;
      #pragma unroll
      for (int r = 0; r < 4; ++r) {
        float v = acc[mf][nf][r] + bv;
        unsigned short h,m,l; split3(v,h,m,l);
        oh[r]=h; om[r]=m; ol[r]=l;
      }
      long base = ((long)(b*64 + co)*64 + oy)*64 + px0;
      *(u16x4*)(zeH + base) = oh;
      *(u16x4*)(zeM + base) = om;
      *(u16x4*)(zeL + base) = ol;
    }
  }
}

// ---------------- MFMA ConvTranspose2d stride2 k4 pad1, prefetch, interleaved out ----------
template<int TX, int MODE>
struct SmemD {
  union {
    struct { __align__(16) unsigned short In[2][TX+2][24];
             __align__(16) unsigned short W[2*128*64]; } o;
    struct { __align__(16) unsigned short In[2][TX+2][16];
             __align__(16) unsigned short W[2*128*64]; } v;
    __align__(16) unsigned short Out[2*TX][136];
  };
};

template<int CIN, int TX, int MODE>
__global__ __launch_bounds__(TX*4, (TX==64)?3:4) void deconv_mfma(
    const void* __restrict__ xin, const unsigned short* __restrict__ w2,
    const float* __restrict__ bias, unsigned short* __restrict__ yI) {
  constexpr int NTHR = TX*4;
  constexpr int K    = CIN*4;
  constexpr int NW   = 2048/NTHR;
  __shared__ SmemD<TX,MODE> sm;
  unsigned short* Wb = MODE ? &sm.v.W[0] : &sm.o.W[0];

  const int tid = threadIdx.x;
  const int ty = blockIdx.x, e = blockIdx.y, b = blockIdx.z;
  const int wave = tid >> 6, lane = tid & 63;
  const int wc = wave & 1, wr = wave >> 1;
  const int f = (wr*64) / TX;
  const int tx_base = (wr*64) & (TX-1);
  const int col_l = lane & 15, kg = lane >> 4;

  int wOff[NW], wLdsO[NW];
  #pragma unroll
  for (int j = 0; j < NW; ++j) {
    int i = tid + j*NTHR;
    int s = i & 7, co = (i >> 3) & 127, ff = i >> 10;
    wOff[j] = ((e*2+ff)*128 + co)*K + s*8;
    wLdsO[j] = (ff*128 + co)*64 + (s ^ (co & 7))*8;
  }
  uint4 pW[NW];
  #pragma unroll
  for (int j=0;j<NW;j++) pW[j] = *(const uint4*)(w2 + wOff[j]);

  constexpr int TPR = NTHR/32;
  const int rowid = tid / TPR, liO = tid % TPR;
  const int sci = rowid >> 1, srr = rowid & 1;
  float4 pLo, pHi; uint4 pIn;
  long aBase = 0; bool aOk = false;
  int pxV = 0, halfV = 0, rrV = 0;
  if (MODE == 0) {
    int iy = ty + e - 1 + srr;
    aOk = (iy >= 0 && iy < TX);
    aBase = ((long)b*CIN + sci)*TX*TX + (long)(aOk?iy:0)*TX + liO*8;
    if (aOk) { const float4* s4 = (const float4*)((const float*)xin + aBase);
               pLo = s4[0]; pHi = s4[1]; }
  } else {
    halfV = tid & 1; pxV = (tid >> 1) & (TX-1); rrV = tid >> 8;
    int iy = ty + e - 1 + rrV;
    aOk = (iy >= 0 && iy < TX);
    aBase = ((long)b*TX + (aOk?iy:0))*((long)(CIN/8)*TX*8) + (long)halfV*TX*8 + pxV*8;
    pIn = aOk ? *(const uint4*)((const unsigned short*)xin + aBase) : zero4();
  }

  if (MODE == 0) {
    if (tid < 64) {
      int rr = tid & 1, cc = ((tid>>1)&1) ? TX+1 : 0, ci = tid >> 2;
      sm.o.In[rr][cc][ci] = 0;
    }
  } else {
    if (tid < 8) {
      int rr = tid & 1, c = (tid>>1)&1, hf = (tid>>2)&1;
      *(uint4*)&sm.v.In[rr][c?TX+1:0][hf*8] = zero4();
    }
  }

  f32x4 acc[4][4] = {};
  for (int ch = 0; ch < CIN/16; ++ch) {
    __syncthreads();
    if (MODE == 0) {
      unsigned short vals[8];
      if (aOk) {
        float4 lo = pLo, hi = pHi;
        vals[0]=bfbits(lo.x); vals[1]=bfbits(lo.y); vals[2]=bfbits(lo.z); vals[3]=bfbits(lo.w);
        vals[4]=bfbits(hi.x); vals[5]=bfbits(hi.y); vals[6]=bfbits(hi.z); vals[7]=bfbits(hi.w);
      } else {
        #pragma unroll
        for (int j=0;j<8;j++) vals[j] = 0;
      }
      #pragma unroll
      for (int j=0;j<8;j++) {
        int jj = (j + liO) & 7;
        sm.o.In[srr][1 + liO*8 + jj][sci] = vals[jj];
      }
    } else {
      *(uint4*)&sm.v.In[rrV][pxV+1][halfV*8] = pIn;
    }
    #pragma unroll
    for (int j=0;j<NW;j++) *(uint4*)(Wb + wLdsO[j]) = pW[j];
    if (ch + 1 < CIN/16) {
      if (MODE == 0) {
        if (aOk) { const float4* s4 = (const float4*)((const float*)xin + aBase + (long)(ch+1)*16*TX*TX);
                   pLo = s4[0]; pHi = s4[1]; }
      } else {
        pIn = aOk ? *(const uint4*)((const unsigned short*)xin + aBase + (ch+1)*2*TX*8) : zero4();
      }
      #pragma unroll
      for (int j=0;j<NW;j++) pW[j] = *(const uint4*)(w2 + wOff[j] + (ch+1)*64);
    }
    __syncthreads();
    #pragma unroll
    for (int kk = 0; kk < 2; ++kk) {
      bf16x8 aF[4];
      const int tap = kk*2 + (kg >> 1), a = tap >> 1, bb = tap & 1;
      #pragma unroll
      for (int mf = 0; mf < 4; ++mf) {
        int tx = tx_base + mf*16 + col_l;
        if (MODE == 0) aF[mf] = *(const bf16x8*)&sm.o.In[1-a][tx + 1 + f - bb][(kg&1)*8];
        else           aF[mf] = *(const bf16x8*)&sm.v.In[1-a][tx + 1 + f - bb][(kg&1)*8];
      }
      const int slot = kk*4 + kg;
      __builtin_amdgcn_s_setprio(1);
      #pragma unroll
      for (int nf = 0; nf < 4; ++nf) {
        int co_l = nf*16 + col_l;
        bf16x8 bF = *(const bf16x8*)(Wb + (f*128 + wc*64 + co_l)*64 + (slot ^ (co_l & 7))*8);
        #pragma unroll
        for (int mf = 0; mf < 4; ++mf)
          acc[mf][nf] = MFMA16(aF[mf], bF, acc[mf][nf]);
      }
      __builtin_amdgcn_s_setprio(0);
    }
  }

  __syncthreads();
  float bv[4];
  #pragma unroll
  for (int nf = 0; nf < 4; ++nf) bv[nf] = bias[wc*64 + nf*16 + col_l];
  #pragma unroll
  for (int mf = 0; mf < 4; ++mf)
  #pragma unroll
  for (int nf = 0; nf < 4; ++nf) {
    int co = wc*64 + nf*16 + col_l;
    #pragma unroll
    for (int r = 0; r < 4; ++r) {
      int tx = tx_base + mf*16 + kg*4 + r;
      float v = fmaxf(acc[mf][nf][r] + bv[nf], 0.f);
      int ox = 2*tx + f;
      sm.Out[ox][co ^ (((ox>>3)&7)<<3)] = bfbits(v);
    }
  }
  __syncthreads();
  const int oy = 2*ty + e;
  #pragma unroll
  for (int j = 0; j < 8; ++j) {
    int i = tid + j*NTHR;
    int px = i & (2*TX-1), chn = i / (2*TX);
    uint4 vv = *(const uint4*)&sm.Out[px][(chn*8) ^ (((px>>3)&7)<<3)];
    *(uint4*)(yI + ((((long)b*(2*TX) + oy)*16 + chn)*(2*TX) + px)*8) = vv;
  }
}

// ---------------- deconv3: MFMA, s1 k3 p1, 128->3(pad16) + sigmoid, interleaved in ----------
__global__ __launch_bounds__(256, 2) void deconv3_mfma(
    const unsigned short* __restrict__ g2I,
    const unsigned short* __restrict__ w2,
    const float* __restrict__ bias, float* __restrict__ y) {
  __shared__ __align__(16) unsigned short sA[3][260][8];
  __shared__ __align__(16) unsigned short sB[16*12*16*8];
  const int tid = threadIdx.x;
  const int oy = blockIdx.x, b = blockIdx.y;
  const int wave = tid >> 6, lane = tid & 63;
  const int col_l = lane & 15, kg = lane >> 4;
  const int pxb = wave*64;
  for (int i = tid; i < 3072; i += 256) {
    int co = i & 15, tap = (i>>4) % 12, ch = i/192;
    *(uint4*)&sB[((ch*12+tap)*16+co)*8] = *(const uint4*)(w2 + (long)co*1536 + ch*96 + tap*8);
  }
  if (tid < 12) {
    int dy = tid >> 2, c = tid & 3;
    *(uint4*)&sA[dy][(c<2)?c:(256+c)][0] = zero4();
  }
  long aBase[3]; int aLdsO[3]; bool aOk[3];
  #pragma unroll
  for (int u = 0; u < 3; ++u) {
    int idx = tid + u*256;
    int px = idx & 255, dy = idx >> 8;
    int iy = oy - 1 + dy;
    aOk[u] = (iy >= 0 && iy < 256);
    aBase[u] = ((long)(b*256 + (aOk[u]?iy:0)))*32768 + px*8;
    aLdsO[u] = (dy*260 + px + 2)*8;
  }
  uint4 pA[3];
  #pragma unroll
  for (int u=0;u<3;u++) pA[u] = aOk[u] ? *(const uint4*)(g2I + aBase[u]) : zero4();

  unsigned short* sAf = &sA[0][0][0];
  f32x4 acc[4] = {};
  for (int ch = 0; ch < 16; ++ch) {
    __syncthreads();
    #pragma unroll
    for (int u=0;u<3;u++) *(uint4*)(sAf + aLdsO[u]) = pA[u];
    if (ch < 15) {
      #pragma unroll
      for (int u=0;u<3;u++)
        pA[u] = aOk[u] ? *(const uint4*)(g2I + aBase[u] + (ch+1)*2048) : zero4();
    }
    __syncthreads();
    #pragma unroll
    for (int s = 0; s < 3; ++s) {
      bf16x8 bF = *(const bf16x8*)&sB[((ch*12 + s*4 + kg)*16 + col_l)*8];
      __builtin_amdgcn_s_setprio(1);
      #pragma unroll
      for (int mf = 0; mf < 4; ++mf) {
        int px = pxb + mf*16 + col_l;
        bf16x8 aF = *(const bf16x8*)&sA[2-s][px + 3 - kg][0];
        acc[mf] = MFMA16(aF, bF, acc[mf]);
      }
      __builtin_amdgcn_s_setprio(0);
    }
  }
  if (col_l < 3) {
    float bv = bias[col_l];
    #pragma unroll
    for (int mf = 0; mf < 4; ++mf) {
      int px = pxb + mf*16 + kg*4;
      float4 o;
      o.x = 1.f/(1.f + expf(-(acc[mf][0] + bv)));
      o.y = 1.f/(1.f + expf(-(acc[mf][1] + bv)));
      o.z = 1.f/(1.f + expf(-(acc[mf][2] + bv)));
      o.w = 1.f/(1.f + expf(-(acc[mf][3] + bv)));
      *(float4*)(y + ((long)(b*3 + col_l)*256 + oy)*256 + px) = o;
    }
  }
}

// ---------------- VQ via MFMA: scores = ||e||^2 - 2 * Z @ E^T (6-term split) ----------------
// block: 64 rows x 512 codes; wave: 16 rows x all codes (4 chunks of 128).
__global__ __launch_bounds__(256, 2) void vq_mfma(
    const unsigned short* __restrict__ zeH, const unsigned short* __restrict__ zeM,
    const unsigned short* __restrict__ zeL,
    const float* __restrict__ emb, const float* __restrict__ esq,
    float* __restrict__ out_idx, float* __restrict__ zq) {
  __shared__ __align__(16) unsigned short sA[64*3*8*8];     // [n][pl][slot^(n&7)][8]
  __shared__ __align__(16) unsigned short sB[128*3*8*8];    // [code][pl][slot^(code&7)][8]
  __shared__ float snb[128];
  __shared__ int sidx[64];
  const int tid = threadIdx.x;
  const long n0 = (long)blockIdx.x*64;
  const int wave = tid >> 6, lane = tid & 63;
  const int col = lane & 15, kg = lane >> 4;

  // ---- stage A once: 64 rows x 64k x 3 planes ----
  #pragma unroll
  for (int j = 0; j < 6; ++j) {
    int idx = tid + j*256;
    int pl = idx >> 9, rem = idx & 511;
    int n = rem >> 3, slot = rem & 7;
    const unsigned short* src = (pl==0 ? zeH : (pl==1 ? zeM : zeL)) + (n0+n)*64 + slot*8;
    *(uint4*)&sA[((n*3 + pl)*8 + (slot ^ (n&7)))*8] = *(const uint4*)src;
  }

  // B prefetch (chunk 0): 2 threads/code, 32 f32 each
  const int codeT = tid >> 1, halfT = tid & 1;
  float4 pB[8];
  #pragma unroll
  for (int q = 0; q < 8; ++q)
    pB[q] = *(const float4*)(emb + (long)codeT*64 + halfT*32 + q*4);
  float pSn = (tid < 128) ? esq[tid] : 0.f;

  float best[4] = {3.4e38f,3.4e38f,3.4e38f,3.4e38f};
  int bidx[4] = {0,0,0,0};

  for (int ch = 0; ch < 4; ++ch) {
    __syncthreads();
    // write B chunk (split3 in-kernel), 4 slots of 8 elems per thread
    #pragma unroll
    for (int s4 = 0; s4 < 4; ++s4) {
      int slot = halfT*4 + s4;
      float4 lo = pB[s4*2], hi = pB[s4*2+1];
      unsigned short th[8], tm[8], tl[8];
      split3(lo.x, th[0], tm[0], tl[0]); split3(lo.y, th[1], tm[1], tl[1]);
      split3(lo.z, th[2], tm[2], tl[2]); split3(lo.w, th[3], tm[3], tl[3]);
      split3(hi.x, th[4], tm[4], tl[4]); split3(hi.y, th[5], tm[5], tl[5]);
      split3(hi.z, th[6], tm[6], tl[6]); split3(hi.w, th[7], tm[7], tl[7]);
      int base = ((codeT*3)*8 + (slot ^ (codeT&7)))*8;
      *(uint4*)&sB[base]       = *(uint4*)th;
      *(uint4*)&sB[base + 64]  = *(uint4*)tm;
      *(uint4*)&sB[base + 128] = *(uint4*)tl;
    }
    if (tid < 128) snb[tid] = pSn;
    if (ch < 3) {
      #pragma unroll
      for (int q = 0; q < 8; ++q)
        pB[q] = *(const float4*)(emb + ((long)(ch+1)*128 + codeT)*64 + halfT*32 + q*4);
      if (tid < 128) pSn = esq[(ch+1)*128 + tid];
    }
    __syncthreads();

    f32x4 acc[8] = {};
    #pragma unroll
    for (int kk = 0; kk < 2; ++kk) {
      const int nloc = wave*16 + col;
      const int slot = kk*4 + kg;
      bf16x8 aF[3];
      #pragma unroll
      for (int pl = 0; pl < 3; ++pl)
        aF[pl] = *(const bf16x8*)&sA[((nloc*3 + pl)*8 + (slot ^ (nloc&7)))*8];
      __builtin_amdgcn_s_setprio(1);
      #pragma unroll
      for (int cf = 0; cf < 8; ++cf) {
        int cl = cf*16 + col;
        int bb = ((cl*3)*8 + (slot ^ (cl&7)))*8;
        bf16x8 b0 = *(const bf16x8*)&sB[bb];
        bf16x8 b1 = *(const bf16x8*)&sB[bb + 64];
        bf16x8 b2 = *(const bf16x8*)&sB[bb + 128];
        f32x4 a = acc[cf];
        a = MFMA16(aF[0], b0, a);
        a = MFMA16(aF[0], b1, a);
        a = MFMA16(aF[1], b0, a);
        a = MFMA16(aF[0], b2, a);
        a = MFMA16(aF[2], b0, a);
        a = MFMA16(aF[1], b1, a);
        acc[cf] = a;
      }
      __builtin_amdgcn_s_setprio(0);
    }
    // fold into best (ascending code, strict <)
    #pragma unroll
    for (int cf = 0; cf < 8; ++cf) {
      float sv = snb[cf*16 + col];
      int code = ch*128 + cf*16 + col;
      #pragma unroll
      for (int j = 0; j < 4; ++j) {
        float s = sv - 2.f*acc[cf][j];
        if (s < best[j]) { best[j] = s; bidx[j] = code; }
      }
    }
  }

  // cross-lane reduce over 16 cols (rows = wave*16 + kg*4 + j)
  #pragma unroll
  for (int j = 0; j < 4; ++j) {
    float b = best[j]; int ii = bidx[j];
    #pragma unroll
    for (int off = 1; off < 16; off <<= 1) {
      float ob = __shfl_xor(b, off);
      int oi = __shfl_xor(ii, off);
      if (ob < b || (ob == b && oi < ii)) { b = ob; ii = oi; }
    }
    if (col == 0) sidx[wave*16 + kg*4 + j] = ii;
  }
  __syncthreads();
  if (tid < 64) out_idx[n0 + tid] = (float)sidx[tid];
  // zq gather: 64 rows x 16 float4
  #pragma unroll
  for (int j = 0; j < 4; ++j) {
    int t = tid + j*256;
    int row = t >> 4, q = t & 15;
    float4 v = *(const float4*)(emb + (long)sidx[row]*64 + q*4);
    *(float4*)(zq + (n0 + row)*64 + q*4) = v;
  }
}

// ---------------- launch ----------------
extern "C" void kernel_launch(void* const* d_in, const int* in_sizes, int n_in,
                              void* d_out, int out_size, void* d_ws, size_t ws_size,
                              hipStream_t stream) {
  const float* x   = (const float*)d_in[0];
  const float* c1w = (const float*)d_in[1];  const float* c1b = (const float*)d_in[2];
  const float* c2w = (const float*)d_in[3];  const float* c2b = (const float*)d_in[4];
  const float* c3w = (const float*)d_in[5];  const float* c3b = (const float*)d_in[6];
  const float* emb = (const float*)d_in[7];
  const float* d1w = (const float*)d_in[8];  const float* d1b = (const float*)d_in[9];
  const float* d2w = (const float*)d_in[10]; const float* d2b = (const float*)d_in[11];
  const float* d3w = (const float*)d_in[12]; const float* d3b = (const float*)d_in[13];
  float* out = (float*)d_out;

  float* xrec = out;
  float* oidx = out + 3145728;
  float* zq   = out + 3211264;

  const long XB  = 196608;   // 3*256*256
  const long ZEB = 262144;   // ze elems per batch (4096 rows x 64)
  const long PS1 = 8388608;  // per-plane h1 (4b, interleaved) in shorts
  const long PS2 = 4194304;  // per-plane h2 (8b) in shorts

  const size_t NEEDED = 112076800ULL;  // known: ws_size >= 120,395,264
  if (ws_size < NEEDED) return;
  char* wsb = (char*)d_ws;
  unsigned short* h1grp = (unsigned short*)wsb;              // interleaved, 50.3MB
  unsigned short* g2grp = (unsigned short*)wsb;              // interleaved, 64MB
  unsigned short* h2grp = (unsigned short*)(wsb + 67108864); // planar 3-plane, 24MB
  unsigned short* g1grp = (unsigned short*)(wsb + 67108864); // interleaved, 16MB
  unsigned short* zeH = (unsigned short*)(wsb + 92274688);   // 8.39MB
  unsigned short* zeM = (unsigned short*)(wsb + 100663296);  // 8.39MB
  unsigned short* zeL = (unsigned short*)out;                // xrec region: dead until deconv3
  char* W = wsb + 109051904;
  float* w2c1          = (float*)(W);
  unsigned short* w2c2 = (unsigned short*)(W + 24576);
  unsigned short* w2c3 = (unsigned short*)(W + 1597440);
  unsigned short* w2d1 = (unsigned short*)(W + 2187264);
  unsigned short* w2d2 = (unsigned short*)(W + 2449408);
  unsigned short* w2d3 = (unsigned short*)(W + 2973696);
  float* esq           = (float*)(W + 3022848);

  // single fused weight-prep dispatch
  wprep_all<<<3066, 256, 0, stream>>>(c1w, w2c1, c2w, w2c2, c3w, w2c3,
                                      d1w, w2d1, d2w, w2d2, d3w, w2d3, emb, esq);

  // encoder
  for (int g = 0; g < 4; ++g) {
    conv1_split<<<dim3(16,16,8), 256, 0, stream>>>(
        x + (long)g*4*XB, w2c1, c1b, h1grp, PS1);
    conv2_mfma<<<dim3(64,2,4), 256, 0, stream>>>(
        h1grp, PS1, w2c2, c2b, h2grp + (long)(g&1)*4*524288, PS2);
    if (g & 1) {
      long zo = (long)(g>>1)*8*ZEB;
      conv3_mfma<<<dim3(64,1,8), 256, 0, stream>>>(
          h2grp, PS2, w2c3, c3b, zeH + zo, zeM + zo, zeL + zo);
    }
  }
  vq_mfma<<<1024, 256, 0, stream>>>(zeH, zeM, zeL, emb, esq, oidx, zq);

  // decoder
  for (int g = 0; g < 4; ++g) {
    deconv_mfma<64, 64, 0 ><<<dim3(64, 2, 4), 256, 0, stream>>>(
        (const void*)(zq + (long)g*4*ZEB), w2d1, d1b, g1grp);
    deconv_mfma<128,128,1 ><<<dim3(128,2,4), 512, 0, stream>>>(
        (const void*)g1grp, w2d2, d2b, g2grp);
    deconv3_mfma<<<dim3(256,4), 256, 0, stream>>>(
        g2grp, w2d3, d3b, xrec + (long)g*4*XB);
  }
}

// Round 9
// 1167.904 us; speedup vs baseline: 5.1195x; 1.2800x over previous
//
#include <hip/hip_runtime.h>
#include <hip/hip_bf16.h>

#define DEV __device__ __forceinline__

typedef __attribute__((ext_vector_type(8))) short bf16x8;
typedef __attribute__((ext_vector_type(4))) float f32x4;
typedef __attribute__((ext_vector_type(4))) unsigned short u16x4;

#define MFMA16(a,b,c) __builtin_amdgcn_mfma_f32_16x16x32_bf16(a,b,c,0,0,0)

DEV unsigned short bfbits(float v){ __hip_bfloat16 h = __float2bfloat16(v); return *(unsigned short*)&h; }
DEV float bf2f(unsigned short u){ __hip_bfloat16 h = *(__hip_bfloat16*)&u; return __bfloat162float(h); }
DEV void split3(float v, unsigned short& h, unsigned short& m, unsigned short& l) {
  h = bfbits(v);        float r  = v - bf2f(h);
  m = bfbits(r);        float r2 = r - bf2f(m);
  l = bfbits(r2);
}
DEV uint4 zero4(){ uint4 z; z.x=0; z.y=0; z.z=0; z.w=0; return z; }
DEV void gload_lds16(const void* g, void* l) {
  __builtin_amdgcn_global_load_lds(
      (const __attribute__((address_space(1))) void*)g,
      (__attribute__((address_space(3))) void*)l, 16, 0, 0);
}

// ---------------- fused weight prep (one dispatch, 3066 blocks) ----------------
DEV void prep_deconv12(int i, int CI, const float* __restrict__ w, unsigned short* __restrict__ w2) {
  const int K = CI*4;
  int k  = i % K;
  int co = (i / K) & 127;
  int f  = (i / (K*128)) & 1;
  int e  = i / (K*256);
  int ci = (k & 15) | ((k >> 6) << 4);
  int tap = (k >> 4) & 3, a = tap >> 1, b = tap & 1;
  float v = w[ (((long)ci*128 + co)*4 + (2*a+1-e))*4 + (2*b+1-f) ];
  w2[i] = bfbits(v);
}
__global__ __launch_bounds__(256) void wprep_all(
    const float* __restrict__ c1w, float* __restrict__ w2c1,
    const float* __restrict__ c2w, unsigned short* __restrict__ w2c2,
    const float* __restrict__ c3w, unsigned short* __restrict__ w2c3,
    const float* __restrict__ d1w, unsigned short* __restrict__ w2d1,
    const float* __restrict__ d2w, unsigned short* __restrict__ w2d2,
    const float* __restrict__ d3w, unsigned short* __restrict__ w2d3,
    const float* __restrict__ emb, float* __restrict__ esq) {
  const int bx = blockIdx.x, t = threadIdx.x;
  if (bx < 24) {                         // conv1 transpose: 6144
    int i = bx*256 + t;
    if (i < 6144) {
      int tap = i & 15, ci = (i>>4) % 3, co = i / 48;
      w2c1[((long)ci*16 + tap)*128 + co] = c1w[i];
    }
  } else if (bx < 1048) {                // conv2 prep -> LDS-image layout
    int i = (bx-24)*256 + t;             // 0..262143
    int cil = i & 7, s = (i>>3) & 15, co = (i>>7) & 63;
    int ch = (i>>13) & 15, cog = i >> 17;
    int co_g = cog*64 + co, ci = ch*8 + cil, ky = s >> 2, kx = s & 3;
    float v = c2w[(((long)co_g*128 + ci)*4 + ky)*4 + kx];
    unsigned short h,m,l; split3(v,h,m,l);
    long base = (long)(cog*16 + ch)*24576 + ((long)co*16 + (s ^ (co&15)))*8 + cil;
    w2c2[base] = h; w2c2[base + 8192] = m; w2c2[base + 16384] = l;
  } else if (bx < 1432) {                // conv3 split prep: 98304
    int i = (bx-1048)*256 + t;
    int k = i % 1536, co = i / 1536;
    int ch = k / 96, rem = k % 96;
    int tap = rem >> 3, cil = rem & 7;
    int ci = ch*8 + cil, ky = tap >> 2, kx = tap & 3;
    float v = (kx < 3) ? c3w[(((long)co*128 + ci)*3 + ky)*3 + kx] : 0.f;
    unsigned short h,m,l; split3(v,h,m,l);
    w2c3[i] = h; w2c3[i + 98304] = m; w2c3[i + 196608] = l;
  } else if (bx < 1944) {                // deconv1: 131072 (CI=64)
    prep_deconv12((bx-1432)*256 + t, 64, d1w, w2d1);
  } else if (bx < 2968) {                // deconv2: 262144 (CI=128)
    prep_deconv12((bx-1944)*256 + t, 128, d2w, w2d2);
  } else if (bx < 3064) {                // deconv3: 24576
    int i = (bx-2968)*256 + t;
    if (i < 24576) {
      int k = i % 1536, co = i / 1536;
      int ch = k / 96, rem = k % 96;
      int tap = rem >> 3, cil = rem & 7;
      int ci = ch*8 + cil, ky = tap >> 2, kx = tap & 3;
      float v = (co < 3 && kx < 3) ? d3w[(((long)ci*3 + co)*3 + ky)*3 + kx] : 0.f;
      w2d3[i] = bfbits(v);
    }
  } else {                               // esq: 512 codes
    int code = (bx-3064)*256 + t;
    if (code < 512) {
      const float4* ev = (const float4*)(emb + (long)code*64);
      float s = 0.f;
      #pragma unroll
      for (int q=0;q<16;q++){ float4 e4 = ev[q];
        s += e4.x*e4.x + e4.y*e4.y + e4.z*e4.z + e4.w*e4.w; }
      esq[code] = s;
    }
  }
}

// ---------------- conv1: f32 direct, out 3 bf16 planes INTERLEAVED ----------------
__global__ __launch_bounds__(256) void conv1_split(
    const float* __restrict__ x, const float* __restrict__ w2,
    const float* __restrict__ bias, unsigned short* __restrict__ h1, long PS1) {
  __shared__ __align__(16) float sIn[3][18][20];
  __shared__ __align__(16) float sW[3*16*64];
  const int tid = threadIdx.x;
  const int b = blockIdx.z >> 1, cog = blockIdx.z & 1;
  const int co0 = cog*64;
  const int oy0 = blockIdx.y*8, ox0 = blockIdx.x*8;
  const int cg2 = tid >> 5;
  const int pg2 = tid & 31;
  const int r = pg2 >> 2, pxp = (pg2 & 3)*2;
  float acc[8][2];
  #pragma unroll
  for (int c=0;c<8;c++){ float bv = bias[co0 + cg2*8 + c];
    acc[c][0]=bv; acc[c][1]=bv; }
  const float* xb = x + (long)b*3*256*256;
  const int iy0 = 2*oy0 - 1, ix0 = 2*ox0 - 1;
  for (int t=tid; t<3*18*18; t+=256) {
    int xx = t%18, yy=(t/18)%18, ci=t/324;
    int gy = iy0+yy, gx = ix0+xx;
    float v = 0.f;
    if (gy>=0 && gy<256 && gx>=0 && gx<256) v = xb[((long)ci*256+gy)*256+gx];
    sIn[ci][yy][xx] = v;
  }
  for (int t=tid; t<3*16*64; t+=256) {
    sW[t] = w2[(long)(t>>6)*128 + co0 + (t&63)];
  }
  __syncthreads();
  for (int ci=0; ci<3; ci++) {
    #pragma unroll
    for (int ky=0;ky<4;ky++)
    #pragma unroll
    for (int kx=0;kx<4;kx++) {
      const float* wp = &sW[(ci*16 + ky*4+kx)*64 + cg2*8];
      float4 w0 = *(const float4*)wp;
      float4 w1 = *(const float4*)(wp+4);
      const int yy = 2*r + ky;
      #pragma unroll
      for (int p=0;p<2;p++) {
        float iv = sIn[ci][yy][2*(pxp+p)+kx];
        acc[0][p] += w0.x*iv; acc[1][p] += w0.y*iv;
        acc[2][p] += w0.z*iv; acc[3][p] += w0.w*iv;
        acc[4][p] += w1.x*iv; acc[5][p] += w1.y*iv;
        acc[6][p] += w1.z*iv; acc[7][p] += w1.w*iv;
      }
    }
  }
  const int chg = cog*8 + cg2;
  #pragma unroll
  for (int p=0;p<2;p++) {
    unsigned short th[8], tm[8], tl[8];
    #pragma unroll
    for (int c=0;c<8;c++) {
      float v = fmaxf(acc[c][p], 0.f);
      split3(v, th[c], tm[c], tl[c]);
    }
    long base = (((long)(b*128 + oy0+r)*16 + chg)*128 + ox0+pxp+p)*8;
    *(uint4*)(h1 + base)          = *(uint4*)th;
    *(uint4*)(h1 + PS1 + base)    = *(uint4*)tm;
    *(uint4*)(h1 + 2*PS1 + base)  = *(uint4*)tl;
  }
}

// ---------------- conv2: MFMA 6-term split; B via global_load_lds; coalesced epilogue -----
__global__ __launch_bounds__(256, 2) void conv2_mfma(
    const unsigned short* __restrict__ h1, long PS1,
    const unsigned short* __restrict__ w2,   // LDS-image: [cog][ch][24576 shorts]
    const float* __restrict__ bias,
    unsigned short* __restrict__ h2, long PS2) {
  __shared__ __align__(16) unsigned short sA[3][4][130][8];
  __shared__ __align__(16) unsigned short sB[24576];
  const int tid = threadIdx.x;
  const int oy = blockIdx.x, cog = blockIdx.y, b = blockIdx.z;
  const int wave = tid >> 6, lane = tid & 63;
  const int wr = wave >> 1, wc = wave & 1;
  const int col_l = lane & 15, kg = lane >> 4;
  const int iy0 = 2*oy - 1;
  f32x4 acc[2][2] = {};
  unsigned short* sAf = &sA[0][0][0][0];
  const unsigned short* bsrc = w2 + (long)cog*16*24576;

  // A prefetch descriptors
  int aOff[6], aLdsO[6]; bool aOk[6];
  #pragma unroll
  for (int j = 0; j < 6; ++j) {
    int idx = tid + j*256;
    int px = idx & 127, rr = (idx >> 7) & 3, pl = idx >> 9;
    int iy = iy0 + rr;
    aOk[j] = (iy >= 0 && iy < 128);
    aOff[j] = (int)(pl*PS1 + (long)(b*128 + (aOk[j]?iy:0))*16384 + px*8);
    aLdsO[j] = ((pl*4 + rr)*130 + px + 1)*8;
  }
  uint4 pA[6];
  #pragma unroll
  for (int j=0;j<6;j++)  pA[j] = aOk[j] ? *(const uint4*)(h1 + aOff[j]) : zero4();

  if (tid < 24) {       // zero pad slots col 0 and 129
    int pl = tid>>3, rr=(tid>>1)&3, c=tid&1;
    *(uint4*)&sA[pl][rr][c?129:0][0] = zero4();
  }

  for (int ch = 0; ch < 16; ++ch) {
    __syncthreads();
    #pragma unroll
    for (int j=0;j<6;j++)  *(uint4*)(sAf + aLdsO[j]) = pA[j];
    // B: 48 KB via global_load_lds, 12 instrs/wave, linear dest
    #pragma unroll
    for (int j = 0; j < 12; ++j) {
      int blk = wave*12 + j;
      gload_lds16(bsrc + (long)ch*24576 + blk*512 + lane*8, &sB[blk*512]);
    }
    if (ch < 15) {
      #pragma unroll
      for (int j=0;j<6;j++)  pA[j] = aOk[j] ? *(const uint4*)(h1 + aOff[j] + (ch+1)*1024) : zero4();
    }
    __syncthreads();
    #pragma unroll
    for (int s = 0; s < 4; ++s) {        // s = ky
      bf16x8 aF[2][3]; bf16x8 bF[2][3];
      const int tap = s*4 + kg;
      #pragma unroll
      for (int mf = 0; mf < 2; ++mf) {
        int ox = wr*32 + mf*16 + col_l;
        #pragma unroll
        for (int pl = 0; pl < 3; ++pl)
          aF[mf][pl] = *(const bf16x8*)&sA[pl][s][2*ox + kg][0];
      }
      #pragma unroll
      for (int nf = 0; nf < 2; ++nf) {
        int co = wc*32 + nf*16 + col_l;
        int ba = (co*16 + (tap ^ (co&15)))*8;
        bF[nf][0] = *(const bf16x8*)&sB[ba];
        bF[nf][1] = *(const bf16x8*)&sB[ba + 8192];
        bF[nf][2] = *(const bf16x8*)&sB[ba + 16384];
      }
      __builtin_amdgcn_s_setprio(1);
      #pragma unroll
      for (int mf = 0; mf < 2; ++mf)
      #pragma unroll
      for (int nf = 0; nf < 2; ++nf) {
        f32x4 a = acc[mf][nf];
        a = MFMA16(aF[mf][0], bF[nf][0], a);
        a = MFMA16(aF[mf][0], bF[nf][1], a);
        a = MFMA16(aF[mf][1], bF[nf][0], a);
        a = MFMA16(aF[mf][0], bF[nf][2], a);
        a = MFMA16(aF[mf][2], bF[nf][0], a);
        a = MFMA16(aF[mf][1], bF[nf][1], a);
        acc[mf][nf] = a;
      }
      __builtin_amdgcn_s_setprio(0);
    }
  }
  // epilogue: acc -> sB[pl][co64][72pad] -> full-line coalesced global
  __syncthreads();
  #pragma unroll
  for (int nf = 0; nf < 2; ++nf) {
    int co = wc*32 + nf*16 + col_l;
    float bv = bias[cog*64 + co];
    #pragma unroll
    for (int mf = 0; mf < 2; ++mf) {
      int px0 = wr*32 + mf*16 + kg*4;
      u16x4 oh, om, ol;
      #pragma unroll
      for (int r = 0; r < 4; ++r) {
        float v = fmaxf(acc[mf][nf][r] + bv, 0.f);
        unsigned short h,m,l; split3(v,h,m,l);
        oh[r]=h; om[r]=m; ol[r]=l;
      }
      *(u16x4*)&sB[(0*64 + co)*72 + px0] = oh;
      *(u16x4*)&sB[(1*64 + co)*72 + px0] = om;
      *(u16x4*)&sB[(2*64 + co)*72 + px0] = ol;
    }
  }
  __syncthreads();
  #pragma unroll
  for (int j = 0; j < 6; ++j) {
    int idx = tid + j*256;
    int pl = idx >> 9, co_l = (idx >> 3) & 63, q = idx & 7;
    uint4 v = *(const uint4*)&sB[(pl*64 + co_l)*72 + q*8];
    *(uint4*)(h2 + (long)pl*PS2 + ((long)(b*128 + cog*64 + co_l)*64 + oy)*64 + q*8) = v;
  }
}

// ---------------- conv3: MFMA 6-term split, coalesced epilogue ----------------
__global__ __launch_bounds__(256, 2) void conv3_mfma(
    const unsigned short* __restrict__ h2, long PS2,
    const unsigned short* __restrict__ w2,
    const float* __restrict__ bias,
    unsigned short* __restrict__ zeH, unsigned short* __restrict__ zeM,
    unsigned short* __restrict__ zeL) {
  __shared__ __align__(16) unsigned short sA[3*67*24];
  __shared__ __align__(16) unsigned short sB[24576];
  const int tid = threadIdx.x;
  const int oy = blockIdx.x, b = blockIdx.z;
  const int wave = tid >> 6, lane = tid & 63;
  const int wr = wave >> 1, wc = wave & 1;
  const int col_l = lane & 15, kg = lane >> 4;
  f32x4 acc[2][2] = {};
  for (int i = tid; i < 3*3*24; i += 256) {
    int j = i % 24, c = (i/24) % 3, rr = i/72;
    int col = (c==0) ? 0 : (c==1 ? 65 : 66);
    sA[(rr*67 + col)*24 + j] = 0;
  }
  const int li = tid & 7, rrA = (tid>>3)%3, ciA = tid/24;
  const int iyA = oy + rrA - 1;
  const bool aAct = (tid < 192);
  const bool aOk = aAct && (iyA >= 0 && iyA < 64);
  const long aBase = ((long)(b*128 + ciA)*64 + (aOk?iyA:0))*64 + li*8;
  int bOff[9], bLdsO[9];
  #pragma unroll
  for (int j = 0; j < 9; ++j) {
    int i = tid + j*256;
    int s = i % 12, co = (i/12) & 63, pl = i/768;
    bOff[j] = (pl*64 + co)*1536 + s*8;
    bLdsO[j] = ((pl*64 + co)*16 + (s ^ (co & 15)))*8;
  }
  uint4 ph, pm, pl4, pB[9];
  ph = aOk ? *(const uint4*)(h2 + aBase) : zero4();
  pm = aOk ? *(const uint4*)(h2 + PS2 + aBase) : zero4();
  pl4 = aOk ? *(const uint4*)(h2 + 2*PS2 + aBase) : zero4();
  #pragma unroll
  for (int j=0;j<9;j++) pB[j] = *(const uint4*)(w2 + bOff[j]);

  for (int ch = 0; ch < 16; ++ch) {
    __syncthreads();
    if (aAct) {
      const unsigned short* vh = (const unsigned short*)&ph;
      const unsigned short* vm = (const unsigned short*)&pm;
      const unsigned short* vl = (const unsigned short*)&pl4;
      #pragma unroll
      for (int p = 0; p < 8; ++p) {
        int pp = (p + li) & 7;
        int col = li*8 + pp + 1;
        int base = (rrA*67 + col)*24 + ciA;
        sA[base]      = vh[pp];
        sA[base + 8]  = vm[pp];
        sA[base + 16] = vl[pp];
      }
    }
    #pragma unroll
    for (int j=0;j<9;j++) *(uint4*)(&sB[bLdsO[j]]) = pB[j];
    if (ch < 15) {
      long nb = aBase + (long)(ch+1)*32768;
      ph = aOk ? *(const uint4*)(h2 + nb) : zero4();
      pm = aOk ? *(const uint4*)(h2 + PS2 + nb) : zero4();
      pl4 = aOk ? *(const uint4*)(h2 + 2*PS2 + nb) : zero4();
      #pragma unroll
      for (int j=0;j<9;j++) pB[j] = *(const uint4*)(w2 + bOff[j] + (ch+1)*96);
    }
    __syncthreads();
    #pragma unroll
    for (int s = 0; s < 3; ++s) {
      bf16x8 aF[2][3]; bf16x8 bF[2][3];
      const int tap = s*4 + kg;
      #pragma unroll
      for (int mf = 0; mf < 2; ++mf) {
        int ox = wr*32 + mf*16 + col_l;
        int base = (s*67 + ox + kg)*24;
        aF[mf][0] = *(const bf16x8*)&sA[base];
        aF[mf][1] = *(const bf16x8*)&sA[base+8];
        aF[mf][2] = *(const bf16x8*)&sA[base+16];
      }
      #pragma unroll
      for (int nf = 0; nf < 2; ++nf) {
        int co = wc*32 + nf*16 + col_l;
        int ba = (co*16 + (tap ^ (co&15)))*8;
        bF[nf][0] = *(const bf16x8*)&sB[ba];
        bF[nf][1] = *(const bf16x8*)&sB[ba + 8192];
        bF[nf][2] = *(const bf16x8*)&sB[ba + 16384];
      }
      __builtin_amdgcn_s_setprio(1);
      #pragma unroll
      for (int mf = 0; mf < 2; ++mf)
      #pragma unroll
      for (int nf = 0; nf < 2; ++nf) {
        f32x4 a = acc[mf][nf];
        a = MFMA16(aF[mf][0], bF[nf][0], a);
        a = MFMA16(aF[mf][0], bF[nf][1], a);
        a = MFMA16(aF[mf][1], bF[nf][0], a);
        a = MFMA16(aF[mf][0], bF[nf][2], a);
        a = MFMA16(aF[mf][2], bF[nf][0], a);
        a = MFMA16(aF[mf][1], bF[nf][1], a);
        acc[mf][nf] = a;
      }
      __builtin_amdgcn_s_setprio(0);
    }
  }
  // epilogue: acc -> sB[pl][co][72pad] -> full-line coalesced global
  __syncthreads();
  #pragma unroll
  for (int nf = 0; nf < 2; ++nf) {
    int co = wc*32 + nf*16 + col_l;
    float bv = bias[co];
    #pragma unroll
    for (int mf = 0; mf < 2; ++mf) {
      int px0 = wr*32 + mf*16 + kg*4;
      u16x4 oh, om, ol;
      #pragma unroll
      for (int r = 0; r < 4; ++r) {
        float v = acc[mf][nf][r] + bv;
        unsigned short h,m,l; split3(v,h,m,l);
        oh[r]=h; om[r]=m; ol[r]=l;
      }
      *(u16x4*)&sB[(0*64 + co)*72 + px0] = oh;
      *(u16x4*)&sB[(1*64 + co)*72 + px0] = om;
      *(u16x4*)&sB[(2*64 + co)*72 + px0] = ol;
    }
  }
  __syncthreads();
  #pragma unroll
  for (int j = 0; j < 6; ++j) {
    int idx = tid + j*256;
    int pl = idx >> 9, co_l = (idx >> 3) & 63, q = idx & 7;
    uint4 v = *(const uint4*)&sB[(pl*64 + co_l)*72 + q*8];
    unsigned short* dst = (pl==0) ? zeH : ((pl==1) ? zeM : zeL);
    *(uint4*)(dst + ((long)(b*64 + co_l)*64 + oy)*64 + q*8) = v;
  }
}

// ---------------- MFMA ConvTranspose2d stride2 k4 pad1 (unchanged from r8) ----------
template<int TX, int MODE>
struct SmemD {
  union {
    struct { __align__(16) unsigned short In[2][TX+2][24];
             __align__(16) unsigned short W[2*128*64]; } o;
    struct { __align__(16) unsigned short In[2][TX+2][16];
             __align__(16) unsigned short W[2*128*64]; } v;
    __align__(16) unsigned short Out[2*TX][136];
  };
};

template<int CIN, int TX, int MODE>
__global__ __launch_bounds__(TX*4, (TX==64)?3:4) void deconv_mfma(
    const void* __restrict__ xin, const unsigned short* __restrict__ w2,
    const float* __restrict__ bias, unsigned short* __restrict__ yI) {
  constexpr int NTHR = TX*4;
  constexpr int K    = CIN*4;
  constexpr int NW   = 2048/NTHR;
  __shared__ SmemD<TX,MODE> sm;
  unsigned short* Wb = MODE ? &sm.v.W[0] : &sm.o.W[0];

  const int tid = threadIdx.x;
  const int ty = blockIdx.x, e = blockIdx.y, b = blockIdx.z;
  const int wave = tid >> 6, lane = tid & 63;
  const int wc = wave & 1, wr = wave >> 1;
  const int f = (wr*64) / TX;
  const int tx_base = (wr*64) & (TX-1);
  const int col_l = lane & 15, kg = lane >> 4;

  int wOff[NW], wLdsO[NW];
  #pragma unroll
  for (int j = 0; j < NW; ++j) {
    int i = tid + j*NTHR;
    int s = i & 7, co = (i >> 3) & 127, ff = i >> 10;
    wOff[j] = ((e*2+ff)*128 + co)*K + s*8;
    wLdsO[j] = (ff*128 + co)*64 + (s ^ (co & 7))*8;
  }
  uint4 pW[NW];
  #pragma unroll
  for (int j=0;j<NW;j++) pW[j] = *(const uint4*)(w2 + wOff[j]);

  constexpr int TPR = NTHR/32;
  const int rowid = tid / TPR, liO = tid % TPR;
  const int sci = rowid >> 1, srr = rowid & 1;
  float4 pLo, pHi; uint4 pIn;
  long aBase = 0; bool aOk = false;
  int pxV = 0, halfV = 0, rrV = 0;
  if (MODE == 0) {
    int iy = ty + e - 1 + srr;
    aOk = (iy >= 0 && iy < TX);
    aBase = ((long)b*CIN + sci)*TX*TX + (long)(aOk?iy:0)*TX + liO*8;
    if (aOk) { const float4* s4 = (const float4*)((const float*)xin + aBase);
               pLo = s4[0]; pHi = s4[1]; }
  } else {
    halfV = tid & 1; pxV = (tid >> 1) & (TX-1); rrV = tid >> 8;
    int iy = ty + e - 1 + rrV;
    aOk = (iy >= 0 && iy < TX);
    aBase = ((long)b*TX + (aOk?iy:0))*((long)(CIN/8)*TX*8) + (long)halfV*TX*8 + pxV*8;
    pIn = aOk ? *(const uint4*)((const unsigned short*)xin + aBase) : zero4();
  }

  if (MODE == 0) {
    if (tid < 64) {
      int rr = tid & 1, cc = ((tid>>1)&1) ? TX+1 : 0, ci = tid >> 2;
      sm.o.In[rr][cc][ci] = 0;
    }
  } else {
    if (tid < 8) {
      int rr = tid & 1, c = (tid>>1)&1, hf = (tid>>2)&1;
      *(uint4*)&sm.v.In[rr][c?TX+1:0][hf*8] = zero4();
    }
  }

  f32x4 acc[4][4] = {};
  for (int ch = 0; ch < CIN/16; ++ch) {
    __syncthreads();
    if (MODE == 0) {
      unsigned short vals[8];
      if (aOk) {
        float4 lo = pLo, hi = pHi;
        vals[0]=bfbits(lo.x); vals[1]=bfbits(lo.y); vals[2]=bfbits(lo.z); vals[3]=bfbits(lo.w);
        vals[4]=bfbits(hi.x); vals[5]=bfbits(hi.y); vals[6]=bfbits(hi.z); vals[7]=bfbits(hi.w);
      } else {
        #pragma unroll
        for (int j=0;j<8;j++) vals[j] = 0;
      }
      #pragma unroll
      for (int j=0;j<8;j++) {
        int jj = (j + liO) & 7;
        sm.o.In[srr][1 + liO*8 + jj][sci] = vals[jj];
      }
    } else {
      *(uint4*)&sm.v.In[rrV][pxV+1][halfV*8] = pIn;
    }
    #pragma unroll
    for (int j=0;j<NW;j++) *(uint4*)(Wb + wLdsO[j]) = pW[j];
    if (ch + 1 < CIN/16) {
      if (MODE == 0) {
        if (aOk) { const float4* s4 = (const float4*)((const float*)xin + aBase + (long)(ch+1)*16*TX*TX);
                   pLo = s4[0]; pHi = s4[1]; }
      } else {
        pIn = aOk ? *(const uint4*)((const unsigned short*)xin + aBase + (ch+1)*2*TX*8) : zero4();
      }
      #pragma unroll
      for (int j=0;j<NW;j++) pW[j] = *(const uint4*)(w2 + wOff[j] + (ch+1)*64);
    }
    __syncthreads();
    #pragma unroll
    for (int kk = 0; kk < 2; ++kk) {
      bf16x8 aF[4];
      const int tap = kk*2 + (kg >> 1), a = tap >> 1, bb = tap & 1;
      #pragma unroll
      for (int mf = 0; mf < 4; ++mf) {
        int tx = tx_base + mf*16 + col_l;
        if (MODE == 0) aF[mf] = *(const bf16x8*)&sm.o.In[1-a][tx + 1 + f - bb][(kg&1)*8];
        else           aF[mf] = *(const bf16x8*)&sm.v.In[1-a][tx + 1 + f - bb][(kg&1)*8];
      }
      const int slot = kk*4 + kg;
      __builtin_amdgcn_s_setprio(1);
      #pragma unroll
      for (int nf = 0; nf < 4; ++nf) {
        int co_l = nf*16 + col_l;
        bf16x8 bF = *(const bf16x8*)(Wb + (f*128 + wc*64 + co_l)*64 + (slot ^ (co_l & 7))*8);
        #pragma unroll
        for (int mf = 0; mf < 4; ++mf)
          acc[mf][nf] = MFMA16(aF[mf], bF, acc[mf][nf]);
      }
      __builtin_amdgcn_s_setprio(0);
    }
  }

  __syncthreads();
  float bv[4];
  #pragma unroll
  for (int nf = 0; nf < 4; ++nf) bv[nf] = bias[wc*64 + nf*16 + col_l];
  #pragma unroll
  for (int mf = 0; mf < 4; ++mf)
  #pragma unroll
  for (int nf = 0; nf < 4; ++nf) {
    int co = wc*64 + nf*16 + col_l;
    #pragma unroll
    for (int r = 0; r < 4; ++r) {
      int tx = tx_base + mf*16 + kg*4 + r;
      float v = fmaxf(acc[mf][nf][r] + bv[nf], 0.f);
      int ox = 2*tx + f;
      sm.Out[ox][co ^ (((ox>>3)&7)<<3)] = bfbits(v);
    }
  }
  __syncthreads();
  const int oy = 2*ty + e;
  #pragma unroll
  for (int j = 0; j < 8; ++j) {
    int i = tid + j*NTHR;
    int px = i & (2*TX-1), chn = i / (2*TX);
    uint4 vv = *(const uint4*)&sm.Out[px][(chn*8) ^ (((px>>3)&7)<<3)];
    *(uint4*)(yI + ((((long)b*(2*TX) + oy)*16 + chn)*(2*TX) + px)*8) = vv;
  }
}

// ---------------- deconv3: MFMA + sigmoid (unchanged from r8) ----------
__global__ __launch_bounds__(256, 2) void deconv3_mfma(
    const unsigned short* __restrict__ g2I,
    const unsigned short* __restrict__ w2,
    const float* __restrict__ bias, float* __restrict__ y) {
  __shared__ __align__(16) unsigned short sA[3][260][8];
  __shared__ __align__(16) unsigned short sB[16*12*16*8];
  const int tid = threadIdx.x;
  const int oy = blockIdx.x, b = blockIdx.y;
  const int wave = tid >> 6, lane = tid & 63;
  const int col_l = lane & 15, kg = lane >> 4;
  const int pxb = wave*64;
  for (int i = tid; i < 3072; i += 256) {
    int co = i & 15, tap = (i>>4) % 12, ch = i/192;
    *(uint4*)&sB[((ch*12+tap)*16+co)*8] = *(const uint4*)(w2 + (long)co*1536 + ch*96 + tap*8);
  }
  if (tid < 12) {
    int dy = tid >> 2, c = tid & 3;
    *(uint4*)&sA[dy][(c<2)?c:(256+c)][0] = zero4();
  }
  long aBase[3]; int aLdsO[3]; bool aOk[3];
  #pragma unroll
  for (int u = 0; u < 3; ++u) {
    int idx = tid + u*256;
    int px = idx & 255, dy = idx >> 8;
    int iy = oy - 1 + dy;
    aOk[u] = (iy >= 0 && iy < 256);
    aBase[u] = ((long)(b*256 + (aOk[u]?iy:0)))*32768 + px*8;
    aLdsO[u] = (dy*260 + px + 2)*8;
  }
  uint4 pA[3];
  #pragma unroll
  for (int u=0;u<3;u++) pA[u] = aOk[u] ? *(const uint4*)(g2I + aBase[u]) : zero4();

  unsigned short* sAf = &sA[0][0][0];
  f32x4 acc[4] = {};
  for (int ch = 0; ch < 16; ++ch) {
    __syncthreads();
    #pragma unroll
    for (int u=0;u<3;u++) *(uint4*)(sAf + aLdsO[u]) = pA[u];
    if (ch < 15) {
      #pragma unroll
      for (int u=0;u<3;u++)
        pA[u] = aOk[u] ? *(const uint4*)(g2I + aBase[u] + (ch+1)*2048) : zero4();
    }
    __syncthreads();
    #pragma unroll
    for (int s = 0; s < 3; ++s) {
      bf16x8 bF = *(const bf16x8*)&sB[((ch*12 + s*4 + kg)*16 + col_l)*8];
      __builtin_amdgcn_s_setprio(1);
      #pragma unroll
      for (int mf = 0; mf < 4; ++mf) {
        int px = pxb + mf*16 + col_l;
        bf16x8 aF = *(const bf16x8*)&sA[2-s][px + 3 - kg][0];
        acc[mf] = MFMA16(aF, bF, acc[mf]);
      }
      __builtin_amdgcn_s_setprio(0);
    }
  }
  if (col_l < 3) {
    float bv = bias[col_l];
    #pragma unroll
    for (int mf = 0; mf < 4; ++mf) {
      int px = pxb + mf*16 + kg*4;
      float4 o;
      o.x = 1.f/(1.f + expf(-(acc[mf][0] + bv)));
      o.y = 1.f/(1.f + expf(-(acc[mf][1] + bv)));
      o.z = 1.f/(1.f + expf(-(acc[mf][2] + bv)));
      o.w = 1.f/(1.f + expf(-(acc[mf][3] + bv)));
      *(float4*)(y + ((long)(b*3 + col_l)*256 + oy)*256 + px) = o;
    }
  }
}

// ---------------- VQ via MFMA (unchanged from r8) ----------------
__global__ __launch_bounds__(256, 2) void vq_mfma(
    const unsigned short* __restrict__ zeH, const unsigned short* __restrict__ zeM,
    const unsigned short* __restrict__ zeL,
    const float* __restrict__ emb, const float* __restrict__ esq,
    float* __restrict__ out_idx, float* __restrict__ zq) {
  __shared__ __align__(16) unsigned short sA[64*3*8*8];
  __shared__ __align__(16) unsigned short sB[128*3*8*8];
  __shared__ float snb[128];
  __shared__ int sidx[64];
  const int tid = threadIdx.x;
  const long n0 = (long)blockIdx.x*64;
  const int wave = tid >> 6, lane = tid & 63;
  const int col = lane & 15, kg = lane >> 4;

  #pragma unroll
  for (int j = 0; j < 6; ++j) {
    int idx = tid + j*256;
    int pl = idx >> 9, rem = idx & 511;
    int n = rem >> 3, slot = rem & 7;
    const unsigned short* src = (pl==0 ? zeH : (pl==1 ? zeM : zeL)) + (n0+n)*64 + slot*8;
    *(uint4*)&sA[((n*3 + pl)*8 + (slot ^ (n&7)))*8] = *(const uint4*)src;
  }

  const int codeT = tid >> 1, halfT = tid & 1;
  float4 pB[8];
  #pragma unroll
  for (int q = 0; q < 8; ++q)
    pB[q] = *(const float4*)(emb + (long)codeT*64 + halfT*32 + q*4);
  float pSn = (tid < 128) ? esq[tid] : 0.f;

  float best[4] = {3.4e38f,3.4e38f,3.4e38f,3.4e38f};
  int bidx[4] = {0,0,0,0};

  for (int ch = 0; ch < 4; ++ch) {
    __syncthreads();
    #pragma unroll
    for (int s4 = 0; s4 < 4; ++s4) {
      int slot = halfT*4 + s4;
      float4 lo = pB[s4*2], hi = pB[s4*2+1];
      unsigned short th[8], tm[8], tl[8];
      split3(lo.x, th[0], tm[0], tl[0]); split3(lo.y, th[1], tm[1], tl[1]);
      split3(lo.z, th[2], tm[2], tl[2]); split3(lo.w, th[3], tm[3], tl[3]);
      split3(hi.x, th[4], tm[4], tl[4]); split3(hi.y, th[5], tm[5], tl[5]);
      split3(hi.z, th[6], tm[6], tl[6]); split3(hi.w, th[7], tm[7], tl[7]);
      int base = ((codeT*3)*8 + (slot ^ (codeT&7)))*8;
      *(uint4*)&sB[base]       = *(uint4*)th;
      *(uint4*)&sB[base + 64]  = *(uint4*)tm;
      *(uint4*)&sB[base + 128] = *(uint4*)tl;
    }
    if (tid < 128) snb[tid] = pSn;
    if (ch < 3) {
      #pragma unroll
      for (int q = 0; q < 8; ++q)
        pB[q] = *(const float4*)(emb + ((long)(ch+1)*128 + codeT)*64 + halfT*32 + q*4);
      if (tid < 128) pSn = esq[(ch+1)*128 + tid];
    }
    __syncthreads();

    f32x4 acc[8] = {};
    #pragma unroll
    for (int kk = 0; kk < 2; ++kk) {
      const int nloc = wave*16 + col;
      const int slot = kk*4 + kg;
      bf16x8 aF[3];
      #pragma unroll
      for (int pl = 0; pl < 3; ++pl)
        aF[pl] = *(const bf16x8*)&sA[((nloc*3 + pl)*8 + (slot ^ (nloc&7)))*8];
      __builtin_amdgcn_s_setprio(1);
      #pragma unroll
      for (int cf = 0; cf < 8; ++cf) {
        int cl = cf*16 + col;
        int bb = ((cl*3)*8 + (slot ^ (cl&7)))*8;
        bf16x8 b0 = *(const bf16x8*)&sB[bb];
        bf16x8 b1 = *(const bf16x8*)&sB[bb + 64];
        bf16x8 b2 = *(const bf16x8*)&sB[bb + 128];
        f32x4 a = acc[cf];
        a = MFMA16(aF[0], b0, a);
        a = MFMA16(aF[0], b1, a);
        a = MFMA16(aF[1], b0, a);
        a = MFMA16(aF[0], b2, a);
        a = MFMA16(aF[2], b0, a);
        a = MFMA16(aF[1], b1, a);
        acc[cf] = a;
      }
      __builtin_amdgcn_s_setprio(0);
    }
    #pragma unroll
    for (int cf = 0; cf < 8; ++cf) {
      float sv = snb[cf*16 + col];
      int code = ch*128 + cf*16 + col;
      #pragma unroll
      for (int j = 0; j < 4; ++j) {
        float s = sv - 2.f*acc[cf][j];
        if (s < best[j]) { best[j] = s; bidx[j] = code; }
      }
    }
  }

  #pragma unroll
  for (int j = 0; j < 4; ++j) {
    float b = best[j]; int ii = bidx[j];
    #pragma unroll
    for (int off = 1; off < 16; off <<= 1) {
      float ob = __shfl_xor(b, off);
      int oi = __shfl_xor(ii, off);
      if (ob < b || (ob == b && oi < ii)) { b = ob; ii = oi; }
    }
    if (col == 0) sidx[wave*16 + kg*4 + j] = ii;
  }
  __syncthreads();
  if (tid < 64) out_idx[n0 + tid] = (float)sidx[tid];
  #pragma unroll
  for (int j = 0; j < 4; ++j) {
    int t = tid + j*256;
    int row = t >> 4, q = t & 15;
    float4 v = *(const float4*)(emb + (long)sidx[row]*64 + q*4);
    *(float4*)(zq + (n0 + row)*64 + q*4) = v;
  }
}

// ---------------- launch ----------------
extern "C" void kernel_launch(void* const* d_in, const int* in_sizes, int n_in,
                              void* d_out, int out_size, void* d_ws, size_t ws_size,
                              hipStream_t stream) {
  const float* x   = (const float*)d_in[0];
  const float* c1w = (const float*)d_in[1];  const float* c1b = (const float*)d_in[2];
  const float* c2w = (const float*)d_in[3];  const float* c2b = (const float*)d_in[4];
  const float* c3w = (const float*)d_in[5];  const float* c3b = (const float*)d_in[6];
  const float* emb = (const float*)d_in[7];
  const float* d1w = (const float*)d_in[8];  const float* d1b = (const float*)d_in[9];
  const float* d2w = (const float*)d_in[10]; const float* d2b = (const float*)d_in[11];
  const float* d3w = (const float*)d_in[12]; const float* d3b = (const float*)d_in[13];
  float* out = (float*)d_out;

  float* xrec = out;
  float* oidx = out + 3145728;
  float* zq   = out + 3211264;

  const long XB  = 196608;   // 3*256*256
  const long ZEB = 262144;   // ze elems per batch
  const long PS1 = 8388608;  // per-plane h1 (interleaved) in shorts
  const long PS2 = 4194304;  // per-plane h2 in shorts

  const size_t NEEDED = 112076800ULL;  // known: ws_size >= 120,395,264
  if (ws_size < NEEDED) return;
  char* wsb = (char*)d_ws;
  unsigned short* h1grp = (unsigned short*)wsb;              // interleaved, 50.3MB
  unsigned short* g2grp = (unsigned short*)wsb;              // interleaved, 64MB
  unsigned short* h2grp = (unsigned short*)(wsb + 67108864); // planar 3-plane, 24MB
  unsigned short* g1grp = (unsigned short*)(wsb + 67108864); // interleaved, 16MB
  unsigned short* zeH = (unsigned short*)(wsb + 92274688);
  unsigned short* zeM = (unsigned short*)(wsb + 100663296);
  unsigned short* zeL = (unsigned short*)out;                // xrec region: dead until deconv3
  char* W = wsb + 109051904;
  float* w2c1          = (float*)(W);
  unsigned short* w2c2 = (unsigned short*)(W + 24576);       // LDS-image, 1.57MB
  unsigned short* w2c3 = (unsigned short*)(W + 1597440);
  unsigned short* w2d1 = (unsigned short*)(W + 2187264);
  unsigned short* w2d2 = (unsigned short*)(W + 2449408);
  unsigned short* w2d3 = (unsigned short*)(W + 2973696);
  float* esq           = (float*)(W + 3022848);

  wprep_all<<<3066, 256, 0, stream>>>(c1w, w2c1, c2w, w2c2, c3w, w2c3,
                                      d1w, w2d1, d2w, w2d2, d3w, w2d3, emb, esq);

  // encoder
  for (int g = 0; g < 4; ++g) {
    conv1_split<<<dim3(16,16,8), 256, 0, stream>>>(
        x + (long)g*4*XB, w2c1, c1b, h1grp, PS1);
    conv2_mfma<<<dim3(64,2,4), 256, 0, stream>>>(
        h1grp, PS1, w2c2, c2b, h2grp + (long)(g&1)*4*524288, PS2);
    if (g & 1) {
      long zo = (long)(g>>1)*8*ZEB;
      conv3_mfma<<<dim3(64,1,8), 256, 0, stream>>>(
          h2grp, PS2, w2c3, c3b, zeH + zo, zeM + zo, zeL + zo);
    }
  }
  vq_mfma<<<1024, 256, 0, stream>>>(zeH, zeM, zeL, emb, esq, oidx, zq);

  // decoder
  for (int g = 0; g < 4; ++g) {
    deconv_mfma<64, 64, 0 ><<<dim3(64, 2, 4), 256, 0, stream>>>(
        (const void*)(zq + (long)g*4*ZEB), w2d1, d1b, g1grp);
    deconv_mfma<128,128,1 ><<<dim3(128,2,4), 512, 0, stream>>>(
        (const void*)g1grp, w2d2, d2b, g2grp);
    deconv3_mfma<<<dim3(256,4), 256, 0, stream>>>(
        g2grp, w2d3, d3b, xrec + (long)g*4*XB);
  }
}

// Round 10
// 1082.743 us; speedup vs baseline: 5.5221x; 1.0787x over previous
//
#include <hip/hip_runtime.h>
#include <hip/hip_bf16.h>

#define DEV __device__ __forceinline__

typedef __attribute__((ext_vector_type(8))) short bf16x8;
typedef __attribute__((ext_vector_type(4))) float f32x4;
typedef __attribute__((ext_vector_type(4))) unsigned short u16x4;

#define MFMA16(a,b,c) __builtin_amdgcn_mfma_f32_16x16x32_bf16(a,b,c,0,0,0)

DEV unsigned short bfbits(float v){ __hip_bfloat16 h = __float2bfloat16(v); return *(unsigned short*)&h; }
DEV float bf2f(unsigned short u){ __hip_bfloat16 h = *(__hip_bfloat16*)&u; return __bfloat162float(h); }
DEV void split3(float v, unsigned short& h, unsigned short& m, unsigned short& l) {
  h = bfbits(v);        float r  = v - bf2f(h);
  m = bfbits(r);        float r2 = r - bf2f(m);
  l = bfbits(r2);
}
DEV uint4 zero4(){ uint4 z; z.x=0; z.y=0; z.z=0; z.w=0; return z; }
DEV void gload_lds16(const void* g, void* l) {
  __builtin_amdgcn_global_load_lds(
      (const __attribute__((address_space(1))) void*)g,
      (__attribute__((address_space(3))) void*)l, 16, 0, 0);
}

// ---------------- fused weight prep (one dispatch, 3066 blocks) ----------------
DEV void prep_deconv12(int i, int CI, const float* __restrict__ w, unsigned short* __restrict__ w2) {
  const int K = CI*4;
  int k  = i % K;
  int co = (i / K) & 127;
  int f  = (i / (K*128)) & 1;
  int e  = i / (K*256);
  int ci = (k & 15) | ((k >> 6) << 4);
  int tap = (k >> 4) & 3, a = tap >> 1, b = tap & 1;
  float v = w[ (((long)ci*128 + co)*4 + (2*a+1-e))*4 + (2*b+1-f) ];
  w2[i] = bfbits(v);
}
__global__ __launch_bounds__(256) void wprep_all(
    const float* __restrict__ c1w, float* __restrict__ w2c1,
    const float* __restrict__ c2w, unsigned short* __restrict__ w2c2,
    const float* __restrict__ c3w, unsigned short* __restrict__ w2c3,
    const float* __restrict__ d1w, unsigned short* __restrict__ w2d1,
    const float* __restrict__ d2w, unsigned short* __restrict__ w2d2,
    const float* __restrict__ d3w, unsigned short* __restrict__ w2d3,
    const float* __restrict__ emb, float* __restrict__ esq) {
  const int bx = blockIdx.x, t = threadIdx.x;
  if (bx < 24) {                         // conv1 transpose: 6144
    int i = bx*256 + t;
    if (i < 6144) {
      int tap = i & 15, ci = (i>>4) % 3, co = i / 48;
      w2c1[((long)ci*16 + tap)*128 + co] = c1w[i];
    }
  } else if (bx < 1048) {                // conv2 prep -> LDS-image layout
    int i = (bx-24)*256 + t;             // 0..262143
    int cil = i & 7, s = (i>>3) & 15, co = (i>>7) & 63;
    int ch = (i>>13) & 15, cog = i >> 17;
    int co_g = cog*64 + co, ci = ch*8 + cil, ky = s >> 2, kx = s & 3;
    float v = c2w[(((long)co_g*128 + ci)*4 + ky)*4 + kx];
    unsigned short h,m,l; split3(v,h,m,l);
    long base = (long)(cog*16 + ch)*24576 + ((long)co*16 + (s ^ (co&15)))*8 + cil;
    w2c2[base] = h; w2c2[base + 8192] = m; w2c2[base + 16384] = l;
  } else if (bx < 1432) {                // conv3 prep -> LDS-image layout: 98304
    int i = (bx-1048)*256 + t;
    int k = i % 1536, co = i / 1536;
    int ch = k / 96, rem = k % 96;
    int tap = rem >> 3, cil = rem & 7;
    int ci = ch*8 + cil, ky = tap >> 2, kx = tap & 3;
    float v = (kx < 3) ? c3w[(((long)co*128 + ci)*3 + ky)*3 + kx] : 0.f;
    unsigned short h,m,l; split3(v,h,m,l);
    long base = (long)ch*24576 + ((long)co*16 + (tap ^ (co&15)))*8 + cil;
    w2c3[base] = h; w2c3[base + 8192] = m; w2c3[base + 16384] = l;
  } else if (bx < 1944) {                // deconv1: 131072 (CI=64)
    prep_deconv12((bx-1432)*256 + t, 64, d1w, w2d1);
  } else if (bx < 2968) {                // deconv2: 262144 (CI=128)
    prep_deconv12((bx-1944)*256 + t, 128, d2w, w2d2);
  } else if (bx < 3064) {                // deconv3: 24576
    int i = (bx-2968)*256 + t;
    if (i < 24576) {
      int k = i % 1536, co = i / 1536;
      int ch = k / 96, rem = k % 96;
      int tap = rem >> 3, cil = rem & 7;
      int ci = ch*8 + cil, ky = tap >> 2, kx = tap & 3;
      float v = (co < 3 && kx < 3) ? d3w[(((long)ci*3 + co)*3 + ky)*3 + kx] : 0.f;
      w2d3[i] = bfbits(v);
    }
  } else {                               // esq: 512 codes
    int code = (bx-3064)*256 + t;
    if (code < 512) {
      const float4* ev = (const float4*)(emb + (long)code*64);
      float s = 0.f;
      #pragma unroll
      for (int q=0;q<16;q++){ float4 e4 = ev[q];
        s += e4.x*e4.x + e4.y*e4.y + e4.z*e4.z + e4.w*e4.w; }
      esq[code] = s;
    }
  }
}

// ---------------- conv1: f32 direct, out 3 bf16 planes INTERLEAVED ----------------
__global__ __launch_bounds__(256) void conv1_split(
    const float* __restrict__ x, const float* __restrict__ w2,
    const float* __restrict__ bias, unsigned short* __restrict__ h1, long PS1) {
  __shared__ __align__(16) float sIn[3][18][20];
  __shared__ __align__(16) float sW[3*16*64];
  const int tid = threadIdx.x;
  const int b = blockIdx.z >> 1, cog = blockIdx.z & 1;
  const int co0 = cog*64;
  const int oy0 = blockIdx.y*8, ox0 = blockIdx.x*8;
  const int cg2 = tid >> 5;
  const int pg2 = tid & 31;
  const int r = pg2 >> 2, pxp = (pg2 & 3)*2;
  float acc[8][2];
  #pragma unroll
  for (int c=0;c<8;c++){ float bv = bias[co0 + cg2*8 + c];
    acc[c][0]=bv; acc[c][1]=bv; }
  const float* xb = x + (long)b*3*256*256;
  const int iy0 = 2*oy0 - 1, ix0 = 2*ox0 - 1;
  for (int t=tid; t<3*18*18; t+=256) {
    int xx = t%18, yy=(t/18)%18, ci=t/324;
    int gy = iy0+yy, gx = ix0+xx;
    float v = 0.f;
    if (gy>=0 && gy<256 && gx>=0 && gx<256) v = xb[((long)ci*256+gy)*256+gx];
    sIn[ci][yy][xx] = v;
  }
  for (int t=tid; t<3*16*64; t+=256) {
    sW[t] = w2[(long)(t>>6)*128 + co0 + (t&63)];
  }
  __syncthreads();
  for (int ci=0; ci<3; ci++) {
    #pragma unroll
    for (int ky=0;ky<4;ky++)
    #pragma unroll
    for (int kx=0;kx<4;kx++) {
      const float* wp = &sW[(ci*16 + ky*4+kx)*64 + cg2*8];
      float4 w0 = *(const float4*)wp;
      float4 w1 = *(const float4*)(wp+4);
      const int yy = 2*r + ky;
      #pragma unroll
      for (int p=0;p<2;p++) {
        float iv = sIn[ci][yy][2*(pxp+p)+kx];
        acc[0][p] += w0.x*iv; acc[1][p] += w0.y*iv;
        acc[2][p] += w0.z*iv; acc[3][p] += w0.w*iv;
        acc[4][p] += w1.x*iv; acc[5][p] += w1.y*iv;
        acc[6][p] += w1.z*iv; acc[7][p] += w1.w*iv;
      }
    }
  }
  const int chg = cog*8 + cg2;
  #pragma unroll
  for (int p=0;p<2;p++) {
    unsigned short th[8], tm[8], tl[8];
    #pragma unroll
    for (int c=0;c<8;c++) {
      float v = fmaxf(acc[c][p], 0.f);
      split3(v, th[c], tm[c], tl[c]);
    }
    long base = (((long)(b*128 + oy0+r)*16 + chg)*128 + ox0+pxp+p)*8;
    *(uint4*)(h1 + base)          = *(uint4*)th;
    *(uint4*)(h1 + PS1 + base)    = *(uint4*)tm;
    *(uint4*)(h1 + 2*PS1 + base)  = *(uint4*)tl;
  }
}

// ---------------- conv2: MFMA 6-term split; B via global_load_lds; coalesced epilogue -----
__global__ __launch_bounds__(256, 2) void conv2_mfma(
    const unsigned short* __restrict__ h1, long PS1,
    const unsigned short* __restrict__ w2,   // LDS-image: [cog][ch][24576 shorts]
    const float* __restrict__ bias,
    unsigned short* __restrict__ h2, long PS2) {
  __shared__ __align__(16) unsigned short sA[3][4][130][8];
  __shared__ __align__(16) unsigned short sB[24576];
  const int tid = threadIdx.x;
  const int oy = blockIdx.x, cog = blockIdx.y, b = blockIdx.z;
  const int wave = tid >> 6, lane = tid & 63;
  const int wr = wave >> 1, wc = wave & 1;
  const int col_l = lane & 15, kg = lane >> 4;
  const int iy0 = 2*oy - 1;
  f32x4 acc[2][2] = {};
  unsigned short* sAf = &sA[0][0][0][0];
  const unsigned short* bsrc = w2 + (long)cog*16*24576;

  int aOff[6], aLdsO[6]; bool aOk[6];
  #pragma unroll
  for (int j = 0; j < 6; ++j) {
    int idx = tid + j*256;
    int px = idx & 127, rr = (idx >> 7) & 3, pl = idx >> 9;
    int iy = iy0 + rr;
    aOk[j] = (iy >= 0 && iy < 128);
    aOff[j] = (int)(pl*PS1 + (long)(b*128 + (aOk[j]?iy:0))*16384 + px*8);
    aLdsO[j] = ((pl*4 + rr)*130 + px + 1)*8;
  }
  uint4 pA[6];
  #pragma unroll
  for (int j=0;j<6;j++)  pA[j] = aOk[j] ? *(const uint4*)(h1 + aOff[j]) : zero4();

  if (tid < 24) {
    int pl = tid>>3, rr=(tid>>1)&3, c=tid&1;
    *(uint4*)&sA[pl][rr][c?129:0][0] = zero4();
  }

  for (int ch = 0; ch < 16; ++ch) {
    __syncthreads();
    #pragma unroll
    for (int j=0;j<6;j++)  *(uint4*)(sAf + aLdsO[j]) = pA[j];
    #pragma unroll
    for (int j = 0; j < 12; ++j) {
      int blk = wave*12 + j;
      gload_lds16(bsrc + (long)ch*24576 + blk*512 + lane*8, &sB[blk*512]);
    }
    if (ch < 15) {
      #pragma unroll
      for (int j=0;j<6;j++)  pA[j] = aOk[j] ? *(const uint4*)(h1 + aOff[j] + (ch+1)*1024) : zero4();
    }
    __syncthreads();
    #pragma unroll
    for (int s = 0; s < 4; ++s) {        // s = ky
      bf16x8 aF[2][3]; bf16x8 bF[2][3];
      const int tap = s*4 + kg;
      #pragma unroll
      for (int mf = 0; mf < 2; ++mf) {
        int ox = wr*32 + mf*16 + col_l;
        #pragma unroll
        for (int pl = 0; pl < 3; ++pl)
          aF[mf][pl] = *(const bf16x8*)&sA[pl][s][2*ox + kg][0];
      }
      #pragma unroll
      for (int nf = 0; nf < 2; ++nf) {
        int co = wc*32 + nf*16 + col_l;
        int ba = (co*16 + (tap ^ (co&15)))*8;
        bF[nf][0] = *(const bf16x8*)&sB[ba];
        bF[nf][1] = *(const bf16x8*)&sB[ba + 8192];
        bF[nf][2] = *(const bf16x8*)&sB[ba + 16384];
      }
      __builtin_amdgcn_s_setprio(1);
      #pragma unroll
      for (int mf = 0; mf < 2; ++mf)
      #pragma unroll
      for (int nf = 0; nf < 2; ++nf) {
        f32x4 a = acc[mf][nf];
        a = MFMA16(aF[mf][0], bF[nf][0], a);
        a = MFMA16(aF[mf][0], bF[nf][1], a);
        a = MFMA16(aF[mf][1], bF[nf][0], a);
        a = MFMA16(aF[mf][0], bF[nf][2], a);
        a = MFMA16(aF[mf][2], bF[nf][0], a);
        a = MFMA16(aF[mf][1], bF[nf][1], a);
        acc[mf][nf] = a;
      }
      __builtin_amdgcn_s_setprio(0);
    }
  }
  __syncthreads();
  #pragma unroll
  for (int nf = 0; nf < 2; ++nf) {
    int co = wc*32 + nf*16 + col_l;
    float bv = bias[cog*64 + co];
    #pragma unroll
    for (int mf = 0; mf < 2; ++mf) {
      int px0 = wr*32 + mf*16 + kg*4;
      u16x4 oh, om, ol;
      #pragma unroll
      for (int r = 0; r < 4; ++r) {
        float v = fmaxf(acc[mf][nf][r] + bv, 0.f);
        unsigned short h,m,l; split3(v,h,m,l);
        oh[r]=h; om[r]=m; ol[r]=l;
      }
      *(u16x4*)&sB[(0*64 + co)*72 + px0] = oh;
      *(u16x4*)&sB[(1*64 + co)*72 + px0] = om;
      *(u16x4*)&sB[(2*64 + co)*72 + px0] = ol;
    }
  }
  __syncthreads();
  #pragma unroll
  for (int j = 0; j < 6; ++j) {
    int idx = tid + j*256;
    int pl = idx >> 9, co_l = (idx >> 3) & 63, q = idx & 7;
    uint4 v = *(const uint4*)&sB[(pl*64 + co_l)*72 + q*8];
    *(uint4*)(h2 + (long)pl*PS2 + ((long)(b*128 + cog*64 + co_l)*64 + oy)*64 + q*8) = v;
  }
}

// ---------------- conv3: MFMA 6-term split; B via global_load_lds; coalesced epilogue -----
__global__ __launch_bounds__(256, 2) void conv3_mfma(
    const unsigned short* __restrict__ h2, long PS2,
    const unsigned short* __restrict__ w2,   // LDS-image: [ch][24576 shorts]
    const float* __restrict__ bias,
    unsigned short* __restrict__ zeH, unsigned short* __restrict__ zeM,
    unsigned short* __restrict__ zeL) {
  __shared__ __align__(16) unsigned short sA[3*67*24];
  __shared__ __align__(16) unsigned short sB[24576];
  const int tid = threadIdx.x;
  const int oy = blockIdx.x, b = blockIdx.z;
  const int wave = tid >> 6, lane = tid & 63;
  const int wr = wave >> 1, wc = wave & 1;
  const int col_l = lane & 15, kg = lane >> 4;
  f32x4 acc[2][2] = {};
  for (int i = tid; i < 3*3*24; i += 256) {
    int j = i % 24, c = (i/24) % 3, rr = i/72;
    int col = (c==0) ? 0 : (c==1 ? 65 : 66);
    sA[(rr*67 + col)*24 + j] = 0;
  }
  const int li = tid & 7, rrA = (tid>>3)%3, ciA = tid/24;
  const int iyA = oy + rrA - 1;
  const bool aAct = (tid < 192);
  const bool aOk = aAct && (iyA >= 0 && iyA < 64);
  const long aBase = ((long)(b*128 + ciA)*64 + (aOk?iyA:0))*64 + li*8;
  uint4 ph, pm, pl4;
  ph = aOk ? *(const uint4*)(h2 + aBase) : zero4();
  pm = aOk ? *(const uint4*)(h2 + PS2 + aBase) : zero4();
  pl4 = aOk ? *(const uint4*)(h2 + 2*PS2 + aBase) : zero4();

  for (int ch = 0; ch < 16; ++ch) {
    __syncthreads();
    if (aAct) {
      const unsigned short* vh = (const unsigned short*)&ph;
      const unsigned short* vm = (const unsigned short*)&pm;
      const unsigned short* vl = (const unsigned short*)&pl4;
      #pragma unroll
      for (int p = 0; p < 8; ++p) {
        int pp = (p + li) & 7;
        int col = li*8 + pp + 1;
        int base = (rrA*67 + col)*24 + ciA;
        sA[base]      = vh[pp];
        sA[base + 8]  = vm[pp];
        sA[base + 16] = vl[pp];
      }
    }
    // B: 48 KB via global_load_lds, 12 instrs/wave, linear dest
    #pragma unroll
    for (int j = 0; j < 12; ++j) {
      int blk = wave*12 + j;
      gload_lds16(w2 + (long)ch*24576 + blk*512 + lane*8, &sB[blk*512]);
    }
    if (ch < 15) {
      long nb = aBase + (long)(ch+1)*32768;
      ph = aOk ? *(const uint4*)(h2 + nb) : zero4();
      pm = aOk ? *(const uint4*)(h2 + PS2 + nb) : zero4();
      pl4 = aOk ? *(const uint4*)(h2 + 2*PS2 + nb) : zero4();
    }
    __syncthreads();
    #pragma unroll
    for (int s = 0; s < 3; ++s) {
      bf16x8 aF[2][3]; bf16x8 bF[2][3];
      const int tap = s*4 + kg;
      #pragma unroll
      for (int mf = 0; mf < 2; ++mf) {
        int ox = wr*32 + mf*16 + col_l;
        int base = (s*67 + ox + kg)*24;
        aF[mf][0] = *(const bf16x8*)&sA[base];
        aF[mf][1] = *(const bf16x8*)&sA[base+8];
        aF[mf][2] = *(const bf16x8*)&sA[base+16];
      }
      #pragma unroll
      for (int nf = 0; nf < 2; ++nf) {
        int co = wc*32 + nf*16 + col_l;
        int ba = (co*16 + (tap ^ (co&15)))*8;
        bF[nf][0] = *(const bf16x8*)&sB[ba];
        bF[nf][1] = *(const bf16x8*)&sB[ba + 8192];
        bF[nf][2] = *(const bf16x8*)&sB[ba + 16384];
      }
      __builtin_amdgcn_s_setprio(1);
      #pragma unroll
      for (int mf = 0; mf < 2; ++mf)
      #pragma unroll
      for (int nf = 0; nf < 2; ++nf) {
        f32x4 a = acc[mf][nf];
        a = MFMA16(aF[mf][0], bF[nf][0], a);
        a = MFMA16(aF[mf][0], bF[nf][1], a);
        a = MFMA16(aF[mf][1], bF[nf][0], a);
        a = MFMA16(aF[mf][0], bF[nf][2], a);
        a = MFMA16(aF[mf][2], bF[nf][0], a);
        a = MFMA16(aF[mf][1], bF[nf][1], a);
        acc[mf][nf] = a;
      }
      __builtin_amdgcn_s_setprio(0);
    }
  }
  // epilogue: acc -> sB[pl][co][72pad] -> full-line coalesced global
  __syncthreads();
  #pragma unroll
  for (int nf = 0; nf < 2; ++nf) {
    int co = wc*32 + nf*16 + col_l;
    float bv = bias[co];
    #pragma unroll
    for (int mf = 0; mf < 2; ++mf) {
      int px0 = wr*32 + mf*16 + kg*4;
      u16x4 oh, om, ol;
      #pragma unroll
      for (int r = 0; r < 4; ++r) {
        float v = acc[mf][nf][r] + bv;
        unsigned short h,m,l; split3(v,h,m,l);
        oh[r]=h; om[r]=m; ol[r]=l;
      }
      *(u16x4*)&sB[(0*64 + co)*72 + px0] = oh;
      *(u16x4*)&sB[(1*64 + co)*72 + px0] = om;
      *(u16x4*)&sB[(2*64 + co)*72 + px0] = ol;
    }
  }
  __syncthreads();
  #pragma unroll
  for (int j = 0; j < 6; ++j) {
    int idx = tid + j*256;
    int pl = idx >> 9, co_l = (idx >> 3) & 63, q = idx & 7;
    uint4 v = *(const uint4*)&sB[(pl*64 + co_l)*72 + q*8];
    unsigned short* dst = (pl==0) ? zeH : ((pl==1) ? zeM : zeL);
    *(uint4*)(dst + ((long)(b*64 + co_l)*64 + oy)*64 + q*8) = v;
  }
}

// ---------------- MFMA ConvTranspose2d stride2 k4 pad1 (unchanged) ----------
template<int TX, int MODE>
struct SmemD {
  union {
    struct { __align__(16) unsigned short In[2][TX+2][24];
             __align__(16) unsigned short W[2*128*64]; } o;
    struct { __align__(16) unsigned short In[2][TX+2][16];
             __align__(16) unsigned short W[2*128*64]; } v;
    __align__(16) unsigned short Out[2*TX][136];
  };
};

template<int CIN, int TX, int MODE>
__global__ __launch_bounds__(TX*4, (TX==64)?3:4) void deconv_mfma(
    const void* __restrict__ xin, const unsigned short* __restrict__ w2,
    const float* __restrict__ bias, unsigned short* __restrict__ yI) {
  constexpr int NTHR = TX*4;
  constexpr int K    = CIN*4;
  constexpr int NW   = 2048/NTHR;
  __shared__ SmemD<TX,MODE> sm;
  unsigned short* Wb = MODE ? &sm.v.W[0] : &sm.o.W[0];

  const int tid = threadIdx.x;
  const int ty = blockIdx.x, e = blockIdx.y, b = blockIdx.z;
  const int wave = tid >> 6, lane = tid & 63;
  const int wc = wave & 1, wr = wave >> 1;
  const int f = (wr*64) / TX;
  const int tx_base = (wr*64) & (TX-1);
  const int col_l = lane & 15, kg = lane >> 4;

  int wOff[NW], wLdsO[NW];
  #pragma unroll
  for (int j = 0; j < NW; ++j) {
    int i = tid + j*NTHR;
    int s = i & 7, co = (i >> 3) & 127, ff = i >> 10;
    wOff[j] = ((e*2+ff)*128 + co)*K + s*8;
    wLdsO[j] = (ff*128 + co)*64 + (s ^ (co & 7))*8;
  }
  uint4 pW[NW];
  #pragma unroll
  for (int j=0;j<NW;j++) pW[j] = *(const uint4*)(w2 + wOff[j]);

  constexpr int TPR = NTHR/32;
  const int rowid = tid / TPR, liO = tid % TPR;
  const int sci = rowid >> 1, srr = rowid & 1;
  float4 pLo, pHi; uint4 pIn;
  long aBase = 0; bool aOk = false;
  int pxV = 0, halfV = 0, rrV = 0;
  if (MODE == 0) {
    int iy = ty + e - 1 + srr;
    aOk = (iy >= 0 && iy < TX);
    aBase = ((long)b*CIN + sci)*TX*TX + (long)(aOk?iy:0)*TX + liO*8;
    if (aOk) { const float4* s4 = (const float4*)((const float*)xin + aBase);
               pLo = s4[0]; pHi = s4[1]; }
  } else {
    halfV = tid & 1; pxV = (tid >> 1) & (TX-1); rrV = tid >> 8;
    int iy = ty + e - 1 + rrV;
    aOk = (iy >= 0 && iy < TX);
    aBase = ((long)b*TX + (aOk?iy:0))*((long)(CIN/8)*TX*8) + (long)halfV*TX*8 + pxV*8;
    pIn = aOk ? *(const uint4*)((const unsigned short*)xin + aBase) : zero4();
  }

  if (MODE == 0) {
    if (tid < 64) {
      int rr = tid & 1, cc = ((tid>>1)&1) ? TX+1 : 0, ci = tid >> 2;
      sm.o.In[rr][cc][ci] = 0;
    }
  } else {
    if (tid < 8) {
      int rr = tid & 1, c = (tid>>1)&1, hf = (tid>>2)&1;
      *(uint4*)&sm.v.In[rr][c?TX+1:0][hf*8] = zero4();
    }
  }

  f32x4 acc[4][4] = {};
  for (int ch = 0; ch < CIN/16; ++ch) {
    __syncthreads();
    if (MODE == 0) {
      unsigned short vals[8];
      if (aOk) {
        float4 lo = pLo, hi = pHi;
        vals[0]=bfbits(lo.x); vals[1]=bfbits(lo.y); vals[2]=bfbits(lo.z); vals[3]=bfbits(lo.w);
        vals[4]=bfbits(hi.x); vals[5]=bfbits(hi.y); vals[6]=bfbits(hi.z); vals[7]=bfbits(hi.w);
      } else {
        #pragma unroll
        for (int j=0;j<8;j++) vals[j] = 0;
      }
      #pragma unroll
      for (int j=0;j<8;j++) {
        int jj = (j + liO) & 7;
        sm.o.In[srr][1 + liO*8 + jj][sci] = vals[jj];
      }
    } else {
      *(uint4*)&sm.v.In[rrV][pxV+1][halfV*8] = pIn;
    }
    #pragma unroll
    for (int j=0;j<NW;j++) *(uint4*)(Wb + wLdsO[j]) = pW[j];
    if (ch + 1 < CIN/16) {
      if (MODE == 0) {
        if (aOk) { const float4* s4 = (const float4*)((const float*)xin + aBase + (long)(ch+1)*16*TX*TX);
                   pLo = s4[0]; pHi = s4[1]; }
      } else {
        pIn = aOk ? *(const uint4*)((const unsigned short*)xin + aBase + (ch+1)*2*TX*8) : zero4();
      }
      #pragma unroll
      for (int j=0;j<NW;j++) pW[j] = *(const uint4*)(w2 + wOff[j] + (ch+1)*64);
    }
    __syncthreads();
    #pragma unroll
    for (int kk = 0; kk < 2; ++kk) {
      bf16x8 aF[4];
      const int tap = kk*2 + (kg >> 1), a = tap >> 1, bb = tap & 1;
      #pragma unroll
      for (int mf = 0; mf < 4; ++mf) {
        int tx = tx_base + mf*16 + col_l;
        if (MODE == 0) aF[mf] = *(const bf16x8*)&sm.o.In[1-a][tx + 1 + f - bb][(kg&1)*8];
        else           aF[mf] = *(const bf16x8*)&sm.v.In[1-a][tx + 1 + f - bb][(kg&1)*8];
      }
      const int slot = kk*4 + kg;
      __builtin_amdgcn_s_setprio(1);
      #pragma unroll
      for (int nf = 0; nf < 4; ++nf) {
        int co_l = nf*16 + col_l;
        bf16x8 bF = *(const bf16x8*)(Wb + (f*128 + wc*64 + co_l)*64 + (slot ^ (co_l & 7))*8);
        #pragma unroll
        for (int mf = 0; mf < 4; ++mf)
          acc[mf][nf] = MFMA16(aF[mf], bF, acc[mf][nf]);
      }
      __builtin_amdgcn_s_setprio(0);
    }
  }

  __syncthreads();
  float bv[4];
  #pragma unroll
  for (int nf = 0; nf < 4; ++nf) bv[nf] = bias[wc*64 + nf*16 + col_l];
  #pragma unroll
  for (int mf = 0; mf < 4; ++mf)
  #pragma unroll
  for (int nf = 0; nf < 4; ++nf) {
    int co = wc*64 + nf*16 + col_l;
    #pragma unroll
    for (int r = 0; r < 4; ++r) {
      int tx = tx_base + mf*16 + kg*4 + r;
      float v = fmaxf(acc[mf][nf][r] + bv[nf], 0.f);
      int ox = 2*tx + f;
      sm.Out[ox][co ^ (((ox>>3)&7)<<3)] = bfbits(v);
    }
  }
  __syncthreads();
  const int oy = 2*ty + e;
  #pragma unroll
  for (int j = 0; j < 8; ++j) {
    int i = tid + j*NTHR;
    int px = i & (2*TX-1), chn = i / (2*TX);
    uint4 vv = *(const uint4*)&sm.Out[px][(chn*8) ^ (((px>>3)&7)<<3)];
    *(uint4*)(yI + ((((long)b*(2*TX) + oy)*16 + chn)*(2*TX) + px)*8) = vv;
  }
}

// ---------------- deconv3: MFMA + sigmoid (unchanged) ----------
__global__ __launch_bounds__(256, 2) void deconv3_mfma(
    const unsigned short* __restrict__ g2I,
    const unsigned short* __restrict__ w2,
    const float* __restrict__ bias, float* __restrict__ y) {
  __shared__ __align__(16) unsigned short sA[3][260][8];
  __shared__ __align__(16) unsigned short sB[16*12*16*8];
  const int tid = threadIdx.x;
  const int oy = blockIdx.x, b = blockIdx.y;
  const int wave = tid >> 6, lane = tid & 63;
  const int col_l = lane & 15, kg = lane >> 4;
  const int pxb = wave*64;
  for (int i = tid; i < 3072; i += 256) {
    int co = i & 15, tap = (i>>4) % 12, ch = i/192;
    *(uint4*)&sB[((ch*12+tap)*16+co)*8] = *(const uint4*)(w2 + (long)co*1536 + ch*96 + tap*8);
  }
  if (tid < 12) {
    int dy = tid >> 2, c = tid & 3;
    *(uint4*)&sA[dy][(c<2)?c:(256+c)][0] = zero4();
  }
  long aBase[3]; int aLdsO[3]; bool aOk[3];
  #pragma unroll
  for (int u = 0; u < 3; ++u) {
    int idx = tid + u*256;
    int px = idx & 255, dy = idx >> 8;
    int iy = oy - 1 + dy;
    aOk[u] = (iy >= 0 && iy < 256);
    aBase[u] = ((long)(b*256 + (aOk[u]?iy:0)))*32768 + px*8;
    aLdsO[u] = (dy*260 + px + 2)*8;
  }
  uint4 pA[3];
  #pragma unroll
  for (int u=0;u<3;u++) pA[u] = aOk[u] ? *(const uint4*)(g2I + aBase[u]) : zero4();

  unsigned short* sAf = &sA[0][0][0];
  f32x4 acc[4] = {};
  for (int ch = 0; ch < 16; ++ch) {
    __syncthreads();
    #pragma unroll
    for (int u=0;u<3;u++) *(uint4*)(sAf + aLdsO[u]) = pA[u];
    if (ch < 15) {
      #pragma unroll
      for (int u=0;u<3;u++)
        pA[u] = aOk[u] ? *(const uint4*)(g2I + aBase[u] + (ch+1)*2048) : zero4();
    }
    __syncthreads();
    #pragma unroll
    for (int s = 0; s < 3; ++s) {
      bf16x8 bF = *(const bf16x8*)&sB[((ch*12 + s*4 + kg)*16 + col_l)*8];
      __builtin_amdgcn_s_setprio(1);
      #pragma unroll
      for (int mf = 0; mf < 4; ++mf) {
        int px = pxb + mf*16 + col_l;
        bf16x8 aF = *(const bf16x8*)&sA[2-s][px + 3 - kg][0];
        acc[mf] = MFMA16(aF, bF, acc[mf]);
      }
      __builtin_amdgcn_s_setprio(0);
    }
  }
  if (col_l < 3) {
    float bv = bias[col_l];
    #pragma unroll
    for (int mf = 0; mf < 4; ++mf) {
      int px = pxb + mf*16 + kg*4;
      float4 o;
      o.x = 1.f/(1.f + expf(-(acc[mf][0] + bv)));
      o.y = 1.f/(1.f + expf(-(acc[mf][1] + bv)));
      o.z = 1.f/(1.f + expf(-(acc[mf][2] + bv)));
      o.w = 1.f/(1.f + expf(-(acc[mf][3] + bv)));
      *(float4*)(y + ((long)(b*3 + col_l)*256 + oy)*256 + px) = o;
    }
  }
}

// ---------------- VQ via MFMA (unchanged) ----------------
__global__ __launch_bounds__(256, 2) void vq_mfma(
    const unsigned short* __restrict__ zeH, const unsigned short* __restrict__ zeM,
    const unsigned short* __restrict__ zeL,
    const float* __restrict__ emb, const float* __restrict__ esq,
    float* __restrict__ out_idx, float* __restrict__ zq) {
  __shared__ __align__(16) unsigned short sA[64*3*8*8];
  __shared__ __align__(16) unsigned short sB[128*3*8*8];
  __shared__ float snb[128];
  __shared__ int sidx[64];
  const int tid = threadIdx.x;
  const long n0 = (long)blockIdx.x*64;
  const int wave = tid >> 6, lane = tid & 63;
  const int col = lane & 15, kg = lane >> 4;

  #pragma unroll
  for (int j = 0; j < 6; ++j) {
    int idx = tid + j*256;
    int pl = idx >> 9, rem = idx & 511;
    int n = rem >> 3, slot = rem & 7;
    const unsigned short* src = (pl==0 ? zeH : (pl==1 ? zeM : zeL)) + (n0+n)*64 + slot*8;
    *(uint4*)&sA[((n*3 + pl)*8 + (slot ^ (n&7)))*8] = *(const uint4*)src;
  }

  const int codeT = tid >> 1, halfT = tid & 1;
  float4 pB[8];
  #pragma unroll
  for (int q = 0; q < 8; ++q)
    pB[q] = *(const float4*)(emb + (long)codeT*64 + halfT*32 + q*4);
  float pSn = (tid < 128) ? esq[tid] : 0.f;

  float best[4] = {3.4e38f,3.4e38f,3.4e38f,3.4e38f};
  int bidx[4] = {0,0,0,0};

  for (int ch = 0; ch < 4; ++ch) {
    __syncthreads();
    #pragma unroll
    for (int s4 = 0; s4 < 4; ++s4) {
      int slot = halfT*4 + s4;
      float4 lo = pB[s4*2], hi = pB[s4*2+1];
      unsigned short th[8], tm[8], tl[8];
      split3(lo.x, th[0], tm[0], tl[0]); split3(lo.y, th[1], tm[1], tl[1]);
      split3(lo.z, th[2], tm[2], tl[2]); split3(lo.w, th[3], tm[3], tl[3]);
      split3(hi.x, th[4], tm[4], tl[4]); split3(hi.y, th[5], tm[5], tl[5]);
      split3(hi.z, th[6], tm[6], tl[6]); split3(hi.w, th[7], tm[7], tl[7]);
      int base = ((codeT*3)*8 + (slot ^ (codeT&7)))*8;
      *(uint4*)&sB[base]       = *(uint4*)th;
      *(uint4*)&sB[base + 64]  = *(uint4*)tm;
      *(uint4*)&sB[base + 128] = *(uint4*)tl;
    }
    if (tid < 128) snb[tid] = pSn;
    if (ch < 3) {
      #pragma unroll
      for (int q = 0; q < 8; ++q)
        pB[q] = *(const float4*)(emb + ((long)(ch+1)*128 + codeT)*64 + halfT*32 + q*4);
      if (tid < 128) pSn = esq[(ch+1)*128 + tid];
    }
    __syncthreads();

    f32x4 acc[8] = {};
    #pragma unroll
    for (int kk = 0; kk < 2; ++kk) {
      const int nloc = wave*16 + col;
      const int slot = kk*4 + kg;
      bf16x8 aF[3];
      #pragma unroll
      for (int pl = 0; pl < 3; ++pl)
        aF[pl] = *(const bf16x8*)&sA[((nloc*3 + pl)*8 + (slot ^ (nloc&7)))*8];
      __builtin_amdgcn_s_setprio(1);
      #pragma unroll
      for (int cf = 0; cf < 8; ++cf) {
        int cl = cf*16 + col;
        int bb = ((cl*3)*8 + (slot ^ (cl&7)))*8;
        bf16x8 b0 = *(const bf16x8*)&sB[bb];
        bf16x8 b1 = *(const bf16x8*)&sB[bb + 64];
        bf16x8 b2 = *(const bf16x8*)&sB[bb + 128];
        f32x4 a = acc[cf];
        a = MFMA16(aF[0], b0, a);
        a = MFMA16(aF[0], b1, a);
        a = MFMA16(aF[1], b0, a);
        a = MFMA16(aF[0], b2, a);
        a = MFMA16(aF[2], b0, a);
        a = MFMA16(aF[1], b1, a);
        acc[cf] = a;
      }
      __builtin_amdgcn_s_setprio(0);
    }
    #pragma unroll
    for (int cf = 0; cf < 8; ++cf) {
      float sv = snb[cf*16 + col];
      int code = ch*128 + cf*16 + col;
      #pragma unroll
      for (int j = 0; j < 4; ++j) {
        float s = sv - 2.f*acc[cf][j];
        if (s < best[j]) { best[j] = s; bidx[j] = code; }
      }
    }
  }

  #pragma unroll
  for (int j = 0; j < 4; ++j) {
    float b = best[j]; int ii = bidx[j];
    #pragma unroll
    for (int off = 1; off < 16; off <<= 1) {
      float ob = __shfl_xor(b, off);
      int oi = __shfl_xor(ii, off);
      if (ob < b || (ob == b && oi < ii)) { b = ob; ii = oi; }
    }
    if (col == 0) sidx[wave*16 + kg*4 + j] = ii;
  }
  __syncthreads();
  if (tid < 64) out_idx[n0 + tid] = (float)sidx[tid];
  #pragma unroll
  for (int j = 0; j < 4; ++j) {
    int t = tid + j*256;
    int row = t >> 4, q = t & 15;
    float4 v = *(const float4*)(emb + (long)sidx[row]*64 + q*4);
    *(float4*)(zq + (n0 + row)*64 + q*4) = v;
  }
}

// ---------------- launch ----------------
extern "C" void kernel_launch(void* const* d_in, const int* in_sizes, int n_in,
                              void* d_out, int out_size, void* d_ws, size_t ws_size,
                              hipStream_t stream) {
  const float* x   = (const float*)d_in[0];
  const float* c1w = (const float*)d_in[1];  const float* c1b = (const float*)d_in[2];
  const float* c2w = (const float*)d_in[3];  const float* c2b = (const float*)d_in[4];
  const float* c3w = (const float*)d_in[5];  const float* c3b = (const float*)d_in[6];
  const float* emb = (const float*)d_in[7];
  const float* d1w = (const float*)d_in[8];  const float* d1b = (const float*)d_in[9];
  const float* d2w = (const float*)d_in[10]; const float* d2b = (const float*)d_in[11];
  const float* d3w = (const float*)d_in[12]; const float* d3b = (const float*)d_in[13];
  float* out = (float*)d_out;

  float* xrec = out;
  float* oidx = out + 3145728;
  float* zq   = out + 3211264;

  const long XB  = 196608;   // 3*256*256
  const long ZEB = 262144;   // ze elems per batch
  const long PS1 = 8388608;  // per-plane h1 (interleaved) in shorts
  const long PS2 = 4194304;  // per-plane h2 in shorts

  const size_t NEEDED = 112273408ULL;  // known: ws_size >= 120,395,264
  if (ws_size < NEEDED) return;
  char* wsb = (char*)d_ws;
  unsigned short* h1grp = (unsigned short*)wsb;              // interleaved, 50.3MB
  unsigned short* g2grp = (unsigned short*)wsb;              // interleaved, 64MB
  unsigned short* h2grp = (unsigned short*)(wsb + 67108864); // planar 3-plane, 24MB
  unsigned short* g1grp = (unsigned short*)(wsb + 67108864); // interleaved, 16MB
  unsigned short* zeH = (unsigned short*)(wsb + 92274688);
  unsigned short* zeM = (unsigned short*)(wsb + 100663296);
  unsigned short* zeL = (unsigned short*)out;                // xrec region: dead until deconv3
  char* W = wsb + 109051904;
  float* w2c1          = (float*)(W);                        // 24,576 B
  unsigned short* w2c2 = (unsigned short*)(W + 24576);       // LDS-image, 1,572,864 B
  unsigned short* w2c3 = (unsigned short*)(W + 1597440);     // LDS-image, 786,432 B
  unsigned short* w2d1 = (unsigned short*)(W + 2383872);     // 262,144 B
  unsigned short* w2d2 = (unsigned short*)(W + 2646016);     // 524,288 B
  unsigned short* w2d3 = (unsigned short*)(W + 3170304);     // 49,152 B
  float* esq           = (float*)(W + 3219456);              // 2,048 B

  wprep_all<<<3066, 256, 0, stream>>>(c1w, w2c1, c2w, w2c2, c3w, w2c3,
                                      d1w, w2d1, d2w, w2d2, d3w, w2d3, emb, esq);

  // encoder
  for (int g = 0; g < 4; ++g) {
    conv1_split<<<dim3(16,16,8), 256, 0, stream>>>(
        x + (long)g*4*XB, w2c1, c1b, h1grp, PS1);
    conv2_mfma<<<dim3(64,2,4), 256, 0, stream>>>(
        h1grp, PS1, w2c2, c2b, h2grp + (long)(g&1)*4*524288, PS2);
    if (g & 1) {
      long zo = (long)(g>>1)*8*ZEB;
      conv3_mfma<<<dim3(64,1,8), 256, 0, stream>>>(
          h2grp, PS2, w2c3, c3b, zeH + zo, zeM + zo, zeL + zo);
    }
  }
  vq_mfma<<<1024, 256, 0, stream>>>(zeH, zeM, zeL, emb, esq, oidx, zq);

  // decoder
  for (int g = 0; g < 4; ++g) {
    deconv_mfma<64, 64, 0 ><<<dim3(64, 2, 4), 256, 0, stream>>>(
        (const void*)(zq + (long)g*4*ZEB), w2d1, d1b, g1grp);
    deconv_mfma<128,128,1 ><<<dim3(128,2,4), 512, 0, stream>>>(
        (const void*)g1grp, w2d2, d2b, g2grp);
    deconv3_mfma<<<dim3(256,4), 256, 0, stream>>>(
        g2grp, w2d3, d3b, xrec + (long)g*4*XB);
  }
}

// Round 11
// 828.775 us; speedup vs baseline: 7.2143x; 1.3064x over previous
//
#include <hip/hip_runtime.h>
#include <hip/hip_bf16.h>

#define DEV __device__ __forceinline__

typedef __attribute__((ext_vector_type(8))) short bf16x8;
typedef __attribute__((ext_vector_type(4))) float f32x4;
typedef __attribute__((ext_vector_type(4))) unsigned short u16x4;

#define MFMA16(a,b,c) __builtin_amdgcn_mfma_f32_16x16x32_bf16(a,b,c,0,0,0)

DEV unsigned short bfbits(float v){ __hip_bfloat16 h = __float2bfloat16(v); return *(unsigned short*)&h; }
DEV float bf2f(unsigned short u){ __hip_bfloat16 h = *(__hip_bfloat16*)&u; return __bfloat162float(h); }
DEV void split3(float v, unsigned short& h, unsigned short& m, unsigned short& l) {
  h = bfbits(v);        float r  = v - bf2f(h);
  m = bfbits(r);        float r2 = r - bf2f(m);
  l = bfbits(r2);
}
DEV uint4 zero4(){ uint4 z; z.x=0; z.y=0; z.z=0; z.w=0; return z; }
DEV void gload_lds16(const void* g, void* l) {
  __builtin_amdgcn_global_load_lds(
      (const __attribute__((address_space(1))) void*)g,
      (__attribute__((address_space(3))) void*)l, 16, 0, 0);
}

// ---------------- fused weight prep (one dispatch, 3066 blocks) ----------------
// deconv1/2 -> per-(e,ch) 32KB LDS-image: dst = (e*nch+ch)*16384 + (f*128+co)*64 + (s^(co&7))*8 + cil
DEV void prep_deconv_img(int i, int CI, const float* __restrict__ w, unsigned short* __restrict__ w2) {
  const int nch = CI/16;
  int cil = i & 7, s = (i >> 3) & 7, co = (i >> 6) & 127, f = (i >> 13) & 1;
  int rest = i >> 14;
  int ch = rest % nch, e = rest / nch;
  int k = ch*64 + s*8 + cil;
  int ci = (k & 15) | ((k >> 6) << 4);
  int tap = (k >> 4) & 3, a = tap >> 1, b = tap & 1;
  float v = w[ (((long)ci*128 + co)*4 + (2*a+1-e))*4 + (2*b+1-f) ];
  w2[(long)(e*nch + ch)*16384 + ((long)(f*128 + co))*64 + ((s ^ (co&7))*8) + cil] = bfbits(v);
}
__global__ __launch_bounds__(256) void wprep_all(
    const float* __restrict__ c1w, float* __restrict__ w2c1,
    const float* __restrict__ c2w, unsigned short* __restrict__ w2c2,
    const float* __restrict__ c3w, unsigned short* __restrict__ w2c3,
    const float* __restrict__ d1w, unsigned short* __restrict__ w2d1,
    const float* __restrict__ d2w, unsigned short* __restrict__ w2d2,
    const float* __restrict__ d3w, unsigned short* __restrict__ w2d3,
    const float* __restrict__ emb, float* __restrict__ esq) {
  const int bx = blockIdx.x, t = threadIdx.x;
  if (bx < 24) {                         // conv1 transpose: 6144
    int i = bx*256 + t;
    if (i < 6144) {
      int tap = i & 15, ci = (i>>4) % 3, co = i / 48;
      w2c1[((long)ci*16 + tap)*128 + co] = c1w[i];
    }
  } else if (bx < 1048) {                // conv2 prep -> LDS-image layout
    int i = (bx-24)*256 + t;             // 0..262143
    int cil = i & 7, s = (i>>3) & 15, co = (i>>7) & 63;
    int ch = (i>>13) & 15, cog = i >> 17;
    int co_g = cog*64 + co, ci = ch*8 + cil, ky = s >> 2, kx = s & 3;
    float v = c2w[(((long)co_g*128 + ci)*4 + ky)*4 + kx];
    unsigned short h,m,l; split3(v,h,m,l);
    long base = (long)(cog*16 + ch)*24576 + ((long)co*16 + (s ^ (co&15)))*8 + cil;
    w2c2[base] = h; w2c2[base + 8192] = m; w2c2[base + 16384] = l;
  } else if (bx < 1432) {                // conv3 prep -> LDS-image layout: 98304
    int i = (bx-1048)*256 + t;
    int k = i % 1536, co = i / 1536;
    int ch = k / 96, rem = k % 96;
    int tap = rem >> 3, cil = rem & 7;
    int ci = ch*8 + cil, ky = tap >> 2, kx = tap & 3;
    float v = (kx < 3) ? c3w[(((long)co*128 + ci)*3 + ky)*3 + kx] : 0.f;
    unsigned short h,m,l; split3(v,h,m,l);
    long base = (long)ch*24576 + ((long)co*16 + (tap ^ (co&15)))*8 + cil;
    w2c3[base] = h; w2c3[base + 8192] = m; w2c3[base + 16384] = l;
  } else if (bx < 1944) {                // deconv1 image: 131072 (CI=64)
    prep_deconv_img((bx-1432)*256 + t, 64, d1w, w2d1);
  } else if (bx < 2968) {                // deconv2 image: 262144 (CI=128)
    prep_deconv_img((bx-1944)*256 + t, 128, d2w, w2d2);
  } else if (bx < 3064) {                // deconv3: 24576
    int i = (bx-2968)*256 + t;
    if (i < 24576) {
      int k = i % 1536, co = i / 1536;
      int ch = k / 96, rem = k % 96;
      int tap = rem >> 3, cil = rem & 7;
      int ci = ch*8 + cil, ky = tap >> 2, kx = tap & 3;
      float v = (co < 3 && kx < 3) ? d3w[(((long)ci*3 + co)*3 + ky)*3 + kx] : 0.f;
      w2d3[i] = bfbits(v);
    }
  } else {                               // esq: 512 codes
    int code = (bx-3064)*256 + t;
    if (code < 512) {
      const float4* ev = (const float4*)(emb + (long)code*64);
      float s = 0.f;
      #pragma unroll
      for (int q=0;q<16;q++){ float4 e4 = ev[q];
        s += e4.x*e4.x + e4.y*e4.y + e4.z*e4.z + e4.w*e4.w; }
      esq[code] = s;
    }
  }
}

// ---------------- conv1: f32 direct, out 3 bf16 planes INTERLEAVED ----------------
__global__ __launch_bounds__(256) void conv1_split(
    const float* __restrict__ x, const float* __restrict__ w2,
    const float* __restrict__ bias, unsigned short* __restrict__ h1, long PS1) {
  __shared__ __align__(16) float sIn[3][18][20];
  __shared__ __align__(16) float sW[3*16*64];
  const int tid = threadIdx.x;
  const int b = blockIdx.z >> 1, cog = blockIdx.z & 1;
  const int co0 = cog*64;
  const int oy0 = blockIdx.y*8, ox0 = blockIdx.x*8;
  const int cg2 = tid >> 5;
  const int pg2 = tid & 31;
  const int r = pg2 >> 2, pxp = (pg2 & 3)*2;
  float acc[8][2];
  #pragma unroll
  for (int c=0;c<8;c++){ float bv = bias[co0 + cg2*8 + c];
    acc[c][0]=bv; acc[c][1]=bv; }
  const float* xb = x + (long)b*3*256*256;
  const int iy0 = 2*oy0 - 1, ix0 = 2*ox0 - 1;
  for (int t=tid; t<3*18*18; t+=256) {
    int xx = t%18, yy=(t/18)%18, ci=t/324;
    int gy = iy0+yy, gx = ix0+xx;
    float v = 0.f;
    if (gy>=0 && gy<256 && gx>=0 && gx<256) v = xb[((long)ci*256+gy)*256+gx];
    sIn[ci][yy][xx] = v;
  }
  for (int t=tid; t<3*16*64; t+=256) {
    sW[t] = w2[(long)(t>>6)*128 + co0 + (t&63)];
  }
  __syncthreads();
  for (int ci=0; ci<3; ci++) {
    #pragma unroll
    for (int ky=0;ky<4;ky++)
    #pragma unroll
    for (int kx=0;kx<4;kx++) {
      const float* wp = &sW[(ci*16 + ky*4+kx)*64 + cg2*8];
      float4 w0 = *(const float4*)wp;
      float4 w1 = *(const float4*)(wp+4);
      const int yy = 2*r + ky;
      #pragma unroll
      for (int p=0;p<2;p++) {
        float iv = sIn[ci][yy][2*(pxp+p)+kx];
        acc[0][p] += w0.x*iv; acc[1][p] += w0.y*iv;
        acc[2][p] += w0.z*iv; acc[3][p] += w0.w*iv;
        acc[4][p] += w1.x*iv; acc[5][p] += w1.y*iv;
        acc[6][p] += w1.z*iv; acc[7][p] += w1.w*iv;
      }
    }
  }
  const int chg = cog*8 + cg2;
  #pragma unroll
  for (int p=0;p<2;p++) {
    unsigned short th[8], tm[8], tl[8];
    #pragma unroll
    for (int c=0;c<8;c++) {
      float v = fmaxf(acc[c][p], 0.f);
      split3(v, th[c], tm[c], tl[c]);
    }
    long base = (((long)(b*128 + oy0+r)*16 + chg)*128 + ox0+pxp+p)*8;
    *(uint4*)(h1 + base)          = *(uint4*)th;
    *(uint4*)(h1 + PS1 + base)    = *(uint4*)tm;
    *(uint4*)(h1 + 2*PS1 + base)  = *(uint4*)tl;
  }
}

// ---------------- conv2: MFMA 6-term split; B via global_load_lds; coalesced epilogue -----
__global__ __launch_bounds__(256, 2) void conv2_mfma(
    const unsigned short* __restrict__ h1, long PS1,
    const unsigned short* __restrict__ w2,   // LDS-image: [cog][ch][24576 shorts]
    const float* __restrict__ bias,
    unsigned short* __restrict__ h2, long PS2) {
  __shared__ __align__(16) unsigned short sA[3][4][130][8];
  __shared__ __align__(16) unsigned short sB[24576];
  const int tid = threadIdx.x;
  const int oy = blockIdx.x, cog = blockIdx.y, b = blockIdx.z;
  const int wave = tid >> 6, lane = tid & 63;
  const int wr = wave >> 1, wc = wave & 1;
  const int col_l = lane & 15, kg = lane >> 4;
  const int iy0 = 2*oy - 1;
  f32x4 acc[2][2] = {};
  unsigned short* sAf = &sA[0][0][0][0];
  const unsigned short* bsrc = w2 + (long)cog*16*24576;

  int aOff[6], aLdsO[6]; bool aOk[6];
  #pragma unroll
  for (int j = 0; j < 6; ++j) {
    int idx = tid + j*256;
    int px = idx & 127, rr = (idx >> 7) & 3, pl = idx >> 9;
    int iy = iy0 + rr;
    aOk[j] = (iy >= 0 && iy < 128);
    aOff[j] = (int)(pl*PS1 + (long)(b*128 + (aOk[j]?iy:0))*16384 + px*8);
    aLdsO[j] = ((pl*4 + rr)*130 + px + 1)*8;
  }
  uint4 pA[6];
  #pragma unroll
  for (int j=0;j<6;j++)  pA[j] = aOk[j] ? *(const uint4*)(h1 + aOff[j]) : zero4();

  if (tid < 24) {
    int pl = tid>>3, rr=(tid>>1)&3, c=tid&1;
    *(uint4*)&sA[pl][rr][c?129:0][0] = zero4();
  }

  for (int ch = 0; ch < 16; ++ch) {
    __syncthreads();
    #pragma unroll
    for (int j=0;j<6;j++)  *(uint4*)(sAf + aLdsO[j]) = pA[j];
    #pragma unroll
    for (int j = 0; j < 12; ++j) {
      int blk = wave*12 + j;
      gload_lds16(bsrc + (long)ch*24576 + blk*512 + lane*8, &sB[blk*512]);
    }
    if (ch < 15) {
      #pragma unroll
      for (int j=0;j<6;j++)  pA[j] = aOk[j] ? *(const uint4*)(h1 + aOff[j] + (ch+1)*1024) : zero4();
    }
    __syncthreads();
    #pragma unroll
    for (int s = 0; s < 4; ++s) {        // s = ky
      bf16x8 aF[2][3]; bf16x8 bF[2][3];
      const int tap = s*4 + kg;
      #pragma unroll
      for (int mf = 0; mf < 2; ++mf) {
        int ox = wr*32 + mf*16 + col_l;
        #pragma unroll
        for (int pl = 0; pl < 3; ++pl)
          aF[mf][pl] = *(const bf16x8*)&sA[pl][s][2*ox + kg][0];
      }
      #pragma unroll
      for (int nf = 0; nf < 2; ++nf) {
        int co = wc*32 + nf*16 + col_l;
        int ba = (co*16 + (tap ^ (co&15)))*8;
        bF[nf][0] = *(const bf16x8*)&sB[ba];
        bF[nf][1] = *(const bf16x8*)&sB[ba + 8192];
        bF[nf][2] = *(const bf16x8*)&sB[ba + 16384];
      }
      __builtin_amdgcn_s_setprio(1);
      #pragma unroll
      for (int mf = 0; mf < 2; ++mf)
      #pragma unroll
      for (int nf = 0; nf < 2; ++nf) {
        f32x4 a = acc[mf][nf];
        a = MFMA16(aF[mf][0], bF[nf][0], a);
        a = MFMA16(aF[mf][0], bF[nf][1], a);
        a = MFMA16(aF[mf][1], bF[nf][0], a);
        a = MFMA16(aF[mf][0], bF[nf][2], a);
        a = MFMA16(aF[mf][2], bF[nf][0], a);
        a = MFMA16(aF[mf][1], bF[nf][1], a);
        acc[mf][nf] = a;
      }
      __builtin_amdgcn_s_setprio(0);
    }
  }
  __syncthreads();
  #pragma unroll
  for (int nf = 0; nf < 2; ++nf) {
    int co = wc*32 + nf*16 + col_l;
    float bv = bias[cog*64 + co];
    #pragma unroll
    for (int mf = 0; mf < 2; ++mf) {
      int px0 = wr*32 + mf*16 + kg*4;
      u16x4 oh, om, ol;
      #pragma unroll
      for (int r = 0; r < 4; ++r) {
        float v = fmaxf(acc[mf][nf][r] + bv, 0.f);
        unsigned short h,m,l; split3(v,h,m,l);
        oh[r]=h; om[r]=m; ol[r]=l;
      }
      *(u16x4*)&sB[(0*64 + co)*72 + px0] = oh;
      *(u16x4*)&sB[(1*64 + co)*72 + px0] = om;
      *(u16x4*)&sB[(2*64 + co)*72 + px0] = ol;
    }
  }
  __syncthreads();
  #pragma unroll
  for (int j = 0; j < 6; ++j) {
    int idx = tid + j*256;
    int pl = idx >> 9, co_l = (idx >> 3) & 63, q = idx & 7;
    uint4 v = *(const uint4*)&sB[(pl*64 + co_l)*72 + q*8];
    *(uint4*)(h2 + (long)pl*PS2 + ((long)(b*128 + cog*64 + co_l)*64 + oy)*64 + q*8) = v;
  }
}

// ---------------- conv3: MFMA 6-term split; B via global_load_lds; coalesced epilogue -----
__global__ __launch_bounds__(256, 2) void conv3_mfma(
    const unsigned short* __restrict__ h2, long PS2,
    const unsigned short* __restrict__ w2,   // LDS-image: [ch][24576 shorts]
    const float* __restrict__ bias,
    unsigned short* __restrict__ zeH, unsigned short* __restrict__ zeM,
    unsigned short* __restrict__ zeL) {
  __shared__ __align__(16) unsigned short sA[3*67*24];
  __shared__ __align__(16) unsigned short sB[24576];
  const int tid = threadIdx.x;
  const int oy = blockIdx.x, b = blockIdx.z;
  const int wave = tid >> 6, lane = tid & 63;
  const int wr = wave >> 1, wc = wave & 1;
  const int col_l = lane & 15, kg = lane >> 4;
  f32x4 acc[2][2] = {};
  for (int i = tid; i < 3*3*24; i += 256) {
    int j = i % 24, c = (i/24) % 3, rr = i/72;
    int col = (c==0) ? 0 : (c==1 ? 65 : 66);
    sA[(rr*67 + col)*24 + j] = 0;
  }
  const int li = tid & 7, rrA = (tid>>3)%3, ciA = tid/24;
  const int iyA = oy + rrA - 1;
  const bool aAct = (tid < 192);
  const bool aOk = aAct && (iyA >= 0 && iyA < 64);
  const long aBase = ((long)(b*128 + ciA)*64 + (aOk?iyA:0))*64 + li*8;
  uint4 ph, pm, pl4;
  ph = aOk ? *(const uint4*)(h2 + aBase) : zero4();
  pm = aOk ? *(const uint4*)(h2 + PS2 + aBase) : zero4();
  pl4 = aOk ? *(const uint4*)(h2 + 2*PS2 + aBase) : zero4();

  for (int ch = 0; ch < 16; ++ch) {
    __syncthreads();
    if (aAct) {
      const unsigned short* vh = (const unsigned short*)&ph;
      const unsigned short* vm = (const unsigned short*)&pm;
      const unsigned short* vl = (const unsigned short*)&pl4;
      #pragma unroll
      for (int p = 0; p < 8; ++p) {
        int pp = (p + li) & 7;
        int col = li*8 + pp + 1;
        int base = (rrA*67 + col)*24 + ciA;
        sA[base]      = vh[pp];
        sA[base + 8]  = vm[pp];
        sA[base + 16] = vl[pp];
      }
    }
    #pragma unroll
    for (int j = 0; j < 12; ++j) {
      int blk = wave*12 + j;
      gload_lds16(w2 + (long)ch*24576 + blk*512 + lane*8, &sB[blk*512]);
    }
    if (ch < 15) {
      long nb = aBase + (long)(ch+1)*32768;
      ph = aOk ? *(const uint4*)(h2 + nb) : zero4();
      pm = aOk ? *(const uint4*)(h2 + PS2 + nb) : zero4();
      pl4 = aOk ? *(const uint4*)(h2 + 2*PS2 + nb) : zero4();
    }
    __syncthreads();
    #pragma unroll
    for (int s = 0; s < 3; ++s) {
      bf16x8 aF[2][3]; bf16x8 bF[2][3];
      const int tap = s*4 + kg;
      #pragma unroll
      for (int mf = 0; mf < 2; ++mf) {
        int ox = wr*32 + mf*16 + col_l;
        int base = (s*67 + ox + kg)*24;
        aF[mf][0] = *(const bf16x8*)&sA[base];
        aF[mf][1] = *(const bf16x8*)&sA[base+8];
        aF[mf][2] = *(const bf16x8*)&sA[base+16];
      }
      #pragma unroll
      for (int nf = 0; nf < 2; ++nf) {
        int co = wc*32 + nf*16 + col_l;
        int ba = (co*16 + (tap ^ (co&15)))*8;
        bF[nf][0] = *(const bf16x8*)&sB[ba];
        bF[nf][1] = *(const bf16x8*)&sB[ba + 8192];
        bF[nf][2] = *(const bf16x8*)&sB[ba + 16384];
      }
      __builtin_amdgcn_s_setprio(1);
      #pragma unroll
      for (int mf = 0; mf < 2; ++mf)
      #pragma unroll
      for (int nf = 0; nf < 2; ++nf) {
        f32x4 a = acc[mf][nf];
        a = MFMA16(aF[mf][0], bF[nf][0], a);
        a = MFMA16(aF[mf][0], bF[nf][1], a);
        a = MFMA16(aF[mf][1], bF[nf][0], a);
        a = MFMA16(aF[mf][0], bF[nf][2], a);
        a = MFMA16(aF[mf][2], bF[nf][0], a);
        a = MFMA16(aF[mf][1], bF[nf][1], a);
        acc[mf][nf] = a;
      }
      __builtin_amdgcn_s_setprio(0);
    }
  }
  __syncthreads();
  #pragma unroll
  for (int nf = 0; nf < 2; ++nf) {
    int co = wc*32 + nf*16 + col_l;
    float bv = bias[co];
    #pragma unroll
    for (int mf = 0; mf < 2; ++mf) {
      int px0 = wr*32 + mf*16 + kg*4;
      u16x4 oh, om, ol;
      #pragma unroll
      for (int r = 0; r < 4; ++r) {
        float v = acc[mf][nf][r] + bv;
        unsigned short h,m,l; split3(v,h,m,l);
        oh[r]=h; om[r]=m; ol[r]=l;
      }
      *(u16x4*)&sB[(0*64 + co)*72 + px0] = oh;
      *(u16x4*)&sB[(1*64 + co)*72 + px0] = om;
      *(u16x4*)&sB[(2*64 + co)*72 + px0] = ol;
    }
  }
  __syncthreads();
  #pragma unroll
  for (int j = 0; j < 6; ++j) {
    int idx = tid + j*256;
    int pl = idx >> 9, co_l = (idx >> 3) & 63, q = idx & 7;
    uint4 v = *(const uint4*)&sB[(pl*64 + co_l)*72 + q*8];
    unsigned short* dst = (pl==0) ? zeH : ((pl==1) ? zeM : zeL);
    *(uint4*)(dst + ((long)(b*64 + co_l)*64 + oy)*64 + q*8) = v;
  }
}

// ---------------- MFMA ConvTranspose2d s2k4p1; W via global_load_lds (pre-swizzled image) --
template<int TX, int MODE>
struct SmemD {
  union {
    struct { __align__(16) unsigned short In[2][TX+2][24];
             __align__(16) unsigned short W[2*128*64]; } o;
    struct { __align__(16) unsigned short In[2][TX+2][16];
             __align__(16) unsigned short W[2*128*64]; } v;
    __align__(16) unsigned short Out[2*TX][136];
  };
};

template<int CIN, int TX, int MODE>
__global__ __launch_bounds__(TX*4, (TX==64)?3:4) void deconv_mfma(
    const void* __restrict__ xin, const unsigned short* __restrict__ w2,
    const float* __restrict__ bias, unsigned short* __restrict__ yI) {
  constexpr int NTHR = TX*4;
  constexpr int NWAVE = NTHR/64;
  constexpr int NWG  = 32/NWAVE;       // 16384-short W image: 32 wave-loads of 512 shorts
  __shared__ SmemD<TX,MODE> sm;
  unsigned short* Wb = MODE ? &sm.v.W[0] : &sm.o.W[0];

  const int tid = threadIdx.x;
  const int ty = blockIdx.x, e = blockIdx.y, b = blockIdx.z;
  const int wave = tid >> 6, lane = tid & 63;
  const int wc = wave & 1, wr = wave >> 1;
  const int f = (wr*64) / TX;
  const int tx_base = (wr*64) & (TX-1);
  const int col_l = lane & 15, kg = lane >> 4;
  const unsigned short* wsrc = w2 + (long)e*(CIN/16)*16384;

  // A prefetch descriptors
  constexpr int TPR = NTHR/32;
  const int rowid = tid / TPR, liO = tid % TPR;
  const int sci = rowid >> 1, srr = rowid & 1;
  float4 pLo, pHi; uint4 pIn;
  long aBase = 0; bool aOk = false;
  int pxV = 0, halfV = 0, rrV = 0;
  if (MODE == 0) {
    int iy = ty + e - 1 + srr;
    aOk = (iy >= 0 && iy < TX);
    aBase = ((long)b*CIN + sci)*TX*TX + (long)(aOk?iy:0)*TX + liO*8;
    if (aOk) { const float4* s4 = (const float4*)((const float*)xin + aBase);
               pLo = s4[0]; pHi = s4[1]; }
  } else {
    halfV = tid & 1; pxV = (tid >> 1) & (TX-1); rrV = tid >> 8;
    int iy = ty + e - 1 + rrV;
    aOk = (iy >= 0 && iy < TX);
    aBase = ((long)b*TX + (aOk?iy:0))*((long)(CIN/8)*TX*8) + (long)halfV*TX*8 + pxV*8;
    pIn = aOk ? *(const uint4*)((const unsigned short*)xin + aBase) : zero4();
  }

  if (MODE == 0) {
    if (tid < 64) {
      int rr = tid & 1, cc = ((tid>>1)&1) ? TX+1 : 0, ci = tid >> 2;
      sm.o.In[rr][cc][ci] = 0;
    }
  } else {
    if (tid < 8) {
      int rr = tid & 1, c = (tid>>1)&1, hf = (tid>>2)&1;
      *(uint4*)&sm.v.In[rr][c?TX+1:0][hf*8] = zero4();
    }
  }

  f32x4 acc[4][4] = {};
  for (int ch = 0; ch < CIN/16; ++ch) {
    __syncthreads();
    if (MODE == 0) {
      unsigned short vals[8];
      if (aOk) {
        float4 lo = pLo, hi = pHi;
        vals[0]=bfbits(lo.x); vals[1]=bfbits(lo.y); vals[2]=bfbits(lo.z); vals[3]=bfbits(lo.w);
        vals[4]=bfbits(hi.x); vals[5]=bfbits(hi.y); vals[6]=bfbits(hi.z); vals[7]=bfbits(hi.w);
      } else {
        #pragma unroll
        for (int j=0;j<8;j++) vals[j] = 0;
      }
      #pragma unroll
      for (int j=0;j<8;j++) {
        int jj = (j + liO) & 7;
        sm.o.In[srr][1 + liO*8 + jj][sci] = vals[jj];
      }
    } else {
      *(uint4*)&sm.v.In[rrV][pxV+1][halfV*8] = pIn;
    }
    // W: 32KB via global_load_lds, linear dest (image pre-swizzled)
    #pragma unroll
    for (int j = 0; j < NWG; ++j) {
      int blk = wave*NWG + j;
      gload_lds16(wsrc + (long)ch*16384 + blk*512 + lane*8, Wb + blk*512);
    }
    if (ch + 1 < CIN/16) {
      if (MODE == 0) {
        if (aOk) { const float4* s4 = (const float4*)((const float*)xin + aBase + (long)(ch+1)*16*TX*TX);
                   pLo = s4[0]; pHi = s4[1]; }
      } else {
        pIn = aOk ? *(const uint4*)((const unsigned short*)xin + aBase + (ch+1)*2*TX*8) : zero4();
      }
    }
    __syncthreads();
    #pragma unroll
    for (int kk = 0; kk < 2; ++kk) {
      bf16x8 aF[4];
      const int tap = kk*2 + (kg >> 1), a = tap >> 1, bb = tap & 1;
      #pragma unroll
      for (int mf = 0; mf < 4; ++mf) {
        int tx = tx_base + mf*16 + col_l;
        if (MODE == 0) aF[mf] = *(const bf16x8*)&sm.o.In[1-a][tx + 1 + f - bb][(kg&1)*8];
        else           aF[mf] = *(const bf16x8*)&sm.v.In[1-a][tx + 1 + f - bb][(kg&1)*8];
      }
      const int slot = kk*4 + kg;
      __builtin_amdgcn_s_setprio(1);
      #pragma unroll
      for (int nf = 0; nf < 4; ++nf) {
        int co_l = nf*16 + col_l;
        bf16x8 bF = *(const bf16x8*)(Wb + (f*128 + wc*64 + co_l)*64 + (slot ^ (co_l & 7))*8);
        #pragma unroll
        for (int mf = 0; mf < 4; ++mf)
          acc[mf][nf] = MFMA16(aF[mf], bF, acc[mf][nf]);
      }
      __builtin_amdgcn_s_setprio(0);
    }
  }

  __syncthreads();
  float bv[4];
  #pragma unroll
  for (int nf = 0; nf < 4; ++nf) bv[nf] = bias[wc*64 + nf*16 + col_l];
  #pragma unroll
  for (int mf = 0; mf < 4; ++mf)
  #pragma unroll
  for (int nf = 0; nf < 4; ++nf) {
    int co = wc*64 + nf*16 + col_l;
    #pragma unroll
    for (int r = 0; r < 4; ++r) {
      int tx = tx_base + mf*16 + kg*4 + r;
      float v = fmaxf(acc[mf][nf][r] + bv[nf], 0.f);
      int ox = 2*tx + f;
      sm.Out[ox][co ^ (((ox>>3)&7)<<3)] = bfbits(v);
    }
  }
  __syncthreads();
  const int oy = 2*ty + e;
  #pragma unroll
  for (int j = 0; j < 8; ++j) {
    int i = tid + j*NTHR;
    int px = i & (2*TX-1), chn = i / (2*TX);
    uint4 vv = *(const uint4*)&sm.Out[px][(chn*8) ^ (((px>>3)&7)<<3)];
    *(uint4*)(yI + ((((long)b*(2*TX) + oy)*16 + chn)*(2*TX) + px)*8) = vv;
  }
}

// ---------------- deconv3: MFMA + sigmoid (unchanged) ----------
__global__ __launch_bounds__(256, 2) void deconv3_mfma(
    const unsigned short* __restrict__ g2I,
    const unsigned short* __restrict__ w2,
    const float* __restrict__ bias, float* __restrict__ y) {
  __shared__ __align__(16) unsigned short sA[3][260][8];
  __shared__ __align__(16) unsigned short sB[16*12*16*8];
  const int tid = threadIdx.x;
  const int oy = blockIdx.x, b = blockIdx.y;
  const int wave = tid >> 6, lane = tid & 63;
  const int col_l = lane & 15, kg = lane >> 4;
  const int pxb = wave*64;
  for (int i = tid; i < 3072; i += 256) {
    int co = i & 15, tap = (i>>4) % 12, ch = i/192;
    *(uint4*)&sB[((ch*12+tap)*16+co)*8] = *(const uint4*)(w2 + (long)co*1536 + ch*96 + tap*8);
  }
  if (tid < 12) {
    int dy = tid >> 2, c = tid & 3;
    *(uint4*)&sA[dy][(c<2)?c:(256+c)][0] = zero4();
  }
  long aBase[3]; int aLdsO[3]; bool aOk[3];
  #pragma unroll
  for (int u = 0; u < 3; ++u) {
    int idx = tid + u*256;
    int px = idx & 255, dy = idx >> 8;
    int iy = oy - 1 + dy;
    aOk[u] = (iy >= 0 && iy < 256);
    aBase[u] = ((long)(b*256 + (aOk[u]?iy:0)))*32768 + px*8;
    aLdsO[u] = (dy*260 + px + 2)*8;
  }
  uint4 pA[3];
  #pragma unroll
  for (int u=0;u<3;u++) pA[u] = aOk[u] ? *(const uint4*)(g2I + aBase[u]) : zero4();

  unsigned short* sAf = &sA[0][0][0];
  f32x4 acc[4] = {};
  for (int ch = 0; ch < 16; ++ch) {
    __syncthreads();
    #pragma unroll
    for (int u=0;u<3;u++) *(uint4*)(sAf + aLdsO[u]) = pA[u];
    if (ch < 15) {
      #pragma unroll
      for (int u=0;u<3;u++)
        pA[u] = aOk[u] ? *(const uint4*)(g2I + aBase[u] + (ch+1)*2048) : zero4();
    }
    __syncthreads();
    #pragma unroll
    for (int s = 0; s < 3; ++s) {
      bf16x8 bF = *(const bf16x8*)&sB[((ch*12 + s*4 + kg)*16 + col_l)*8];
      __builtin_amdgcn_s_setprio(1);
      #pragma unroll
      for (int mf = 0; mf < 4; ++mf) {
        int px = pxb + mf*16 + col_l;
        bf16x8 aF = *(const bf16x8*)&sA[2-s][px + 3 - kg][0];
        acc[mf] = MFMA16(aF, bF, acc[mf]);
      }
      __builtin_amdgcn_s_setprio(0);
    }
  }
  if (col_l < 3) {
    float bv = bias[col_l];
    #pragma unroll
    for (int mf = 0; mf < 4; ++mf) {
      int px = pxb + mf*16 + kg*4;
      float4 o;
      o.x = 1.f/(1.f + expf(-(acc[mf][0] + bv)));
      o.y = 1.f/(1.f + expf(-(acc[mf][1] + bv)));
      o.z = 1.f/(1.f + expf(-(acc[mf][2] + bv)));
      o.w = 1.f/(1.f + expf(-(acc[mf][3] + bv)));
      *(float4*)(y + ((long)(b*3 + col_l)*256 + oy)*256 + px) = o;
    }
  }
}

// ---------------- VQ via MFMA (unchanged) ----------------
__global__ __launch_bounds__(256, 2) void vq_mfma(
    const unsigned short* __restrict__ zeH, const unsigned short* __restrict__ zeM,
    const unsigned short* __restrict__ zeL,
    const float* __restrict__ emb, const float* __restrict__ esq,
    float* __restrict__ out_idx, float* __restrict__ zq) {
  __shared__ __align__(16) unsigned short sA[64*3*8*8];
  __shared__ __align__(16) unsigned short sB[128*3*8*8];
  __shared__ float snb[128];
  __shared__ int sidx[64];
  const int tid = threadIdx.x;
  const long n0 = (long)blockIdx.x*64;
  const int wave = tid >> 6, lane = tid & 63;
  const int col = lane & 15, kg = lane >> 4;

  #pragma unroll
  for (int j = 0; j < 6; ++j) {
    int idx = tid + j*256;
    int pl = idx >> 9, rem = idx & 511;
    int n = rem >> 3, slot = rem & 7;
    const unsigned short* src = (pl==0 ? zeH : (pl==1 ? zeM : zeL)) + (n0+n)*64 + slot*8;
    *(uint4*)&sA[((n*3 + pl)*8 + (slot ^ (n&7)))*8] = *(const uint4*)src;
  }

  const int codeT = tid >> 1, halfT = tid & 1;
  float4 pB[8];
  #pragma unroll
  for (int q = 0; q < 8; ++q)
    pB[q] = *(const float4*)(emb + (long)codeT*64 + halfT*32 + q*4);
  float pSn = (tid < 128) ? esq[tid] : 0.f;

  float best[4] = {3.4e38f,3.4e38f,3.4e38f,3.4e38f};
  int bidx[4] = {0,0,0,0};

  for (int ch = 0; ch < 4; ++ch) {
    __syncthreads();
    #pragma unroll
    for (int s4 = 0; s4 < 4; ++s4) {
      int slot = halfT*4 + s4;
      float4 lo = pB[s4*2], hi = pB[s4*2+1];
      unsigned short th[8], tm[8], tl[8];
      split3(lo.x, th[0], tm[0], tl[0]); split3(lo.y, th[1], tm[1], tl[1]);
      split3(lo.z, th[2], tm[2], tl[2]); split3(lo.w, th[3], tm[3], tl[3]);
      split3(hi.x, th[4], tm[4], tl[4]); split3(hi.y, th[5], tm[5], tl[5]);
      split3(hi.z, th[6], tm[6], tl[6]); split3(hi.w, th[7], tm[7], tl[7]);
      int base = ((codeT*3)*8 + (slot ^ (codeT&7)))*8;
      *(uint4*)&sB[base]       = *(uint4*)th;
      *(uint4*)&sB[base + 64]  = *(uint4*)tm;
      *(uint4*)&sB[base + 128] = *(uint4*)tl;
    }
    if (tid < 128) snb[tid] = pSn;
    if (ch < 3) {
      #pragma unroll
      for (int q = 0; q < 8; ++q)
        pB[q] = *(const float4*)(emb + ((long)(ch+1)*128 + codeT)*64 + halfT*32 + q*4);
      if (tid < 128) pSn = esq[(ch+1)*128 + tid];
    }
    __syncthreads();

    f32x4 acc[8] = {};
    #pragma unroll
    for (int kk = 0; kk < 2; ++kk) {
      const int nloc = wave*16 + col;
      const int slot = kk*4 + kg;
      bf16x8 aF[3];
      #pragma unroll
      for (int pl = 0; pl < 3; ++pl)
        aF[pl] = *(const bf16x8*)&sA[((nloc*3 + pl)*8 + (slot ^ (nloc&7)))*8];
      __builtin_amdgcn_s_setprio(1);
      #pragma unroll
      for (int cf = 0; cf < 8; ++cf) {
        int cl = cf*16 + col;
        int bb = ((cl*3)*8 + (slot ^ (cl&7)))*8;
        bf16x8 b0 = *(const bf16x8*)&sB[bb];
        bf16x8 b1 = *(const bf16x8*)&sB[bb + 64];
        bf16x8 b2 = *(const bf16x8*)&sB[bb + 128];
        f32x4 a = acc[cf];
        a = MFMA16(aF[0], b0, a);
        a = MFMA16(aF[0], b1, a);
        a = MFMA16(aF[1], b0, a);
        a = MFMA16(aF[0], b2, a);
        a = MFMA16(aF[2], b0, a);
        a = MFMA16(aF[1], b1, a);
        acc[cf] = a;
      }
      __builtin_amdgcn_s_setprio(0);
    }
    #pragma unroll
    for (int cf = 0; cf < 8; ++cf) {
      float sv = snb[cf*16 + col];
      int code = ch*128 + cf*16 + col;
      #pragma unroll
      for (int j = 0; j < 4; ++j) {
        float s = sv - 2.f*acc[cf][j];
        if (s < best[j]) { best[j] = s; bidx[j] = code; }
      }
    }
  }

  #pragma unroll
  for (int j = 0; j < 4; ++j) {
    float b = best[j]; int ii = bidx[j];
    #pragma unroll
    for (int off = 1; off < 16; off <<= 1) {
      float ob = __shfl_xor(b, off);
      int oi = __shfl_xor(ii, off);
      if (ob < b || (ob == b && oi < ii)) { b = ob; ii = oi; }
    }
    if (col == 0) sidx[wave*16 + kg*4 + j] = ii;
  }
  __syncthreads();
  if (tid < 64) out_idx[n0 + tid] = (float)sidx[tid];
  #pragma unroll
  for (int j = 0; j < 4; ++j) {
    int t = tid + j*256;
    int row = t >> 4, q = t & 15;
    float4 v = *(const float4*)(emb + (long)sidx[row]*64 + q*4);
    *(float4*)(zq + (n0 + row)*64 + q*4) = v;
  }
}

// ---------------- launch ----------------
extern "C" void kernel_launch(void* const* d_in, const int* in_sizes, int n_in,
                              void* d_out, int out_size, void* d_ws, size_t ws_size,
                              hipStream_t stream) {
  const float* x   = (const float*)d_in[0];
  const float* c1w = (const float*)d_in[1];  const float* c1b = (const float*)d_in[2];
  const float* c2w = (const float*)d_in[3];  const float* c2b = (const float*)d_in[4];
  const float* c3w = (const float*)d_in[5];  const float* c3b = (const float*)d_in[6];
  const float* emb = (const float*)d_in[7];
  const float* d1w = (const float*)d_in[8];  const float* d1b = (const float*)d_in[9];
  const float* d2w = (const float*)d_in[10]; const float* d2b = (const float*)d_in[11];
  const float* d3w = (const float*)d_in[12]; const float* d3b = (const float*)d_in[13];
  float* out = (float*)d_out;

  float* xrec = out;
  float* oidx = out + 3145728;
  float* zq   = out + 3211264;

  const long XB  = 196608;   // 3*256*256
  const long ZEB = 262144;   // ze elems per batch
  const long PS1 = 8388608;  // per-plane h1 (interleaved) in shorts
  const long PS2 = 4194304;  // per-plane h2 in shorts

  const size_t NEEDED = 112273408ULL;  // known: ws_size >= 120,395,264
  if (ws_size < NEEDED) return;
  char* wsb = (char*)d_ws;
  unsigned short* h1grp = (unsigned short*)wsb;              // interleaved, 50.3MB
  unsigned short* g2grp = (unsigned short*)wsb;              // interleaved, 64MB
  unsigned short* h2grp = (unsigned short*)(wsb + 67108864); // planar 3-plane, 24MB
  unsigned short* g1grp = (unsigned short*)(wsb + 67108864); // interleaved, 16MB
  unsigned short* zeH = (unsigned short*)(wsb + 92274688);
  unsigned short* zeM = (unsigned short*)(wsb + 100663296);
  unsigned short* zeL = (unsigned short*)out;                // xrec region: dead until deconv3
  char* W = wsb + 109051904;
  float* w2c1          = (float*)(W);                        // 24,576 B
  unsigned short* w2c2 = (unsigned short*)(W + 24576);       // LDS-image, 1,572,864 B
  unsigned short* w2c3 = (unsigned short*)(W + 1597440);     // LDS-image, 786,432 B
  unsigned short* w2d1 = (unsigned short*)(W + 2383872);     // image, 262,144 B
  unsigned short* w2d2 = (unsigned short*)(W + 2646016);     // image, 524,288 B
  unsigned short* w2d3 = (unsigned short*)(W + 3170304);     // 49,152 B
  float* esq           = (float*)(W + 3219456);              // 2,048 B

  wprep_all<<<3066, 256, 0, stream>>>(c1w, w2c1, c2w, w2c2, c3w, w2c3,
                                      d1w, w2d1, d2w, w2d2, d3w, w2d3, emb, esq);

  // encoder
  for (int g = 0; g < 4; ++g) {
    conv1_split<<<dim3(16,16,8), 256, 0, stream>>>(
        x + (long)g*4*XB, w2c1, c1b, h1grp, PS1);
    conv2_mfma<<<dim3(64,2,4), 256, 0, stream>>>(
        h1grp, PS1, w2c2, c2b, h2grp + (long)(g&1)*4*524288, PS2);
    if (g & 1) {
      long zo = (long)(g>>1)*8*ZEB;
      conv3_mfma<<<dim3(64,1,8), 256, 0, stream>>>(
          h2grp, PS2, w2c3, c3b, zeH + zo, zeM + zo, zeL + zo);
    }
  }
  vq_mfma<<<1024, 256, 0, stream>>>(zeH, zeM, zeL, emb, esq, oidx, zq);

  // decoder
  for (int g = 0; g < 4; ++g) {
    deconv_mfma<64, 64, 0 ><<<dim3(64, 2, 4), 256, 0, stream>>>(
        (const void*)(zq + (long)g*4*ZEB), w2d1, d1b, g1grp);
    deconv_mfma<128,128,1 ><<<dim3(128,2,4), 512, 0, stream>>>(
        (const void*)g1grp, w2d2, d2b, g2grp);
    deconv3_mfma<<<dim3(256,4), 256, 0, stream>>>(
        g2grp, w2d3, d3b, xrec + (long)g*4*XB);
  }
}

// Round 12
// 746.236 us; speedup vs baseline: 8.0123x; 1.1106x over previous
//
#include <hip/hip_runtime.h>
#include <hip/hip_bf16.h>

#define DEV __device__ __forceinline__

typedef __attribute__((ext_vector_type(8))) short bf16x8;
typedef __attribute__((ext_vector_type(4))) float f32x4;
typedef __attribute__((ext_vector_type(4))) unsigned short u16x4;

#define MFMA16(a,b,c) __builtin_amdgcn_mfma_f32_16x16x32_bf16(a,b,c,0,0,0)

DEV unsigned short bfbits(float v){ __hip_bfloat16 h = __float2bfloat16(v); return *(unsigned short*)&h; }
DEV float bf2f(unsigned short u){ __hip_bfloat16 h = *(__hip_bfloat16*)&u; return __bfloat162float(h); }
DEV void split3(float v, unsigned short& h, unsigned short& m, unsigned short& l) {
  h = bfbits(v);        float r  = v - bf2f(h);
  m = bfbits(r);        float r2 = r - bf2f(m);
  l = bfbits(r2);
}
DEV uint4 zero4(){ uint4 z; z.x=0; z.y=0; z.z=0; z.w=0; return z; }
DEV void gload_lds16(const void* g, void* l) {
  __builtin_amdgcn_global_load_lds(
      (const __attribute__((address_space(1))) void*)g,
      (__attribute__((address_space(3))) void*)l, 16, 0, 0);
}

// ---------------- fused weight prep (one dispatch, 3066 blocks) ----------------
DEV void prep_deconv_img(int i, int CI, const float* __restrict__ w, unsigned short* __restrict__ w2) {
  const int nch = CI/16;
  int cil = i & 7, s = (i >> 3) & 7, co = (i >> 6) & 127, f = (i >> 13) & 1;
  int rest = i >> 14;
  int ch = rest % nch, e = rest / nch;
  int k = ch*64 + s*8 + cil;
  int ci = (k & 15) | ((k >> 6) << 4);
  int tap = (k >> 4) & 3, a = tap >> 1, b = tap & 1;
  float v = w[ (((long)ci*128 + co)*4 + (2*a+1-e))*4 + (2*b+1-f) ];
  w2[(long)(e*nch + ch)*16384 + ((long)(f*128 + co))*64 + ((s ^ (co&7))*8) + cil] = bfbits(v);
}
__global__ __launch_bounds__(256) void wprep_all(
    const float* __restrict__ c1w, float* __restrict__ w2c1,
    const float* __restrict__ c2w, unsigned short* __restrict__ w2c2,
    const float* __restrict__ c3w, unsigned short* __restrict__ w2c3,
    const float* __restrict__ d1w, unsigned short* __restrict__ w2d1,
    const float* __restrict__ d2w, unsigned short* __restrict__ w2d2,
    const float* __restrict__ d3w, unsigned short* __restrict__ w2d3,
    const float* __restrict__ emb, float* __restrict__ esq) {
  const int bx = blockIdx.x, t = threadIdx.x;
  if (bx < 24) {                         // conv1 transpose: 6144
    int i = bx*256 + t;
    if (i < 6144) {
      int tap = i & 15, ci = (i>>4) % 3, co = i / 48;
      w2c1[((long)ci*16 + tap)*128 + co] = c1w[i];
    }
  } else if (bx < 1048) {                // conv2 prep -> LDS-image layout
    int i = (bx-24)*256 + t;             // 0..262143
    int cil = i & 7, s = (i>>3) & 15, co = (i>>7) & 63;
    int ch = (i>>13) & 15, cog = i >> 17;
    int co_g = cog*64 + co, ci = ch*8 + cil, ky = s >> 2, kx = s & 3;
    float v = c2w[(((long)co_g*128 + ci)*4 + ky)*4 + kx];
    unsigned short h,m,l; split3(v,h,m,l);
    long base = (long)(cog*16 + ch)*24576 + ((long)co*16 + (s ^ (co&15)))*8 + cil;
    w2c2[base] = h; w2c2[base + 8192] = m; w2c2[base + 16384] = l;
  } else if (bx < 1432) {                // conv3 prep -> LDS-image layout: 98304
    int i = (bx-1048)*256 + t;
    int k = i % 1536, co = i / 1536;
    int ch = k / 96, rem = k % 96;
    int tap = rem >> 3, cil = rem & 7;
    int ci = ch*8 + cil, ky = tap >> 2, kx = tap & 3;
    float v = (kx < 3) ? c3w[(((long)co*128 + ci)*3 + ky)*3 + kx] : 0.f;
    unsigned short h,m,l; split3(v,h,m,l);
    long base = (long)ch*24576 + ((long)co*16 + (tap ^ (co&15)))*8 + cil;
    w2c3[base] = h; w2c3[base + 8192] = m; w2c3[base + 16384] = l;
  } else if (bx < 1944) {                // deconv1 image: 131072 (CI=64)
    prep_deconv_img((bx-1432)*256 + t, 64, d1w, w2d1);
  } else if (bx < 2968) {                // deconv2 image: 262144 (CI=128)
    prep_deconv_img((bx-1944)*256 + t, 128, d2w, w2d2);
  } else if (bx < 3064) {                // deconv3: 24576
    int i = (bx-2968)*256 + t;
    if (i < 24576) {
      int k = i % 1536, co = i / 1536;
      int ch = k / 96, rem = k % 96;
      int tap = rem >> 3, cil = rem & 7;
      int ci = ch*8 + cil, ky = tap >> 2, kx = tap & 3;
      float v = (co < 3 && kx < 3) ? d3w[(((long)ci*3 + co)*3 + ky)*3 + kx] : 0.f;
      w2d3[i] = bfbits(v);
    }
  } else {                               // esq: 512 codes
    int code = (bx-3064)*256 + t;
    if (code < 512) {
      const float4* ev = (const float4*)(emb + (long)code*64);
      float s = 0.f;
      #pragma unroll
      for (int q=0;q<16;q++){ float4 e4 = ev[q];
        s += e4.x*e4.x + e4.y*e4.y + e4.z*e4.z + e4.w*e4.w; }
      esq[code] = s;
    }
  }
}

// ---------------- conv1: f32 direct, out 3 bf16 planes INTERLEAVED ----------------
__global__ __launch_bounds__(256) void conv1_split(
    const float* __restrict__ x, const float* __restrict__ w2,
    const float* __restrict__ bias, unsigned short* __restrict__ h1, long PS1) {
  __shared__ __align__(16) float sIn[3][18][20];
  __shared__ __align__(16) float sW[3*16*64];
  const int tid = threadIdx.x;
  const int b = blockIdx.z >> 1, cog = blockIdx.z & 1;
  const int co0 = cog*64;
  const int oy0 = blockIdx.y*8, ox0 = blockIdx.x*8;
  const int cg2 = tid >> 5;
  const int pg2 = tid & 31;
  const int r = pg2 >> 2, pxp = (pg2 & 3)*2;
  float acc[8][2];
  #pragma unroll
  for (int c=0;c<8;c++){ float bv = bias[co0 + cg2*8 + c];
    acc[c][0]=bv; acc[c][1]=bv; }
  const float* xb = x + (long)b*3*256*256;
  const int iy0 = 2*oy0 - 1, ix0 = 2*ox0 - 1;
  for (int t=tid; t<3*18*18; t+=256) {
    int xx = t%18, yy=(t/18)%18, ci=t/324;
    int gy = iy0+yy, gx = ix0+xx;
    float v = 0.f;
    if (gy>=0 && gy<256 && gx>=0 && gx<256) v = xb[((long)ci*256+gy)*256+gx];
    sIn[ci][yy][xx] = v;
  }
  for (int t=tid; t<3*16*64; t+=256) {
    sW[t] = w2[(long)(t>>6)*128 + co0 + (t&63)];
  }
  __syncthreads();
  for (int ci=0; ci<3; ci++) {
    #pragma unroll
    for (int ky=0;ky<4;ky++)
    #pragma unroll
    for (int kx=0;kx<4;kx++) {
      const float* wp = &sW[(ci*16 + ky*4+kx)*64 + cg2*8];
      float4 w0 = *(const float4*)wp;
      float4 w1 = *(const float4*)(wp+4);
      const int yy = 2*r + ky;
      #pragma unroll
      for (int p=0;p<2;p++) {
        float iv = sIn[ci][yy][2*(pxp+p)+kx];
        acc[0][p] += w0.x*iv; acc[1][p] += w0.y*iv;
        acc[2][p] += w0.z*iv; acc[3][p] += w0.w*iv;
        acc[4][p] += w1.x*iv; acc[5][p] += w1.y*iv;
        acc[6][p] += w1.z*iv; acc[7][p] += w1.w*iv;
      }
    }
  }
  const int chg = cog*8 + cg2;
  #pragma unroll
  for (int p=0;p<2;p++) {
    unsigned short th[8], tm[8], tl[8];
    #pragma unroll
    for (int c=0;c<8;c++) {
      float v = fmaxf(acc[c][p], 0.f);
      split3(v, th[c], tm[c], tl[c]);
    }
    long base = (((long)(b*128 + oy0+r)*16 + chg)*128 + ox0+pxp+p)*8;
    *(uint4*)(h1 + base)          = *(uint4*)th;
    *(uint4*)(h1 + PS1 + base)    = *(uint4*)tm;
    *(uint4*)(h1 + 2*PS1 + base)  = *(uint4*)tl;
  }
}

// ---------------- conv2: MFMA 6-term split; B via global_load_lds; interleaved h2 out -----
__global__ __launch_bounds__(256, 2) void conv2_mfma(
    const unsigned short* __restrict__ h1, long PS1,
    const unsigned short* __restrict__ w2,   // LDS-image: [cog][ch][24576 shorts]
    const float* __restrict__ bias,
    unsigned short* __restrict__ h2I) {      // [b][row64][pl3][ch16][px64][8]
  __shared__ __align__(16) unsigned short sA[3][4][130][8];
  __shared__ __align__(16) unsigned short sB[24576];
  const int tid = threadIdx.x;
  const int oy = blockIdx.x, cog = blockIdx.y, b = blockIdx.z;
  const int wave = tid >> 6, lane = tid & 63;
  const int wr = wave >> 1, wc = wave & 1;
  const int col_l = lane & 15, kg = lane >> 4;
  const int iy0 = 2*oy - 1;
  f32x4 acc[2][2] = {};
  unsigned short* sAf = &sA[0][0][0][0];
  const unsigned short* bsrc = w2 + (long)cog*16*24576;

  int aOff[6], aLdsO[6]; bool aOk[6];
  #pragma unroll
  for (int j = 0; j < 6; ++j) {
    int idx = tid + j*256;
    int px = idx & 127, rr = (idx >> 7) & 3, pl = idx >> 9;
    int iy = iy0 + rr;
    aOk[j] = (iy >= 0 && iy < 128);
    aOff[j] = (int)(pl*PS1 + (long)(b*128 + (aOk[j]?iy:0))*16384 + px*8);
    aLdsO[j] = ((pl*4 + rr)*130 + px + 1)*8;
  }
  uint4 pA[6];
  #pragma unroll
  for (int j=0;j<6;j++)  pA[j] = aOk[j] ? *(const uint4*)(h1 + aOff[j]) : zero4();

  if (tid < 24) {
    int pl = tid>>3, rr=(tid>>1)&3, c=tid&1;
    *(uint4*)&sA[pl][rr][c?129:0][0] = zero4();
  }

  for (int ch = 0; ch < 16; ++ch) {
    __syncthreads();
    #pragma unroll
    for (int j=0;j<6;j++)  *(uint4*)(sAf + aLdsO[j]) = pA[j];
    #pragma unroll
    for (int j = 0; j < 12; ++j) {
      int blk = wave*12 + j;
      gload_lds16(bsrc + (long)ch*24576 + blk*512 + lane*8, &sB[blk*512]);
    }
    if (ch < 15) {
      #pragma unroll
      for (int j=0;j<6;j++)  pA[j] = aOk[j] ? *(const uint4*)(h1 + aOff[j] + (ch+1)*1024) : zero4();
    }
    __syncthreads();
    #pragma unroll
    for (int s = 0; s < 4; ++s) {        // s = ky
      bf16x8 aF[2][3]; bf16x8 bF[2][3];
      const int tap = s*4 + kg;
      #pragma unroll
      for (int mf = 0; mf < 2; ++mf) {
        int ox = wr*32 + mf*16 + col_l;
        #pragma unroll
        for (int pl = 0; pl < 3; ++pl)
          aF[mf][pl] = *(const bf16x8*)&sA[pl][s][2*ox + kg][0];
      }
      #pragma unroll
      for (int nf = 0; nf < 2; ++nf) {
        int co = wc*32 + nf*16 + col_l;
        int ba = (co*16 + (tap ^ (co&15)))*8;
        bF[nf][0] = *(const bf16x8*)&sB[ba];
        bF[nf][1] = *(const bf16x8*)&sB[ba + 8192];
        bF[nf][2] = *(const bf16x8*)&sB[ba + 16384];
      }
      __builtin_amdgcn_s_setprio(1);
      #pragma unroll
      for (int mf = 0; mf < 2; ++mf)
      #pragma unroll
      for (int nf = 0; nf < 2; ++nf) {
        f32x4 a = acc[mf][nf];
        a = MFMA16(aF[mf][0], bF[nf][0], a);
        a = MFMA16(aF[mf][0], bF[nf][1], a);
        a = MFMA16(aF[mf][1], bF[nf][0], a);
        a = MFMA16(aF[mf][0], bF[nf][2], a);
        a = MFMA16(aF[mf][2], bF[nf][0], a);
        a = MFMA16(aF[mf][1], bF[nf][1], a);
        acc[mf][nf] = a;
      }
      __builtin_amdgcn_s_setprio(0);
    }
  }
  // epilogue: acc -> sB[pl][co64][72pad] -> interleaved h2I
  __syncthreads();
  #pragma unroll
  for (int nf = 0; nf < 2; ++nf) {
    int co = wc*32 + nf*16 + col_l;
    float bv = bias[cog*64 + co];
    #pragma unroll
    for (int mf = 0; mf < 2; ++mf) {
      int px0 = wr*32 + mf*16 + kg*4;
      u16x4 oh, om, ol;
      #pragma unroll
      for (int r = 0; r < 4; ++r) {
        float v = fmaxf(acc[mf][nf][r] + bv, 0.f);
        unsigned short h,m,l; split3(v,h,m,l);
        oh[r]=h; om[r]=m; ol[r]=l;
      }
      *(u16x4*)&sB[(0*64 + co)*72 + px0] = oh;
      *(u16x4*)&sB[(1*64 + co)*72 + px0] = om;
      *(u16x4*)&sB[(2*64 + co)*72 + px0] = ol;
    }
  }
  __syncthreads();
  #pragma unroll
  for (int j = 0; j < 6; ++j) {
    int idx = tid + j*256;
    int pl = idx >> 9, ch = (idx >> 6) & 7, px = idx & 63;
    unsigned short tmp[8];
    #pragma unroll
    for (int c = 0; c < 8; ++c) tmp[c] = sB[(pl*64 + ch*8 + c)*72 + px];
    *(uint4*)(h2I + ((((long)(b*64 + oy)*3 + pl)*16 + cog*8 + ch)*64 + px)*8) = *(uint4*)tmp;
  }
}

// ---------------- conv3: MFMA 6-term split; A+B via global_load_lds ----------------
__global__ __launch_bounds__(256, 2) void conv3_mfma(
    const unsigned short* __restrict__ h2I,  // [b][row64][pl3][ch16][px64][8]
    const unsigned short* __restrict__ w2,   // LDS-image: [ch][24576 shorts]
    const float* __restrict__ bias,
    unsigned short* __restrict__ zeH, unsigned short* __restrict__ zeM,
    unsigned short* __restrict__ zeL) {
  __shared__ __align__(16) unsigned short sA3[3][3][68][8];
  __shared__ __align__(16) unsigned short sB[24576];
  const int tid = threadIdx.x;
  const int oy = blockIdx.x, b = blockIdx.z;
  const int wave = tid >> 6, lane = tid & 63;
  const int wr = wave >> 1, wc = wave & 1;
  const int col_l = lane & 15, kg = lane >> 4;
  f32x4 acc[2][2] = {};
  // zero pad cols {0,65,66} for all 9 (pl,rr) rows
  if (tid < 27) {
    int row = tid/3, c = tid%3;
    int pl = row/3, rr = row%3;
    *(uint4*)&sA3[pl][rr][(c==0)?0:(64+c)][0] = zero4();
  }
  // zero full OOB rows once (iy fixed per rr for this block)
  if (oy == 0 && tid < 192) {
    int pl = tid >> 6, px = tid & 63;
    *(uint4*)&sA3[pl][0][px+1][0] = zero4();
  }
  if (oy == 63 && tid < 192) {
    int pl = tid >> 6, px = tid & 63;
    *(uint4*)&sA3[pl][2][px+1][0] = zero4();
  }

  for (int ch = 0; ch < 16; ++ch) {
    __syncthreads();
    // A: 9 row-copies (1KB each) via global_load_lds, linear dest
    #pragma unroll
    for (int j = 0; j < 3; ++j) {
      int row = wave*3 + j;
      if (row < 9) {
        int pl = row/3, rr = row%3;
        int iy = oy + rr - 1;
        if (iy >= 0 && iy < 64)
          gload_lds16(h2I + ((((long)(b*64 + iy)*3 + pl)*16 + ch)*64)*8 + lane*8,
                      &sA3[pl][rr][1][0]);
      }
    }
    // B: 48 KB via global_load_lds
    #pragma unroll
    for (int j = 0; j < 12; ++j) {
      int blk = wave*12 + j;
      gload_lds16(w2 + (long)ch*24576 + blk*512 + lane*8, &sB[blk*512]);
    }
    __syncthreads();
    #pragma unroll
    for (int s = 0; s < 3; ++s) {
      bf16x8 aF[2][3]; bf16x8 bF[2][3];
      const int tap = s*4 + kg;
      #pragma unroll
      for (int mf = 0; mf < 2; ++mf) {
        int ox = wr*32 + mf*16 + col_l;
        #pragma unroll
        for (int pl = 0; pl < 3; ++pl)
          aF[mf][pl] = *(const bf16x8*)&sA3[pl][s][ox + kg][0];
      }
      #pragma unroll
      for (int nf = 0; nf < 2; ++nf) {
        int co = wc*32 + nf*16 + col_l;
        int ba = (co*16 + (tap ^ (co&15)))*8;
        bF[nf][0] = *(const bf16x8*)&sB[ba];
        bF[nf][1] = *(const bf16x8*)&sB[ba + 8192];
        bF[nf][2] = *(const bf16x8*)&sB[ba + 16384];
      }
      __builtin_amdgcn_s_setprio(1);
      #pragma unroll
      for (int mf = 0; mf < 2; ++mf)
      #pragma unroll
      for (int nf = 0; nf < 2; ++nf) {
        f32x4 a = acc[mf][nf];
        a = MFMA16(aF[mf][0], bF[nf][0], a);
        a = MFMA16(aF[mf][0], bF[nf][1], a);
        a = MFMA16(aF[mf][1], bF[nf][0], a);
        a = MFMA16(aF[mf][0], bF[nf][2], a);
        a = MFMA16(aF[mf][2], bF[nf][0], a);
        a = MFMA16(aF[mf][1], bF[nf][1], a);
        acc[mf][nf] = a;
      }
      __builtin_amdgcn_s_setprio(0);
    }
  }
  // epilogue: acc -> sB[pl][co][72pad] -> planar ze planes (vq_mfma layout)
  __syncthreads();
  #pragma unroll
  for (int nf = 0; nf < 2; ++nf) {
    int co = wc*32 + nf*16 + col_l;
    float bv = bias[co];
    #pragma unroll
    for (int mf = 0; mf < 2; ++mf) {
      int px0 = wr*32 + mf*16 + kg*4;
      u16x4 oh, om, ol;
      #pragma unroll
      for (int r = 0; r < 4; ++r) {
        float v = acc[mf][nf][r] + bv;
        unsigned short h,m,l; split3(v,h,m,l);
        oh[r]=h; om[r]=m; ol[r]=l;
      }
      *(u16x4*)&sB[(0*64 + co)*72 + px0] = oh;
      *(u16x4*)&sB[(1*64 + co)*72 + px0] = om;
      *(u16x4*)&sB[(2*64 + co)*72 + px0] = ol;
    }
  }
  __syncthreads();
  #pragma unroll
  for (int j = 0; j < 6; ++j) {
    int idx = tid + j*256;
    int pl = idx >> 9, co_l = (idx >> 3) & 63, q = idx & 7;
    uint4 v = *(const uint4*)&sB[(pl*64 + co_l)*72 + q*8];
    unsigned short* dst = (pl==0) ? zeH : ((pl==1) ? zeM : zeL);
    *(uint4*)(dst + ((long)(b*64 + co_l)*64 + oy)*64 + q*8) = v;
  }
}

// ---------------- MFMA ConvTranspose2d s2k4p1; W via global_load_lds (image) ----------
template<int TX, int MODE>
struct SmemD {
  union {
    struct { __align__(16) unsigned short In[2][TX+2][24];
             __align__(16) unsigned short W[2*128*64]; } o;
    struct { __align__(16) unsigned short In[2][TX+2][16];
             __align__(16) unsigned short W[2*128*64]; } v;
    __align__(16) unsigned short Out[2*TX][136];
  };
};

template<int CIN, int TX, int MODE>
__global__ __launch_bounds__(TX*4, (TX==64)?3:4) void deconv_mfma(
    const void* __restrict__ xin, const unsigned short* __restrict__ w2,
    const float* __restrict__ bias, unsigned short* __restrict__ yI) {
  constexpr int NTHR = TX*4;
  constexpr int NWAVE = NTHR/64;
  constexpr int NWG  = 32/NWAVE;
  __shared__ SmemD<TX,MODE> sm;
  unsigned short* Wb = MODE ? &sm.v.W[0] : &sm.o.W[0];

  const int tid = threadIdx.x;
  const int ty = blockIdx.x, e = blockIdx.y, b = blockIdx.z;
  const int wave = tid >> 6, lane = tid & 63;
  const int wc = wave & 1, wr = wave >> 1;
  const int f = (wr*64) / TX;
  const int tx_base = (wr*64) & (TX-1);
  const int col_l = lane & 15, kg = lane >> 4;
  const unsigned short* wsrc = w2 + (long)e*(CIN/16)*16384;

  constexpr int TPR = NTHR/32;
  const int rowid = tid / TPR, liO = tid % TPR;
  const int sci = rowid >> 1, srr = rowid & 1;
  float4 pLo, pHi; uint4 pIn;
  long aBase = 0; bool aOk = false;
  int pxV = 0, halfV = 0, rrV = 0;
  if (MODE == 0) {
    int iy = ty + e - 1 + srr;
    aOk = (iy >= 0 && iy < TX);
    aBase = ((long)b*CIN + sci)*TX*TX + (long)(aOk?iy:0)*TX + liO*8;
    if (aOk) { const float4* s4 = (const float4*)((const float*)xin + aBase);
               pLo = s4[0]; pHi = s4[1]; }
  } else {
    halfV = tid & 1; pxV = (tid >> 1) & (TX-1); rrV = tid >> 8;
    int iy = ty + e - 1 + rrV;
    aOk = (iy >= 0 && iy < TX);
    aBase = ((long)b*TX + (aOk?iy:0))*((long)(CIN/8)*TX*8) + (long)halfV*TX*8 + pxV*8;
    pIn = aOk ? *(const uint4*)((const unsigned short*)xin + aBase) : zero4();
  }

  if (MODE == 0) {
    if (tid < 64) {
      int rr = tid & 1, cc = ((tid>>1)&1) ? TX+1 : 0, ci = tid >> 2;
      sm.o.In[rr][cc][ci] = 0;
    }
  } else {
    if (tid < 8) {
      int rr = tid & 1, c = (tid>>1)&1, hf = (tid>>2)&1;
      *(uint4*)&sm.v.In[rr][c?TX+1:0][hf*8] = zero4();
    }
  }

  f32x4 acc[4][4] = {};
  for (int ch = 0; ch < CIN/16; ++ch) {
    __syncthreads();
    if (MODE == 0) {
      unsigned short vals[8];
      if (aOk) {
        float4 lo = pLo, hi = pHi;
        vals[0]=bfbits(lo.x); vals[1]=bfbits(lo.y); vals[2]=bfbits(lo.z); vals[3]=bfbits(lo.w);
        vals[4]=bfbits(hi.x); vals[5]=bfbits(hi.y); vals[6]=bfbits(hi.z); vals[7]=bfbits(hi.w);
      } else {
        #pragma unroll
        for (int j=0;j<8;j++) vals[j] = 0;
      }
      #pragma unroll
      for (int j=0;j<8;j++) {
        int jj = (j + liO) & 7;
        sm.o.In[srr][1 + liO*8 + jj][sci] = vals[jj];
      }
    } else {
      *(uint4*)&sm.v.In[rrV][pxV+1][halfV*8] = pIn;
    }
    #pragma unroll
    for (int j = 0; j < NWG; ++j) {
      int blk = wave*NWG + j;
      gload_lds16(wsrc + (long)ch*16384 + blk*512 + lane*8, Wb + blk*512);
    }
    if (ch + 1 < CIN/16) {
      if (MODE == 0) {
        if (aOk) { const float4* s4 = (const float4*)((const float*)xin + aBase + (long)(ch+1)*16*TX*TX);
                   pLo = s4[0]; pHi = s4[1]; }
      } else {
        pIn = aOk ? *(const uint4*)((const unsigned short*)xin + aBase + (ch+1)*2*TX*8) : zero4();
      }
    }
    __syncthreads();
    #pragma unroll
    for (int kk = 0; kk < 2; ++kk) {
      bf16x8 aF[4];
      const int tap = kk*2 + (kg >> 1), a = tap >> 1, bb = tap & 1;
      #pragma unroll
      for (int mf = 0; mf < 4; ++mf) {
        int tx = tx_base + mf*16 + col_l;
        if (MODE == 0) aF[mf] = *(const bf16x8*)&sm.o.In[1-a][tx + 1 + f - bb][(kg&1)*8];
        else           aF[mf] = *(const bf16x8*)&sm.v.In[1-a][tx + 1 + f - bb][(kg&1)*8];
      }
      const int slot = kk*4 + kg;
      __builtin_amdgcn_s_setprio(1);
      #pragma unroll
      for (int nf = 0; nf < 4; ++nf) {
        int co_l = nf*16 + col_l;
        bf16x8 bF = *(const bf16x8*)(Wb + (f*128 + wc*64 + co_l)*64 + (slot ^ (co_l & 7))*8);
        #pragma unroll
        for (int mf = 0; mf < 4; ++mf)
          acc[mf][nf] = MFMA16(aF[mf], bF, acc[mf][nf]);
      }
      __builtin_amdgcn_s_setprio(0);
    }
  }

  __syncthreads();
  float bv[4];
  #pragma unroll
  for (int nf = 0; nf < 4; ++nf) bv[nf] = bias[wc*64 + nf*16 + col_l];
  #pragma unroll
  for (int mf = 0; mf < 4; ++mf)
  #pragma unroll
  for (int nf = 0; nf < 4; ++nf) {
    int co = wc*64 + nf*16 + col_l;
    #pragma unroll
    for (int r = 0; r < 4; ++r) {
      int tx = tx_base + mf*16 + kg*4 + r;
      float v = fmaxf(acc[mf][nf][r] + bv[nf], 0.f);
      int ox = 2*tx + f;
      sm.Out[ox][co ^ (((ox>>3)&7)<<3)] = bfbits(v);
    }
  }
  __syncthreads();
  const int oy = 2*ty + e;
  #pragma unroll
  for (int j = 0; j < 8; ++j) {
    int i = tid + j*NTHR;
    int px = i & (2*TX-1), chn = i / (2*TX);
    uint4 vv = *(const uint4*)&sm.Out[px][(chn*8) ^ (((px>>3)&7)<<3)];
    *(uint4*)(yI + ((((long)b*(2*TX) + oy)*16 + chn)*(2*TX) + px)*8) = vv;
  }
}

// ---------------- deconv3: MFMA + sigmoid (unchanged) ----------
__global__ __launch_bounds__(256, 2) void deconv3_mfma(
    const unsigned short* __restrict__ g2I,
    const unsigned short* __restrict__ w2,
    const float* __restrict__ bias, float* __restrict__ y) {
  __shared__ __align__(16) unsigned short sA[3][260][8];
  __shared__ __align__(16) unsigned short sB[16*12*16*8];
  const int tid = threadIdx.x;
  const int oy = blockIdx.x, b = blockIdx.y;
  const int wave = tid >> 6, lane = tid & 63;
  const int col_l = lane & 15, kg = lane >> 4;
  const int pxb = wave*64;
  for (int i = tid; i < 3072; i += 256) {
    int co = i & 15, tap = (i>>4) % 12, ch = i/192;
    *(uint4*)&sB[((ch*12+tap)*16+co)*8] = *(const uint4*)(w2 + (long)co*1536 + ch*96 + tap*8);
  }
  if (tid < 12) {
    int dy = tid >> 2, c = tid & 3;
    *(uint4*)&sA[dy][(c<2)?c:(256+c)][0] = zero4();
  }
  long aBase[3]; int aLdsO[3]; bool aOk[3];
  #pragma unroll
  for (int u = 0; u < 3; ++u) {
    int idx = tid + u*256;
    int px = idx & 255, dy = idx >> 8;
    int iy = oy - 1 + dy;
    aOk[u] = (iy >= 0 && iy < 256);
    aBase[u] = ((long)(b*256 + (aOk[u]?iy:0)))*32768 + px*8;
    aLdsO[u] = (dy*260 + px + 2)*8;
  }
  uint4 pA[3];
  #pragma unroll
  for (int u=0;u<3;u++) pA[u] = aOk[u] ? *(const uint4*)(g2I + aBase[u]) : zero4();

  unsigned short* sAf = &sA[0][0][0];
  f32x4 acc[4] = {};
  for (int ch = 0; ch < 16; ++ch) {
    __syncthreads();
    #pragma unroll
    for (int u=0;u<3;u++) *(uint4*)(sAf + aLdsO[u]) = pA[u];
    if (ch < 15) {
      #pragma unroll
      for (int u=0;u<3;u++)
        pA[u] = aOk[u] ? *(const uint4*)(g2I + aBase[u] + (ch+1)*2048) : zero4();
    }
    __syncthreads();
    #pragma unroll
    for (int s = 0; s < 3; ++s) {
      bf16x8 bF = *(const bf16x8*)&sB[((ch*12 + s*4 + kg)*16 + col_l)*8];
      __builtin_amdgcn_s_setprio(1);
      #pragma unroll
      for (int mf = 0; mf < 4; ++mf) {
        int px = pxb + mf*16 + col_l;
        bf16x8 aF = *(const bf16x8*)&sA[2-s][px + 3 - kg][0];
        acc[mf] = MFMA16(aF, bF, acc[mf]);
      }
      __builtin_amdgcn_s_setprio(0);
    }
  }
  if (col_l < 3) {
    float bv = bias[col_l];
    #pragma unroll
    for (int mf = 0; mf < 4; ++mf) {
      int px = pxb + mf*16 + kg*4;
      float4 o;
      o.x = 1.f/(1.f + expf(-(acc[mf][0] + bv)));
      o.y = 1.f/(1.f + expf(-(acc[mf][1] + bv)));
      o.z = 1.f/(1.f + expf(-(acc[mf][2] + bv)));
      o.w = 1.f/(1.f + expf(-(acc[mf][3] + bv)));
      *(float4*)(y + ((long)(b*3 + col_l)*256 + oy)*256 + px) = o;
    }
  }
}

// ---------------- VQ via MFMA (unchanged) ----------------
__global__ __launch_bounds__(256, 2) void vq_mfma(
    const unsigned short* __restrict__ zeH, const unsigned short* __restrict__ zeM,
    const unsigned short* __restrict__ zeL,
    const float* __restrict__ emb, const float* __restrict__ esq,
    float* __restrict__ out_idx, float* __restrict__ zq) {
  __shared__ __align__(16) unsigned short sA[64*3*8*8];
  __shared__ __align__(16) unsigned short sB[128*3*8*8];
  __shared__ float snb[128];
  __shared__ int sidx[64];
  const int tid = threadIdx.x;
  const long n0 = (long)blockIdx.x*64;
  const int wave = tid >> 6, lane = tid & 63;
  const int col = lane & 15, kg = lane >> 4;

  #pragma unroll
  for (int j = 0; j < 6; ++j) {
    int idx = tid + j*256;
    int pl = idx >> 9, rem = idx & 511;
    int n = rem >> 3, slot = rem & 7;
    const unsigned short* src = (pl==0 ? zeH : (pl==1 ? zeM : zeL)) + (n0+n)*64 + slot*8;
    *(uint4*)&sA[((n*3 + pl)*8 + (slot ^ (n&7)))*8] = *(const uint4*)src;
  }

  const int codeT = tid >> 1, halfT = tid & 1;
  float4 pB[8];
  #pragma unroll
  for (int q = 0; q < 8; ++q)
    pB[q] = *(const float4*)(emb + (long)codeT*64 + halfT*32 + q*4);
  float pSn = (tid < 128) ? esq[tid] : 0.f;

  float best[4] = {3.4e38f,3.4e38f,3.4e38f,3.4e38f};
  int bidx[4] = {0,0,0,0};

  for (int ch = 0; ch < 4; ++ch) {
    __syncthreads();
    #pragma unroll
    for (int s4 = 0; s4 < 4; ++s4) {
      int slot = halfT*4 + s4;
      float4 lo = pB[s4*2], hi = pB[s4*2+1];
      unsigned short th[8], tm[8], tl[8];
      split3(lo.x, th[0], tm[0], tl[0]); split3(lo.y, th[1], tm[1], tl[1]);
      split3(lo.z, th[2], tm[2], tl[2]); split3(lo.w, th[3], tm[3], tl[3]);
      split3(hi.x, th[4], tm[4], tl[4]); split3(hi.y, th[5], tm[5], tl[5]);
      split3(hi.z, th[6], tm[6], tl[6]); split3(hi.w, th[7], tm[7], tl[7]);
      int base = ((codeT*3)*8 + (slot ^ (codeT&7)))*8;
      *(uint4*)&sB[base]       = *(uint4*)th;
      *(uint4*)&sB[base + 64]  = *(uint4*)tm;
      *(uint4*)&sB[base + 128] = *(uint4*)tl;
    }
    if (tid < 128) snb[tid] = pSn;
    if (ch < 3) {
      #pragma unroll
      for (int q = 0; q < 8; ++q)
        pB[q] = *(const float4*)(emb + ((long)(ch+1)*128 + codeT)*64 + halfT*32 + q*4);
      if (tid < 128) pSn = esq[(ch+1)*128 + tid];
    }
    __syncthreads();

    f32x4 acc[8] = {};
    #pragma unroll
    for (int kk = 0; kk < 2; ++kk) {
      const int nloc = wave*16 + col;
      const int slot = kk*4 + kg;
      bf16x8 aF[3];
      #pragma unroll
      for (int pl = 0; pl < 3; ++pl)
        aF[pl] = *(const bf16x8*)&sA[((nloc*3 + pl)*8 + (slot ^ (nloc&7)))*8];
      __builtin_amdgcn_s_setprio(1);
      #pragma unroll
      for (int cf = 0; cf < 8; ++cf) {
        int cl = cf*16 + col;
        int bb = ((cl*3)*8 + (slot ^ (cl&7)))*8;
        bf16x8 b0 = *(const bf16x8*)&sB[bb];
        bf16x8 b1 = *(const bf16x8*)&sB[bb + 64];
        bf16x8 b2 = *(const bf16x8*)&sB[bb + 128];
        f32x4 a = acc[cf];
        a = MFMA16(aF[0], b0, a);
        a = MFMA16(aF[0], b1, a);
        a = MFMA16(aF[1], b0, a);
        a = MFMA16(aF[0], b2, a);
        a = MFMA16(aF[2], b0, a);
        a = MFMA16(aF[1], b1, a);
        acc[cf] = a;
      }
      __builtin_amdgcn_s_setprio(0);
    }
    #pragma unroll
    for (int cf = 0; cf < 8; ++cf) {
      float sv = snb[cf*16 + col];
      int code = ch*128 + cf*16 + col;
      #pragma unroll
      for (int j = 0; j < 4; ++j) {
        float s = sv - 2.f*acc[cf][j];
        if (s < best[j]) { best[j] = s; bidx[j] = code; }
      }
    }
  }

  #pragma unroll
  for (int j = 0; j < 4; ++j) {
    float b = best[j]; int ii = bidx[j];
    #pragma unroll
    for (int off = 1; off < 16; off <<= 1) {
      float ob = __shfl_xor(b, off);
      int oi = __shfl_xor(ii, off);
      if (ob < b || (ob == b && oi < ii)) { b = ob; ii = oi; }
    }
    if (col == 0) sidx[wave*16 + kg*4 + j] = ii;
  }
  __syncthreads();
  if (tid < 64) out_idx[n0 + tid] = (float)sidx[tid];
  #pragma unroll
  for (int j = 0; j < 4; ++j) {
    int t = tid + j*256;
    int row = t >> 4, q = t & 15;
    float4 v = *(const float4*)(emb + (long)sidx[row]*64 + q*4);
    *(float4*)(zq + (n0 + row)*64 + q*4) = v;
  }
}

// ---------------- launch ----------------
extern "C" void kernel_launch(void* const* d_in, const int* in_sizes, int n_in,
                              void* d_out, int out_size, void* d_ws, size_t ws_size,
                              hipStream_t stream) {
  const float* x   = (const float*)d_in[0];
  const float* c1w = (const float*)d_in[1];  const float* c1b = (const float*)d_in[2];
  const float* c2w = (const float*)d_in[3];  const float* c2b = (const float*)d_in[4];
  const float* c3w = (const float*)d_in[5];  const float* c3b = (const float*)d_in[6];
  const float* emb = (const float*)d_in[7];
  const float* d1w = (const float*)d_in[8];  const float* d1b = (const float*)d_in[9];
  const float* d2w = (const float*)d_in[10]; const float* d2b = (const float*)d_in[11];
  const float* d3w = (const float*)d_in[12]; const float* d3b = (const float*)d_in[13];
  float* out = (float*)d_out;

  float* xrec = out;
  float* oidx = out + 3145728;
  float* zq   = out + 3211264;

  const long XB  = 196608;   // 3*256*256
  const long ZEB = 262144;   // ze elems per batch
  const long PS1 = 8388608;  // per-plane h1 (interleaved) in shorts
  const long H2B = 1572864;  // per-batch h2I stride in shorts (64row*3pl*16ch*512)

  const size_t NEEDED = 112273408ULL;  // known: ws_size >= 120,395,264
  if (ws_size < NEEDED) return;
  char* wsb = (char*)d_ws;
  unsigned short* h1grp = (unsigned short*)wsb;              // interleaved, 50.3MB
  unsigned short* g2grp = (unsigned short*)wsb;              // interleaved, 64MB
  unsigned short* h2I   = (unsigned short*)(wsb + 67108864); // interleaved 8-batch, 25.17MB
  unsigned short* g1grp = (unsigned short*)(wsb + 67108864); // interleaved, 16MB
  unsigned short* zeH = (unsigned short*)(wsb + 92274688);
  unsigned short* zeM = (unsigned short*)(wsb + 100663296);
  unsigned short* zeL = (unsigned short*)out;                // xrec region: dead until deconv3
  char* W = wsb + 109051904;
  float* w2c1          = (float*)(W);
  unsigned short* w2c2 = (unsigned short*)(W + 24576);
  unsigned short* w2c3 = (unsigned short*)(W + 1597440);
  unsigned short* w2d1 = (unsigned short*)(W + 2383872);
  unsigned short* w2d2 = (unsigned short*)(W + 2646016);
  unsigned short* w2d3 = (unsigned short*)(W + 3170304);
  float* esq           = (float*)(W + 3219456);

  wprep_all<<<3066, 256, 0, stream>>>(c1w, w2c1, c2w, w2c2, c3w, w2c3,
                                      d1w, w2d1, d2w, w2d2, d3w, w2d3, emb, esq);

  // encoder
  for (int g = 0; g < 4; ++g) {
    conv1_split<<<dim3(16,16,8), 256, 0, stream>>>(
        x + (long)g*4*XB, w2c1, c1b, h1grp, PS1);
    conv2_mfma<<<dim3(64,2,4), 256, 0, stream>>>(
        h1grp, PS1, w2c2, c2b, h2I + (long)(g&1)*4*H2B);
    if (g & 1) {
      long zo = (long)(g>>1)*8*ZEB;
      conv3_mfma<<<dim3(64,1,8), 256, 0, stream>>>(
          h2I, w2c3, c3b, zeH + zo, zeM + zo, zeL + zo);
    }
  }
  vq_mfma<<<1024, 256, 0, stream>>>(zeH, zeM, zeL, emb, esq, oidx, zq);

  // decoder
  for (int g = 0; g < 4; ++g) {
    deconv_mfma<64, 64, 0 ><<<dim3(64, 2, 4), 256, 0, stream>>>(
        (const void*)(zq + (long)g*4*ZEB), w2d1, d1b, g1grp);
    deconv_mfma<128,128,1 ><<<dim3(128,2,4), 512, 0, stream>>>(
        (const void*)g1grp, w2d2, d2b, g2grp);
    deconv3_mfma<<<dim3(256,4), 256, 0, stream>>>(
        g2grp, w2d3, d3b, xrec + (long)g*4*XB);
  }
}